// Round 1
// baseline (710.671 us; speedup 1.0000x reference)
//
#include <hip/hip_runtime.h>
#include <stdint.h>

#define PI_F 3.14159265358979323846f

constexpr int INSZ = 224;
constexpr int GD   = 53;
constexpr int C0R = 8427, C1R = 2106, C2R = 526;
constexpr int C0P = 8448, C1P = 2176, C2P = 640;
constexpr int NTOK = 2048; // 8 batches * 256 DCT positions

typedef __attribute__((ext_vector_type(4))) float f32x4;
typedef __attribute__((ext_vector_type(8))) short bf16x8;

__device__ __forceinline__ unsigned short f2bf(float f) {
  union { float f; unsigned u; } v; v.f = f;
  return (unsigned short)((v.u + 0x7FFFu + ((v.u >> 16) & 1u)) >> 16);
}
__device__ __forceinline__ float bf2f(unsigned short b) {
  union { unsigned u; float f; } v; v.u = ((unsigned)b) << 16;
  return v.f;
}

// global -> LDS async copy, 16B per lane; LDS dest is wave-uniform base + lane*16
__device__ __forceinline__ void gload_lds16(const void* g, void* l) {
  __builtin_amdgcn_global_load_lds(
      (__attribute__((address_space(1))) unsigned int*)(uintptr_t)g,
      (__attribute__((address_space(3))) unsigned int*)(unsigned int)(uintptr_t)l,
      16, 0, 0);
}

// -------- weight fp32 -> bf16 with zero padding --------
__global__ void cvt_pad(const float* __restrict__ src, unsigned short* __restrict__ dst,
                        int M, int K, int Kp) {
  const int k = blockIdx.x * 256 + threadIdx.x;
  const int m = blockIdx.y;
  if (k >= Kp) return;
  const float v = (m < M && k < K) ? src[(size_t)m * K + k] : 0.f;
  dst[(size_t)m * Kp + k] = f2bf(v);
}

// -------- DCT: x -> H0 bf16 [n=2048][c=8448]  (h = dct/256) --------
__global__ __launch_bounds__(256)
void dct_h0(const float* __restrict__ x, unsigned short* __restrict__ H0) {
  __shared__ float Dm[256];               // D[k][m] = 2*cos(pi*(2m+1)k/32)
  __shared__ float patch[16 * 272];       // [tile][row][17] padded
  __shared__ unsigned short hst[256 * 64];// [kl][tile_local]
  const int tid = threadIdx.x;
  const int b   = blockIdx.y;
  const int c0  = blockIdx.x * 64;
  {
    const int k = tid >> 4, m = tid & 15;
    Dm[tid] = 2.f * cosf(PI_F * (float)((2 * m + 1) * k) / 32.f);
  }
  __syncthreads();
  const int t = tid >> 4, q = tid & 15;
  float Drow[16];
#pragma unroll
  for (int m = 0; m < 16; ++m) Drow[m] = Dm[q * 16 + m];

  for (int g = 0; g < 4; ++g) {
    const int c = c0 + g * 16 + t;
    { // stage A: load row q of tile t's 16x16 patch
      float4 v0{}, v1{}, v2{}, v3{};
      if (c < C0R) {
        const int ch = c % 3, gw = (c / 3) % GD, gh = c / (3 * GD);
        const float* xr = x + ((size_t)(b * 3 + ch) * INSZ + (gh * 4 + q)) * INSZ + gw * 4;
        v0 = *(const float4*)(xr);      v1 = *(const float4*)(xr + 4);
        v2 = *(const float4*)(xr + 8);  v3 = *(const float4*)(xr + 12);
      }
      float* pr = &patch[t * 272 + q * 17];
      pr[0]=v0.x; pr[1]=v0.y; pr[2]=v0.z; pr[3]=v0.w;
      pr[4]=v1.x; pr[5]=v1.y; pr[6]=v1.z; pr[7]=v1.w;
      pr[8]=v2.x; pr[9]=v2.y; pr[10]=v2.z; pr[11]=v2.w;
      pr[12]=v3.x; pr[13]=v3.y; pr[14]=v3.z; pr[15]=v3.w;
    }
    __syncthreads();
    // stage B: tmpr[n] = sum_m D[q][m] * P[m][n]   (thread owns DCT row q of tile t)
    float tmpr[16];
#pragma unroll
    for (int n = 0; n < 16; ++n) tmpr[n] = 0.f;
#pragma unroll
    for (int m = 0; m < 16; ++m) {
      const float dm = Drow[m];
      const float* pr = &patch[t * 272 + m * 17];
#pragma unroll
      for (int n = 0; n < 16; ++n) tmpr[n] += dm * pr[n];
    }
    // stage C: dct[q][l] = sum_n tmpr[n]*D[l][n]; stage to LDS transposed
#pragma unroll
    for (int l = 0; l < 16; ++l) {
      float s = 0.f;
#pragma unroll
      for (int n = 0; n < 16; ++n) s += tmpr[n] * Dm[l * 16 + n];
      hst[(q * 16 + l) * 64 + g * 16 + t] = f2bf(s * (1.f / 256.f));
    }
    __syncthreads();
  }
  // write H0[n][c]: per iteration a 64-lane group writes 64 contiguous bf16
  const size_t base = ((size_t)b * 256) * C0P + c0;
  for (int i = 0; i < 64; ++i) {
    const int flat = i * 256 + tid;
    const int kl = flat >> 6, tc = flat & 63;
    H0[base + (size_t)kl * C0P + tc] = hst[flat];
  }
}

// -------- m97-style 128x128 bf16 MFMA GEMM, B^T storage both sides --------
// W:[Mp][Kp] bf16, Ht:[NTOK][Kp] bf16.
// OUT_NM=1: out[n*ldo + m] = act(sum_k W[m,k]*Ht[n,k] + bias[m])   (acc = mfma(h,w))
// OUT_NM=0: out[m*ldo + n] = ...                                    (acc = mfma(w,h))
template<int ACT, int OUT_NM>
__global__ __launch_bounds__(256)
void gemm_bt(const unsigned short* __restrict__ W, const unsigned short* __restrict__ Ht,
             const float* __restrict__ bias, int Mreal,
             unsigned short* __restrict__ out, int ldo, int Kp) {
  __shared__ unsigned short As[128 * 32];
  __shared__ unsigned short Bs[128 * 32];
  const int tid = threadIdx.x;
  const int w = tid >> 6, lane = tid & 63;
  const int m0 = blockIdx.x * 128, n0 = blockIdx.y * 128;
  const int wr = w >> 1, wc = w & 1;
  const int lhi = lane >> 4, llo = lane & 15;

  f32x4 acc[4][4];
#pragma unroll
  for (int i = 0; i < 4; ++i)
#pragma unroll
    for (int j = 0; j < 4; ++j) acc[i][j] = f32x4{0.f, 0.f, 0.f, 0.f};

  const int nkt = Kp >> 5;
  for (int kt = 0; kt < nkt; ++kt) {
    const int kb = kt * 32;
#pragma unroll
    for (int it = 0; it < 2; ++it) {
      const int chunk = it * 256 + w * 64 + lane; // 16B chunk id in 8KB tile
      const int row = chunk >> 2, kc = chunk & 3;
      gload_lds16(W  + (size_t)(m0 + row) * Kp + kb + kc * 8,
                  &As[(size_t)(it * 256 + w * 64) * 8]);
      gload_lds16(Ht + (size_t)(n0 + row) * Kp + kb + kc * 8,
                  &Bs[(size_t)(it * 256 + w * 64) * 8]);
    }
    __syncthreads();
    bf16x8 af[4], bfr[4];
#pragma unroll
    for (int mi = 0; mi < 4; ++mi)
      af[mi]  = *(const bf16x8*)(&As[(wr * 64 + mi * 16 + llo) * 32 + lhi * 8]);
#pragma unroll
    for (int ni = 0; ni < 4; ++ni)
      bfr[ni] = *(const bf16x8*)(&Bs[(wc * 64 + ni * 16 + llo) * 32 + lhi * 8]);
#pragma unroll
    for (int mi = 0; mi < 4; ++mi)
#pragma unroll
      for (int ni = 0; ni < 4; ++ni) {
        if (OUT_NM)
          acc[mi][ni] = __builtin_amdgcn_mfma_f32_16x16x32_bf16(bfr[ni], af[mi], acc[mi][ni], 0, 0, 0);
        else
          acc[mi][ni] = __builtin_amdgcn_mfma_f32_16x16x32_bf16(af[mi], bfr[ni], acc[mi][ni], 0, 0, 0);
      }
    __syncthreads();
  }

  if (OUT_NM) {
#pragma unroll
    for (int mi = 0; mi < 4; ++mi) {
      const int mg = m0 + wr * 64 + mi * 16 + llo;
      const float bv = (mg < Mreal) ? bias[mg] : 0.f;
#pragma unroll
      for (int ni = 0; ni < 4; ++ni) {
        const int ng = n0 + wc * 64 + ni * 16 + lhi * 4;
#pragma unroll
        for (int r = 0; r < 4; ++r) {
          float v = acc[mi][ni][r] + bv;
          if (ACT == 1) v = fmaxf(v, 0.f);
          else if (ACT == 2) v = 1.f / (1.f + expf(-v));
          out[(size_t)(ng + r) * ldo + mg] = f2bf(v);
        }
      }
    }
  } else {
#pragma unroll
    for (int mi = 0; mi < 4; ++mi) {
      const int mgb = m0 + wr * 64 + mi * 16 + lhi * 4;
#pragma unroll
      for (int ni = 0; ni < 4; ++ni) {
        const int ng = n0 + wc * 64 + ni * 16 + llo;
#pragma unroll
        for (int r = 0; r < 4; ++r) {
          const int mg = mgb + r;
          float v = acc[mi][ni][r] + ((mg < Mreal) ? bias[mg] : 0.f);
          if (ACT == 1) v = fmaxf(v, 0.f);
          else if (ACT == 2) v = 1.f / (1.f + expf(-v));
          out[(size_t)mg * ldo + ng] = f2bf(v);
        }
      }
    }
  }
}

// -------- recompute fp32 DCT, multiply by mask, IDCT, write clean tiles --------
__global__ __launch_bounds__(256)
void mask_idct(const float* __restrict__ x, const unsigned short* __restrict__ masks,
               float* __restrict__ clean) {
  __shared__ float Dm[256];   // D[k][m]
  __shared__ float Din[256];  // Di[n][k] = cos(pi(2n+1)k/32)*w[k]/16
  __shared__ float patch[16 * 272];
  __shared__ float cd[16 * 272];
  const int tid = threadIdx.x;
  const int b   = blockIdx.y;
  const int c0  = blockIdx.x * 16;
  {
    const int k = tid >> 4, m = tid & 15;
    Dm[tid] = 2.f * cosf(PI_F * (float)((2 * m + 1) * k) / 32.f);
    const int n = tid >> 4, kk = tid & 15;
    Din[tid] = cosf(PI_F * (float)((2 * n + 1) * kk) / 32.f) * ((kk == 0) ? 0.5f : 1.f) * (1.f / 16.f);
  }
  __syncthreads();
  const int t = tid >> 4, q = tid & 15;
  const int c = c0 + t;
  const bool valid = (c < C0R);
  { // patch load (row q of tile t)
    float4 v0{}, v1{}, v2{}, v3{};
    if (valid) {
      const int ch = c % 3, gw = (c / 3) % GD, gh = c / (3 * GD);
      const float* xr = x + ((size_t)(b * 3 + ch) * INSZ + (gh * 4 + q)) * INSZ + gw * 4;
      v0 = *(const float4*)(xr);      v1 = *(const float4*)(xr + 4);
      v2 = *(const float4*)(xr + 8);  v3 = *(const float4*)(xr + 12);
    }
    float* pr = &patch[t * 272 + q * 17];
    pr[0]=v0.x; pr[1]=v0.y; pr[2]=v0.z; pr[3]=v0.w;
    pr[4]=v1.x; pr[5]=v1.y; pr[6]=v1.z; pr[7]=v1.w;
    pr[8]=v2.x; pr[9]=v2.y; pr[10]=v2.z; pr[11]=v2.w;
    pr[12]=v3.x; pr[13]=v3.y; pr[14]=v3.z; pr[15]=v3.w;
  }
  __syncthreads();
  float Drow[16];
#pragma unroll
  for (int m = 0; m < 16; ++m) Drow[m] = Dm[q * 16 + m];
  float tmpr[16];
#pragma unroll
  for (int n = 0; n < 16; ++n) tmpr[n] = 0.f;
#pragma unroll
  for (int m = 0; m < 16; ++m) {
    const float dm = Drow[m];
    const float* pr = &patch[t * 272 + m * 17];
#pragma unroll
    for (int n = 0; n < 16; ++n) tmpr[n] += dm * pr[n];
  }
  // masks row: masks[c][b*256 + q*16 + l]  (bf16, 16B vector loads)
  unsigned mu[8] = {0, 0, 0, 0, 0, 0, 0, 0};
  if (valid) {
    const uint4* mp = (const uint4*)(masks + (size_t)c * NTOK + (size_t)b * 256 + q * 16);
    uint4 a = mp[0], bb = mp[1];
    mu[0]=a.x; mu[1]=a.y; mu[2]=a.z; mu[3]=a.w;
    mu[4]=bb.x; mu[5]=bb.y; mu[6]=bb.z; mu[7]=bb.w;
  }
  float mrowf[16];
#pragma unroll
  for (int l = 0; l < 8; ++l) {
    mrowf[2 * l]     = bf2f((unsigned short)(mu[l] & 0xFFFFu));
    mrowf[2 * l + 1] = bf2f((unsigned short)(mu[l] >> 16));
  }
  float* cdr = &cd[t * 272 + q * 17];
#pragma unroll
  for (int l = 0; l < 16; ++l) {
    float s = 0.f;
#pragma unroll
    for (int n = 0; n < 16; ++n) s += tmpr[n] * Dm[l * 16 + n];
    cdr[l] = s * mrowf[l];
  }
  __syncthreads();
  // IDCT: t2[q][l] = sum_k Di[q][k]*cd[k][l];  out[q][np] = sum_l t2[l]*Di[np][l]
  float Dirow[16];
#pragma unroll
  for (int k = 0; k < 16; ++k) Dirow[k] = Din[q * 16 + k];
  float t2r[16];
#pragma unroll
  for (int l = 0; l < 16; ++l) t2r[l] = 0.f;
#pragma unroll
  for (int k = 0; k < 16; ++k) {
    const float dk = Dirow[k];
    const float* cdk = &cd[t * 272 + k * 17];
#pragma unroll
    for (int l = 0; l < 16; ++l) t2r[l] += dk * cdk[l];
  }
  if (valid) {
    float orow[16];
#pragma unroll
    for (int np = 0; np < 16; ++np) {
      float s = 0.f;
#pragma unroll
      for (int l = 0; l < 16; ++l) s += t2r[l] * Din[np * 16 + l];
      orow[np] = s;
    }
    float* dst = clean + ((size_t)b * C0R + c) * 256 + q * 16;
    float4* d4 = (float4*)dst;
    d4[0] = make_float4(orow[0], orow[1], orow[2], orow[3]);
    d4[1] = make_float4(orow[4], orow[5], orow[6], orow[7]);
    d4[2] = make_float4(orow[8], orow[9], orow[10], orow[11]);
    d4[3] = make_float4(orow[12], orow[13], orow[14], orow[15]);
  }
}

// -------- overlap-add gather + count normalization --------
__global__ void overlap_add(const float* __restrict__ clean, float* __restrict__ out) {
  const int px = blockIdx.x * 256 + threadIdx.x;
  if (px >= 8 * 3 * 224 * 224) return;
  const int j = px % 224;
  const int i = (px / 224) % 224;
  const int bc = px / (224 * 224);
  const int ch = bc % 3, b = bc / 3;
  const int ilo = i - 15;
  const int ghlo = ilo > 0 ? (ilo + 3) >> 2 : 0;
  const int ghhi = (i >> 2) < 52 ? (i >> 2) : 52;
  const int jlo = j - 15;
  const int gwlo = jlo > 0 ? (jlo + 3) >> 2 : 0;
  const int gwhi = (j >> 2) < 52 ? (j >> 2) : 52;
  float sum = 0.f;
  for (int gh = ghlo; gh <= ghhi; ++gh) {
    const int r = i - gh * 4;
    const size_t base = ((size_t)b * C0R + (size_t)gh * (3 * GD) + ch) * 256 + (size_t)r * 16 + j;
    for (int gw = gwlo; gw <= gwhi; ++gw) {
      sum += clean[base + (size_t)gw * 764]; // +gw*3*256 - 4*gw
    }
  }
  const int cnt = (ghhi - ghlo + 1) * (gwhi - gwlo + 1);
  out[px] = sum / (float)cnt;
}

extern "C" void kernel_launch(void* const* d_in, const int* in_sizes, int n_in,
                              void* d_out, int out_size, void* d_ws, size_t ws_size,
                              hipStream_t stream) {
  const float* x  = (const float*)d_in[0];
  const float* w1 = (const float*)d_in[1];
  const float* b1 = (const float*)d_in[2];
  const float* w2 = (const float*)d_in[3];
  const float* b2 = (const float*)d_in[4];
  const float* w3 = (const float*)d_in[5];
  const float* b3 = (const float*)d_in[6];
  const float* w4 = (const float*)d_in[7];
  const float* b4 = (const float*)d_in[8];
  float* out = (float*)d_out;
  char* ws = (char*)d_ws;

  const size_t OFF_WB1 = 0;
  const size_t OFF_WB2 = OFF_WB1 + (size_t)C1P * C0P * 2;
  const size_t OFF_WB3 = OFF_WB2 + (size_t)C2P * C1P * 2;
  const size_t OFF_WB4 = OFF_WB3 + (size_t)C1P * C2P * 2;
  const size_t OFF_H0  = OFF_WB4 + (size_t)C0P * C1P * 2;   // 79.1 MB
  const size_t OFF_Y1  = OFF_H0 + (size_t)NTOK * C0P * 2;
  const size_t OFF_Y2  = OFF_Y1 + (size_t)NTOK * C1P * 2;
  const size_t OFF_Y3  = OFF_Y2 + (size_t)NTOK * C2P * 2;   // total ~134 MB

  unsigned short* wb1 = (unsigned short*)(ws + OFF_WB1);
  unsigned short* wb2 = (unsigned short*)(ws + OFF_WB2);
  unsigned short* wb3 = (unsigned short*)(ws + OFF_WB3);
  unsigned short* wb4 = (unsigned short*)(ws + OFF_WB4);
  unsigned short* H0v = (unsigned short*)(ws + OFF_H0);
  unsigned short* Y1  = (unsigned short*)(ws + OFF_Y1);
  unsigned short* Y2  = (unsigned short*)(ws + OFF_Y2);
  unsigned short* Y3  = (unsigned short*)(ws + OFF_Y3);
  unsigned short* msk = (unsigned short*)(ws + OFF_H0);  // alias H0 (dead after GEMM1)
  float* clean = (float*)(ws + 0);                        // alias weights (dead after GEMM4)

  cvt_pad<<<dim3((C0P + 255) / 256, C1P), 256, 0, stream>>>(w1, wb1, C1R, C0R, C0P);
  cvt_pad<<<dim3((C1P + 255) / 256, C2P), 256, 0, stream>>>(w2, wb2, C2R, C1R, C1P);
  cvt_pad<<<dim3((C2P + 255) / 256, C1P), 256, 0, stream>>>(w3, wb3, C1R, C2R, C2P);
  cvt_pad<<<dim3((C1P + 255) / 256, C0P), 256, 0, stream>>>(w4, wb4, C0R, C1R, C1P);

  dct_h0<<<dim3(C0P / 64, 8), 256, 0, stream>>>(x, H0v);

  gemm_bt<1, 1><<<dim3(C1P / 128, NTOK / 128), 256, 0, stream>>>(wb1, H0v, b1, C1R, Y1, C1P, C0P);
  gemm_bt<1, 1><<<dim3(C2P / 128, NTOK / 128), 256, 0, stream>>>(wb2, Y1,  b2, C2R, Y2, C2P, C1P);
  gemm_bt<1, 1><<<dim3(C1P / 128, NTOK / 128), 256, 0, stream>>>(wb3, Y2,  b3, C1R, Y3, C1P, C2P);
  gemm_bt<2, 0><<<dim3(C0P / 128, NTOK / 128), 256, 0, stream>>>(wb4, Y3,  b4, C0R, msk, NTOK, C1P);

  mask_idct<<<dim3((C0R + 15) / 16, 8), 256, 0, stream>>>(x, msk, clean);
  overlap_add<<<dim3((8 * 3 * 224 * 224 + 255) / 256), 256, 0, stream>>>(clean, out);
}

// Round 2
// 656.221 us; speedup vs baseline: 1.0830x; 1.0830x over previous
//
#include <hip/hip_runtime.h>
#include <stdint.h>

#define PI_F 3.14159265358979323846f

constexpr int INSZ = 224;
constexpr int GD   = 53;
constexpr int C0R = 8427, C1R = 2106, C2R = 526;
constexpr int C0P = 8448, C1P = 2176, C2P = 640;
constexpr int NTOK = 2048; // 8 batches * 256 DCT positions

typedef __attribute__((ext_vector_type(4))) float f32x4;
typedef __attribute__((ext_vector_type(8))) short bf16x8;

__device__ __forceinline__ unsigned short f2bf(float f) {
  union { float f; unsigned u; } v; v.f = f;
  return (unsigned short)((v.u + 0x7FFFu + ((v.u >> 16) & 1u)) >> 16);
}
__device__ __forceinline__ float bf2f(unsigned short b) {
  union { unsigned u; float f; } v; v.u = ((unsigned)b) << 16;
  return v.f;
}

// global -> LDS async copy, 16B per lane; LDS dest is wave-uniform base + lane*16
__device__ __forceinline__ void gload_lds16(const void* g, void* l) {
  __builtin_amdgcn_global_load_lds(
      (__attribute__((address_space(1))) unsigned int*)(uintptr_t)g,
      (__attribute__((address_space(3))) unsigned int*)(unsigned int)(uintptr_t)l,
      16, 0, 0);
}

// XCD-aware block swizzle over the (x,y) grid; requires (gx*gy)%8==0
__device__ __forceinline__ void xcd_swz(int& bx, int& by) {
  const int gx = gridDim.x, gy = gridDim.y;
  const int nwg = gx * gy;
  const int bid = blockIdx.y * gx + blockIdx.x;
  const int cpx = nwg >> 3;
  const int swz = (bid & 7) * cpx + (bid >> 3);
  bx = swz % gx;
  by = swz / gx;
}

// -------- weight fp32 -> bf16 with zero padding --------
__global__ void cvt_pad(const float* __restrict__ src, unsigned short* __restrict__ dst,
                        int M, int K, int Kp) {
  const int k = blockIdx.x * 256 + threadIdx.x;
  const int m = blockIdx.y;
  if (k >= Kp) return;
  const float v = (m < M && k < K) ? src[(size_t)m * K + k] : 0.f;
  dst[(size_t)m * Kp + k] = f2bf(v);
}

// -------- DCT: x -> H0 bf16 [n=2048][c=8448]  (h = dct/256) --------
__global__ __launch_bounds__(256)
void dct_h0(const float* __restrict__ x, unsigned short* __restrict__ H0) {
  __shared__ float Dm[256];               // D[k][m] = 2*cos(pi*(2m+1)k/32)
  __shared__ float patch[16 * 272];       // [tile][row][17] padded
  __shared__ unsigned short hst[256 * 64];// [kl][tile_local]
  const int tid = threadIdx.x;
  const int b   = blockIdx.y;
  const int c0  = blockIdx.x * 64;
  {
    const int k = tid >> 4, m = tid & 15;
    Dm[tid] = 2.f * cosf(PI_F * (float)((2 * m + 1) * k) / 32.f);
  }
  __syncthreads();
  const int t = tid >> 4, q = tid & 15;
  float Drow[16];
#pragma unroll
  for (int m = 0; m < 16; ++m) Drow[m] = Dm[q * 16 + m];

  for (int g = 0; g < 4; ++g) {
    const int c = c0 + g * 16 + t;
    { // stage A: load row q of tile t's 16x16 patch
      float4 v0{}, v1{}, v2{}, v3{};
      if (c < C0R) {
        const int ch = c % 3, gw = (c / 3) % GD, gh = c / (3 * GD);
        const float* xr = x + ((size_t)(b * 3 + ch) * INSZ + (gh * 4 + q)) * INSZ + gw * 4;
        v0 = *(const float4*)(xr);      v1 = *(const float4*)(xr + 4);
        v2 = *(const float4*)(xr + 8);  v3 = *(const float4*)(xr + 12);
      }
      float* pr = &patch[t * 272 + q * 17];
      pr[0]=v0.x; pr[1]=v0.y; pr[2]=v0.z; pr[3]=v0.w;
      pr[4]=v1.x; pr[5]=v1.y; pr[6]=v1.z; pr[7]=v1.w;
      pr[8]=v2.x; pr[9]=v2.y; pr[10]=v2.z; pr[11]=v2.w;
      pr[12]=v3.x; pr[13]=v3.y; pr[14]=v3.z; pr[15]=v3.w;
    }
    __syncthreads();
    // stage B: tmpr[n] = sum_m D[q][m] * P[m][n]
    float tmpr[16];
#pragma unroll
    for (int n = 0; n < 16; ++n) tmpr[n] = 0.f;
#pragma unroll
    for (int m = 0; m < 16; ++m) {
      const float dm = Drow[m];
      const float* pr = &patch[t * 272 + m * 17];
#pragma unroll
      for (int n = 0; n < 16; ++n) tmpr[n] += dm * pr[n];
    }
    // stage C: dct[q][l] = sum_n tmpr[n]*D[l][n]; stage to LDS transposed
#pragma unroll
    for (int l = 0; l < 16; ++l) {
      float s = 0.f;
#pragma unroll
      for (int n = 0; n < 16; ++n) s += tmpr[n] * Dm[l * 16 + n];
      hst[(q * 16 + l) * 64 + g * 16 + t] = f2bf(s * (1.f / 256.f));
    }
    __syncthreads();
  }
  // write H0[n][c] as uint4 (16B per lane)
  const size_t base = ((size_t)b * 256) * C0P + c0;
#pragma unroll
  for (int i = 0; i < 8; ++i) {
    const int s = i * 256 + tid;        // 2048 uint4 stores total
    const int kl = s >> 3, c16 = s & 7;
    *(uint4*)&H0[base + (size_t)kl * C0P + c16 * 8] = *(const uint4*)&hst[kl * 64 + c16 * 8];
  }
}

// -------- m97-style 128x128 bf16 MFMA GEMM (direct, with epilogue) --------
// W:[Mp][Kp] bf16, Ht:[NTOK][Kp] bf16.
// OUT_NM=1: out[n*ldo + m] = act(sum_k W[m,k]*Ht[n,k] + bias[m])
// OUT_NM=0: out[m*ldo + n] = ...
template<int ACT, int OUT_NM>
__global__ __launch_bounds__(256)
void gemm_bt(const unsigned short* __restrict__ W, const unsigned short* __restrict__ Ht,
             const float* __restrict__ bias, int Mreal,
             unsigned short* __restrict__ out, int ldo, int Kp) {
  __shared__ unsigned short As[128 * 32];
  __shared__ unsigned short Bs[128 * 32];
  int bx, by; xcd_swz(bx, by);
  const int tid = threadIdx.x;
  const int w = tid >> 6, lane = tid & 63;
  const int m0 = bx * 128, n0 = by * 128;
  const int wr = w >> 1, wc = w & 1;
  const int lhi = lane >> 4, llo = lane & 15;

  f32x4 acc[4][4];
#pragma unroll
  for (int i = 0; i < 4; ++i)
#pragma unroll
    for (int j = 0; j < 4; ++j) acc[i][j] = f32x4{0.f, 0.f, 0.f, 0.f};

  const int nkt = Kp >> 5;
  for (int kt = 0; kt < nkt; ++kt) {
    const int kb = kt * 32;
#pragma unroll
    for (int it = 0; it < 2; ++it) {
      const int chunk = it * 256 + w * 64 + lane;
      const int row = chunk >> 2, kc = chunk & 3;
      gload_lds16(W  + (size_t)(m0 + row) * Kp + kb + kc * 8,
                  &As[(size_t)(it * 256 + w * 64) * 8]);
      gload_lds16(Ht + (size_t)(n0 + row) * Kp + kb + kc * 8,
                  &Bs[(size_t)(it * 256 + w * 64) * 8]);
    }
    __syncthreads();
    bf16x8 af[4], bfr[4];
#pragma unroll
    for (int mi = 0; mi < 4; ++mi)
      af[mi]  = *(const bf16x8*)(&As[(wr * 64 + mi * 16 + llo) * 32 + lhi * 8]);
#pragma unroll
    for (int ni = 0; ni < 4; ++ni)
      bfr[ni] = *(const bf16x8*)(&Bs[(wc * 64 + ni * 16 + llo) * 32 + lhi * 8]);
#pragma unroll
    for (int mi = 0; mi < 4; ++mi)
#pragma unroll
      for (int ni = 0; ni < 4; ++ni) {
        if (OUT_NM)
          acc[mi][ni] = __builtin_amdgcn_mfma_f32_16x16x32_bf16(bfr[ni], af[mi], acc[mi][ni], 0, 0, 0);
        else
          acc[mi][ni] = __builtin_amdgcn_mfma_f32_16x16x32_bf16(af[mi], bfr[ni], acc[mi][ni], 0, 0, 0);
      }
    __syncthreads();
  }

  if (OUT_NM) {
#pragma unroll
    for (int mi = 0; mi < 4; ++mi) {
      const int mg = m0 + wr * 64 + mi * 16 + llo;
      const float bv = (mg < Mreal) ? bias[mg] : 0.f;
#pragma unroll
      for (int ni = 0; ni < 4; ++ni) {
        const int ng = n0 + wc * 64 + ni * 16 + lhi * 4;
#pragma unroll
        for (int r = 0; r < 4; ++r) {
          float v = acc[mi][ni][r] + bv;
          if (ACT == 1) v = fmaxf(v, 0.f);
          else if (ACT == 2) v = 1.f / (1.f + expf(-v));
          out[(size_t)(ng + r) * ldo + mg] = f2bf(v);
        }
      }
    }
  } else {
#pragma unroll
    for (int mi = 0; mi < 4; ++mi) {
      const int mgb = m0 + wr * 64 + mi * 16 + lhi * 4;
#pragma unroll
      for (int ni = 0; ni < 4; ++ni) {
        const int ng = n0 + wc * 64 + ni * 16 + llo;
#pragma unroll
        for (int r = 0; r < 4; ++r) {
          const int mg = mgb + r;
          float v = acc[mi][ni][r] + ((mg < Mreal) ? bias[mg] : 0.f);
          if (ACT == 1) v = fmaxf(v, 0.f);
          else if (ACT == 2) v = 1.f / (1.f + expf(-v));
          out[(size_t)mg * ldo + ng] = f2bf(v);
        }
      }
    }
  }
}

// -------- split-K GEMM: fp32 partials, no epilogue; chunk = blockIdx.z --------
__global__ __launch_bounds__(256)
void gemm_splitk(const unsigned short* __restrict__ W, const unsigned short* __restrict__ Ht,
                 float* __restrict__ part, int ldo /*Mp*/, int Kp, int chunkK) {
  __shared__ unsigned short As[128 * 32];
  __shared__ unsigned short Bs[128 * 32];
  int bx, by; xcd_swz(bx, by);
  const int z = blockIdx.z;
  const int tid = threadIdx.x;
  const int w = tid >> 6, lane = tid & 63;
  const int m0 = bx * 128, n0 = by * 128;
  const int wr = w >> 1, wc = w & 1;
  const int lhi = lane >> 4, llo = lane & 15;

  f32x4 acc[4][4];
#pragma unroll
  for (int i = 0; i < 4; ++i)
#pragma unroll
    for (int j = 0; j < 4; ++j) acc[i][j] = f32x4{0.f, 0.f, 0.f, 0.f};

  const int kbase = z * chunkK;
  const int nkt = chunkK >> 5;
  for (int kt = 0; kt < nkt; ++kt) {
    const int kb = kbase + kt * 32;
#pragma unroll
    for (int it = 0; it < 2; ++it) {
      const int chunk = it * 256 + w * 64 + lane;
      const int row = chunk >> 2, kc = chunk & 3;
      gload_lds16(W  + (size_t)(m0 + row) * Kp + kb + kc * 8,
                  &As[(size_t)(it * 256 + w * 64) * 8]);
      gload_lds16(Ht + (size_t)(n0 + row) * Kp + kb + kc * 8,
                  &Bs[(size_t)(it * 256 + w * 64) * 8]);
    }
    __syncthreads();
    bf16x8 af[4], bfr[4];
#pragma unroll
    for (int mi = 0; mi < 4; ++mi)
      af[mi]  = *(const bf16x8*)(&As[(wr * 64 + mi * 16 + llo) * 32 + lhi * 8]);
#pragma unroll
    for (int ni = 0; ni < 4; ++ni)
      bfr[ni] = *(const bf16x8*)(&Bs[(wc * 64 + ni * 16 + llo) * 32 + lhi * 8]);
#pragma unroll
    for (int mi = 0; mi < 4; ++mi)
#pragma unroll
      for (int ni = 0; ni < 4; ++ni)
        acc[mi][ni] = __builtin_amdgcn_mfma_f32_16x16x32_bf16(bfr[ni], af[mi], acc[mi][ni], 0, 0, 0);
    __syncthreads();
  }

  float* pz = part + (size_t)z * NTOK * ldo;
#pragma unroll
  for (int mi = 0; mi < 4; ++mi) {
    const int mg = m0 + wr * 64 + mi * 16 + llo;
#pragma unroll
    for (int ni = 0; ni < 4; ++ni) {
      const int ng = n0 + wc * 64 + ni * 16 + lhi * 4;
#pragma unroll
      for (int r = 0; r < 4; ++r)
        pz[(size_t)(ng + r) * ldo + mg] = acc[mi][ni][r];
    }
  }
}

// -------- split-K reduce + bias + ReLU -> bf16 [n][m] --------
__global__ __launch_bounds__(256)
void reduce_act(const float* __restrict__ part, const float* __restrict__ bias,
                unsigned short* __restrict__ out, int Mp, int Mreal, int nch) {
  const int i4 = blockIdx.x * 256 + threadIdx.x;
  const int total = NTOK * Mp / 4;
  if (i4 >= total) return;
  const size_t off = (size_t)i4 * 4;
  const int m0 = (int)(off % Mp);
  float s0 = 0.f, s1 = 0.f, s2 = 0.f, s3 = 0.f;
  for (int z = 0; z < nch; ++z) {
    const float4 v = *(const float4*)(part + (size_t)z * NTOK * Mp + off);
    s0 += v.x; s1 += v.y; s2 += v.z; s3 += v.w;
  }
  s0 += (m0 + 0 < Mreal) ? bias[m0 + 0] : 0.f;
  s1 += (m0 + 1 < Mreal) ? bias[m0 + 1] : 0.f;
  s2 += (m0 + 2 < Mreal) ? bias[m0 + 2] : 0.f;
  s3 += (m0 + 3 < Mreal) ? bias[m0 + 3] : 0.f;
  s0 = fmaxf(s0, 0.f); s1 = fmaxf(s1, 0.f); s2 = fmaxf(s2, 0.f); s3 = fmaxf(s3, 0.f);
  uint2 pk;
  pk.x = (unsigned)f2bf(s0) | ((unsigned)f2bf(s1) << 16);
  pk.y = (unsigned)f2bf(s2) | ((unsigned)f2bf(s3) << 16);
  *(uint2*)&out[off] = pk;
}

// -------- recompute fp32 DCT, multiply by mask, IDCT, write clean tiles (bf16) --------
__global__ __launch_bounds__(256)
void mask_idct(const float* __restrict__ x, const unsigned short* __restrict__ masks,
               unsigned short* __restrict__ clean) {
  __shared__ float Dm[256];   // D[k][m]
  __shared__ float Din[256];  // Di[n][k]
  __shared__ float patch[16 * 272];
  __shared__ float cd[16 * 272];
  const int tid = threadIdx.x;
  const int b   = blockIdx.y;
  const int c0  = blockIdx.x * 16;
  {
    const int k = tid >> 4, m = tid & 15;
    Dm[tid] = 2.f * cosf(PI_F * (float)((2 * m + 1) * k) / 32.f);
    const int n = tid >> 4, kk = tid & 15;
    Din[tid] = cosf(PI_F * (float)((2 * n + 1) * kk) / 32.f) * ((kk == 0) ? 0.5f : 1.f) * (1.f / 16.f);
  }
  __syncthreads();
  const int t = tid >> 4, q = tid & 15;
  const int c = c0 + t;
  const bool valid = (c < C0R);
  {
    float4 v0{}, v1{}, v2{}, v3{};
    if (valid) {
      const int ch = c % 3, gw = (c / 3) % GD, gh = c / (3 * GD);
      const float* xr = x + ((size_t)(b * 3 + ch) * INSZ + (gh * 4 + q)) * INSZ + gw * 4;
      v0 = *(const float4*)(xr);      v1 = *(const float4*)(xr + 4);
      v2 = *(const float4*)(xr + 8);  v3 = *(const float4*)(xr + 12);
    }
    float* pr = &patch[t * 272 + q * 17];
    pr[0]=v0.x; pr[1]=v0.y; pr[2]=v0.z; pr[3]=v0.w;
    pr[4]=v1.x; pr[5]=v1.y; pr[6]=v1.z; pr[7]=v1.w;
    pr[8]=v2.x; pr[9]=v2.y; pr[10]=v2.z; pr[11]=v2.w;
    pr[12]=v3.x; pr[13]=v3.y; pr[14]=v3.z; pr[15]=v3.w;
  }
  __syncthreads();
  float Drow[16];
#pragma unroll
  for (int m = 0; m < 16; ++m) Drow[m] = Dm[q * 16 + m];
  float tmpr[16];
#pragma unroll
  for (int n = 0; n < 16; ++n) tmpr[n] = 0.f;
#pragma unroll
  for (int m = 0; m < 16; ++m) {
    const float dm = Drow[m];
    const float* pr = &patch[t * 272 + m * 17];
#pragma unroll
    for (int n = 0; n < 16; ++n) tmpr[n] += dm * pr[n];
  }
  unsigned mu[8] = {0, 0, 0, 0, 0, 0, 0, 0};
  if (valid) {
    const uint4* mp = (const uint4*)(masks + (size_t)c * NTOK + (size_t)b * 256 + q * 16);
    uint4 a = mp[0], bb = mp[1];
    mu[0]=a.x; mu[1]=a.y; mu[2]=a.z; mu[3]=a.w;
    mu[4]=bb.x; mu[5]=bb.y; mu[6]=bb.z; mu[7]=bb.w;
  }
  float mrowf[16];
#pragma unroll
  for (int l = 0; l < 8; ++l) {
    mrowf[2 * l]     = bf2f((unsigned short)(mu[l] & 0xFFFFu));
    mrowf[2 * l + 1] = bf2f((unsigned short)(mu[l] >> 16));
  }
  float* cdr = &cd[t * 272 + q * 17];
#pragma unroll
  for (int l = 0; l < 16; ++l) {
    float s = 0.f;
#pragma unroll
    for (int n = 0; n < 16; ++n) s += tmpr[n] * Dm[l * 16 + n];
    cdr[l] = s * mrowf[l];
  }
  __syncthreads();
  float Dirow[16];
#pragma unroll
  for (int k = 0; k < 16; ++k) Dirow[k] = Din[q * 16 + k];
  float t2r[16];
#pragma unroll
  for (int l = 0; l < 16; ++l) t2r[l] = 0.f;
#pragma unroll
  for (int k = 0; k < 16; ++k) {
    const float dk = Dirow[k];
    const float* cdk = &cd[t * 272 + k * 17];
#pragma unroll
    for (int l = 0; l < 16; ++l) t2r[l] += dk * cdk[l];
  }
  if (valid) {
    float orow[16];
#pragma unroll
    for (int np = 0; np < 16; ++np) {
      float s = 0.f;
#pragma unroll
      for (int l = 0; l < 16; ++l) s += t2r[l] * Din[np * 16 + l];
      orow[np] = s;
    }
    unsigned pk[8];
#pragma unroll
    for (int l = 0; l < 8; ++l)
      pk[l] = (unsigned)f2bf(orow[2 * l]) | ((unsigned)f2bf(orow[2 * l + 1]) << 16);
    unsigned short* dst = clean + ((size_t)b * C0R + c) * 256 + q * 16;
    uint4* d4 = (uint4*)dst;
    d4[0] = make_uint4(pk[0], pk[1], pk[2], pk[3]);
    d4[1] = make_uint4(pk[4], pk[5], pk[6], pk[7]);
  }
}

// -------- overlap-add gather + count normalization --------
__global__ void overlap_add(const unsigned short* __restrict__ clean, float* __restrict__ out) {
  const int px = blockIdx.x * 256 + threadIdx.x;
  if (px >= 8 * 3 * 224 * 224) return;
  const int j = px % 224;
  const int i = (px / 224) % 224;
  const int bc = px / (224 * 224);
  const int ch = bc % 3, b = bc / 3;
  const int ilo = i - 15;
  const int ghlo = ilo > 0 ? (ilo + 3) >> 2 : 0;
  const int ghhi = (i >> 2) < 52 ? (i >> 2) : 52;
  const int jlo = j - 15;
  const int gwlo = jlo > 0 ? (jlo + 3) >> 2 : 0;
  const int gwhi = (j >> 2) < 52 ? (j >> 2) : 52;
  float sum = 0.f;
  for (int gh = ghlo; gh <= ghhi; ++gh) {
    const int r = i - gh * 4;
    const size_t base = ((size_t)b * C0R + (size_t)gh * (3 * GD) + ch) * 256 + (size_t)r * 16 + j;
    for (int gw = gwlo; gw <= gwhi; ++gw) {
      sum += bf2f(clean[base + (size_t)gw * 764]); // +gw*3*256 - 4*gw
    }
  }
  const int cnt = (ghhi - ghlo + 1) * (gwhi - gwlo + 1);
  out[px] = sum / (float)cnt;
}

extern "C" void kernel_launch(void* const* d_in, const int* in_sizes, int n_in,
                              void* d_out, int out_size, void* d_ws, size_t ws_size,
                              hipStream_t stream) {
  const float* x  = (const float*)d_in[0];
  const float* w1 = (const float*)d_in[1];
  const float* b1 = (const float*)d_in[2];
  const float* w2 = (const float*)d_in[3];
  const float* b2 = (const float*)d_in[4];
  const float* w3 = (const float*)d_in[5];
  const float* b3 = (const float*)d_in[6];
  const float* w4 = (const float*)d_in[7];
  const float* b4 = (const float*)d_in[8];
  float* out = (float*)d_out;
  char* ws = (char*)d_ws;

  // ---- workspace layout (peak 133.8 MB) ----
  const size_t S_WB1  = (size_t)C1P * C0P * 2;       // 36,765,696
  const size_t S_H0   = (size_t)NTOK * C0P * 2;      // 34,603,008
  const size_t S_PART = (size_t)3 * NTOK * C1P * 4;  // 53,477,376
  const size_t OFF_WB1  = 0;
  const size_t OFF_H0   = OFF_WB1 + S_WB1;
  const size_t OFF_PART = OFF_H0 + S_H0;
  const size_t OFF_Y1   = OFF_PART + S_PART;

  unsigned short* wb1 = (unsigned short*)(ws + OFF_WB1);
  unsigned short* H0v = (unsigned short*)(ws + OFF_H0);
  float*          pt1 = (float*)(ws + OFF_PART);
  unsigned short* Y1  = (unsigned short*)(ws + OFF_Y1);
  // aliases after reduce1 (PART slot): wb2, wb3, wb4, Y2
  unsigned short* wb2 = (unsigned short*)(ws + OFF_PART);
  unsigned short* wb3 = (unsigned short*)(ws + OFF_PART + (size_t)C2P * C1P * 2);
  unsigned short* wb4 = (unsigned short*)(ws + OFF_PART + (size_t)2 * C2P * C1P * 2);
  unsigned short* Y2  = (unsigned short*)(ws + OFF_PART + (size_t)2 * C2P * C1P * 2 + (size_t)C0P * C1P * 2);
  // aliases in WB1 slot: part2 (21.0MB), part3 (35.7MB), clean bf16 (34.5MB)
  float*          pt2 = (float*)(ws + OFF_WB1);
  float*          pt3 = (float*)(ws + OFF_WB1);
  unsigned short* clean = (unsigned short*)(ws + OFF_WB1);
  // Y3 reuses Y1 slot (Y1 dead after GEMM2); masks reuse H0 slot
  unsigned short* Y3  = (unsigned short*)(ws + OFF_Y1);
  unsigned short* msk = (unsigned short*)(ws + OFF_H0);

  // 1. stage inputs for GEMM1
  cvt_pad<<<dim3((C0P + 255) / 256, C1P), 256, 0, stream>>>(w1, wb1, C1R, C0R, C0P);
  dct_h0<<<dim3(C0P / 64, 8), 256, 0, stream>>>(x, H0v);

  // 2. GEMM1 split-K x3 (chunk 2816), reduce -> Y1
  gemm_splitk<<<dim3(C1P / 128, NTOK / 128, 3), 256, 0, stream>>>(wb1, H0v, pt1, C1P, C0P, 2816);
  reduce_act<<<dim3(NTOK * C1P / 4 / 256), 256, 0, stream>>>(pt1, b1, Y1, C1P, C1R, 3);

  // 3. remaining weight conversions (into dead PART slot)
  cvt_pad<<<dim3((C1P + 255) / 256, C2P), 256, 0, stream>>>(w2, wb2, C2R, C1R, C1P);
  cvt_pad<<<dim3((C2P + 255) / 256, C1P), 256, 0, stream>>>(w3, wb3, C1R, C2R, C2P);
  cvt_pad<<<dim3((C1P + 255) / 256, C0P), 256, 0, stream>>>(w4, wb4, C0R, C1R, C1P);

  // 4. GEMM2 split-K x4 (chunk 544) -> Y2
  gemm_splitk<<<dim3(C2P / 128, NTOK / 128, 4), 256, 0, stream>>>(wb2, Y1, pt2, C2P, C1P, 544);
  reduce_act<<<dim3(NTOK * C2P / 4 / 256), 256, 0, stream>>>(pt2, b2, Y2, C2P, C2R, 4);

  // 5. GEMM3 split-K x2 (chunk 320) -> Y3 (Y1 slot)
  gemm_splitk<<<dim3(C1P / 128, NTOK / 128, 2), 256, 0, stream>>>(wb3, Y2, pt3, C1P, C2P, 320);
  reduce_act<<<dim3(NTOK * C1P / 4 / 256), 256, 0, stream>>>(pt3, b3, Y3, C1P, C1R, 2);

  // 6. GEMM4 direct (sigmoid, out [m][n]) -> masks (H0 slot)
  gemm_bt<2, 0><<<dim3(C0P / 128, NTOK / 128), 256, 0, stream>>>(wb4, Y3, b4, C0R, msk, NTOK, C1P);

  // 7. mask*DCT -> IDCT -> clean (bf16, WB1 slot)
  mask_idct<<<dim3((C0R + 15) / 16, 8), 256, 0, stream>>>(x, msk, clean);

  // 8. overlap-add + normalize
  overlap_add<<<dim3((8 * 3 * 224 * 224 + 255) / 256), 256, 0, stream>>>(clean, out);
}

// Round 3
// 597.440 us; speedup vs baseline: 1.1895x; 1.0984x over previous
//
#include <hip/hip_runtime.h>
#include <stdint.h>

#define PI_F 3.14159265358979323846f

constexpr int INSZ = 224;
constexpr int GD   = 53;
constexpr int C0R = 8427, C1R = 2106, C2R = 526;
constexpr int C0P = 8448, C1P = 2176, C2P = 640;
constexpr int NTOK = 2048; // 8 batches * 256 DCT positions

typedef __attribute__((ext_vector_type(4))) float f32x4;
typedef __attribute__((ext_vector_type(8))) short bf16x8;

__device__ __forceinline__ unsigned short f2bf(float f) {
  union { float f; unsigned u; } v; v.f = f;
  return (unsigned short)((v.u + 0x7FFFu + ((v.u >> 16) & 1u)) >> 16);
}
__device__ __forceinline__ float bf2f(unsigned short b) {
  union { unsigned u; float f; } v; v.u = ((unsigned)b) << 16;
  return v.f;
}

// global -> LDS async copy, 16B per lane; LDS dest is wave-uniform base + lane*16
__device__ __forceinline__ void gload_lds16(const void* g, void* l) {
  __builtin_amdgcn_global_load_lds(
      (__attribute__((address_space(1))) unsigned int*)(uintptr_t)g,
      (__attribute__((address_space(3))) unsigned int*)(unsigned int)(uintptr_t)l,
      16, 0, 0);
}

// XCD-aware block swizzle over the (x,y) grid; requires (gx*gy)%8==0
__device__ __forceinline__ void xcd_swz(int& bx, int& by) {
  const int gx = gridDim.x, gy = gridDim.y;
  const int nwg = gx * gy;
  const int bid = blockIdx.y * gx + blockIdx.x;
  const int cpx = nwg >> 3;
  const int swz = (bid & 7) * cpx + (bid >> 3);
  bx = swz % gx;
  by = swz / gx;
}

// -------- weight fp32 -> bf16 with zero padding --------
__global__ void cvt_pad(const float* __restrict__ src, unsigned short* __restrict__ dst,
                        int M, int K, int Kp) {
  const int k = blockIdx.x * 256 + threadIdx.x;
  const int m = blockIdx.y;
  if (k >= Kp) return;
  const float v = (m < M && k < K) ? src[(size_t)m * K + k] : 0.f;
  dst[(size_t)m * Kp + k] = f2bf(v);
}

// -------- DCT: x -> H0 bf16 [n=2048][c=8448]  (h = dct/256) --------
__global__ __launch_bounds__(256)
void dct_h0(const float* __restrict__ x, unsigned short* __restrict__ H0) {
  __shared__ float Dm[256];               // D[k][m] = 2*cos(pi*(2m+1)k/32)
  __shared__ float patch[16 * 272];       // [tile][row][17] padded
  __shared__ unsigned short hst[256 * 64];// [kl][tile_local]
  const int tid = threadIdx.x;
  const int b   = blockIdx.y;
  const int c0  = blockIdx.x * 64;
  {
    const int k = tid >> 4, m = tid & 15;
    Dm[tid] = 2.f * cosf(PI_F * (float)((2 * m + 1) * k) / 32.f);
  }
  __syncthreads();
  const int t = tid >> 4, q = tid & 15;
  float Drow[16];
#pragma unroll
  for (int m = 0; m < 16; ++m) Drow[m] = Dm[q * 16 + m];

  for (int g = 0; g < 4; ++g) {
    const int c = c0 + g * 16 + t;
    { // stage A: load row q of tile t's 16x16 patch
      float4 v0{}, v1{}, v2{}, v3{};
      if (c < C0R) {
        const int ch = c % 3, gw = (c / 3) % GD, gh = c / (3 * GD);
        const float* xr = x + ((size_t)(b * 3 + ch) * INSZ + (gh * 4 + q)) * INSZ + gw * 4;
        v0 = *(const float4*)(xr);      v1 = *(const float4*)(xr + 4);
        v2 = *(const float4*)(xr + 8);  v3 = *(const float4*)(xr + 12);
      }
      float* pr = &patch[t * 272 + q * 17];
      pr[0]=v0.x; pr[1]=v0.y; pr[2]=v0.z; pr[3]=v0.w;
      pr[4]=v1.x; pr[5]=v1.y; pr[6]=v1.z; pr[7]=v1.w;
      pr[8]=v2.x; pr[9]=v2.y; pr[10]=v2.z; pr[11]=v2.w;
      pr[12]=v3.x; pr[13]=v3.y; pr[14]=v3.z; pr[15]=v3.w;
    }
    __syncthreads();
    // stage B: tmpr[n] = sum_m D[q][m] * P[m][n]
    float tmpr[16];
#pragma unroll
    for (int n = 0; n < 16; ++n) tmpr[n] = 0.f;
#pragma unroll
    for (int m = 0; m < 16; ++m) {
      const float dm = Drow[m];
      const float* pr = &patch[t * 272 + m * 17];
#pragma unroll
      for (int n = 0; n < 16; ++n) tmpr[n] += dm * pr[n];
    }
    // stage C: dct[q][l] = sum_n tmpr[n]*D[l][n]; stage to LDS transposed
#pragma unroll
    for (int l = 0; l < 16; ++l) {
      float s = 0.f;
#pragma unroll
      for (int n = 0; n < 16; ++n) s += tmpr[n] * Dm[l * 16 + n];
      hst[(q * 16 + l) * 64 + g * 16 + t] = f2bf(s * (1.f / 256.f));
    }
    __syncthreads();
  }
  // write H0[n][c] as uint4 (16B per lane)
  const size_t base = ((size_t)b * 256) * C0P + c0;
#pragma unroll
  for (int i = 0; i < 8; ++i) {
    const int s = i * 256 + tid;        // 2048 uint4 stores total
    const int kl = s >> 3, c16 = s & 7;
    *(uint4*)&H0[base + (size_t)kl * C0P + c16 * 8] = *(const uint4*)&hst[kl * 64 + c16 * 8];
  }
}

// ======== shared GEMM core: 128x128 tile, BK=32, LDS dbuf + 2-phase pipeline,
// ======== XOR-swizzled LDS (stage-source + read, rule #21), one barrier/K-step.
// As/Bs: [2][128*32] shorts. Logical slot (row, c16) holds global chunk
// (row, c16 ^ ((row>>1)&3)); read applies the same XOR -> 2-way (free) banks.
template<int OUT_NM>
__device__ __forceinline__ void gemm_core(
    const unsigned short* __restrict__ W, const unsigned short* __restrict__ Ht,
    unsigned short (*As)[128 * 32], unsigned short (*Bs)[128 * 32],
    int m0, int n0, int Kp, int kbase, int nkt, int w, int lane, f32x4 acc[4][4]) {
  const int wr = w >> 1, wc = w & 1;
  const int lhi = lane >> 4, llo = lane & 15;

  // per-thread stage coords (2 chunks per matrix per K-step)
  const int chunk0 = w * 64 + lane;          // it=0
  const int row0 = chunk0 >> 2, kc0 = chunk0 & 3;
  const int kcg0 = kc0 ^ ((row0 >> 1) & 3);
  const int chunk1 = 256 + w * 64 + lane;    // it=1
  const int row1 = chunk1 >> 2, kc1 = chunk1 & 3;
  const int kcg1 = kc1 ^ ((row1 >> 1) & 3);

  auto STAGE = [&](int kt, int sel) {
    const int kb = kbase + kt * 32;
    gload_lds16(W  + (size_t)(m0 + row0) * Kp + kb + kcg0 * 8, &As[sel][(w * 64) * 8]);
    gload_lds16(Ht + (size_t)(n0 + row0) * Kp + kb + kcg0 * 8, &Bs[sel][(w * 64) * 8]);
    gload_lds16(W  + (size_t)(m0 + row1) * Kp + kb + kcg1 * 8, &As[sel][(256 + w * 64) * 8]);
    gload_lds16(Ht + (size_t)(n0 + row1) * Kp + kb + kcg1 * 8, &Bs[sel][(256 + w * 64) * 8]);
  };

  STAGE(0, 0);
  asm volatile("s_waitcnt vmcnt(0)" ::: "memory");
  __builtin_amdgcn_s_barrier();
  __builtin_amdgcn_sched_barrier(0);

  int sel = 0;
  for (int kt = 0; kt < nkt; ++kt) {
    if (kt + 1 < nkt) STAGE(kt + 1, sel ^ 1);
    bf16x8 af[4], bfr[4];
#pragma unroll
    for (int mi = 0; mi < 4; ++mi) {
      const int row = wr * 64 + mi * 16 + llo;
      af[mi] = *(const bf16x8*)(&As[sel][row * 32 + (lhi ^ ((row >> 1) & 3)) * 8]);
    }
#pragma unroll
    for (int ni = 0; ni < 4; ++ni) {
      const int row = wc * 64 + ni * 16 + llo;
      bfr[ni] = *(const bf16x8*)(&Bs[sel][row * 32 + (lhi ^ ((row >> 1) & 3)) * 8]);
    }
#pragma unroll
    for (int mi = 0; mi < 4; ++mi)
#pragma unroll
      for (int ni = 0; ni < 4; ++ni) {
        if (OUT_NM)
          acc[mi][ni] = __builtin_amdgcn_mfma_f32_16x16x32_bf16(bfr[ni], af[mi], acc[mi][ni], 0, 0, 0);
        else
          acc[mi][ni] = __builtin_amdgcn_mfma_f32_16x16x32_bf16(af[mi], bfr[ni], acc[mi][ni], 0, 0, 0);
      }
    asm volatile("s_waitcnt vmcnt(0)" ::: "memory");
    __builtin_amdgcn_s_barrier();
    __builtin_amdgcn_sched_barrier(0);
    sel ^= 1;
  }
}

// -------- direct GEMM with fused epilogue --------
template<int ACT, int OUT_NM>
__global__ __launch_bounds__(256)
void gemm_bt(const unsigned short* __restrict__ W, const unsigned short* __restrict__ Ht,
             const float* __restrict__ bias, int Mreal,
             unsigned short* __restrict__ out, int ldo, int Kp) {
  __shared__ unsigned short As[2][128 * 32];
  __shared__ unsigned short Bs[2][128 * 32];
  int bx, by; xcd_swz(bx, by);
  const int tid = threadIdx.x;
  const int w = tid >> 6, lane = tid & 63;
  const int m0 = bx * 128, n0 = by * 128;
  const int wr = w >> 1, wc = w & 1;
  const int lhi = lane >> 4, llo = lane & 15;

  f32x4 acc[4][4];
#pragma unroll
  for (int i = 0; i < 4; ++i)
#pragma unroll
    for (int j = 0; j < 4; ++j) acc[i][j] = f32x4{0.f, 0.f, 0.f, 0.f};

  gemm_core<OUT_NM>(W, Ht, As, Bs, m0, n0, Kp, 0, Kp >> 5, w, lane, acc);

  if (OUT_NM) {
#pragma unroll
    for (int mi = 0; mi < 4; ++mi) {
      const int mg = m0 + wr * 64 + mi * 16 + llo;
      const float bv = (mg < Mreal) ? bias[mg] : 0.f;
#pragma unroll
      for (int ni = 0; ni < 4; ++ni) {
        const int ng = n0 + wc * 64 + ni * 16 + lhi * 4;
#pragma unroll
        for (int r = 0; r < 4; ++r) {
          float v = acc[mi][ni][r] + bv;
          if (ACT == 1) v = fmaxf(v, 0.f);
          else if (ACT == 2) v = 1.f / (1.f + expf(-v));
          out[(size_t)(ng + r) * ldo + mg] = f2bf(v);
        }
      }
    }
  } else {
#pragma unroll
    for (int mi = 0; mi < 4; ++mi) {
      const int mgb = m0 + wr * 64 + mi * 16 + lhi * 4;
#pragma unroll
      for (int ni = 0; ni < 4; ++ni) {
        const int ng = n0 + wc * 64 + ni * 16 + llo;
#pragma unroll
        for (int r = 0; r < 4; ++r) {
          const int mg = mgb + r;
          float v = acc[mi][ni][r] + ((mg < Mreal) ? bias[mg] : 0.f);
          if (ACT == 1) v = fmaxf(v, 0.f);
          else if (ACT == 2) v = 1.f / (1.f + expf(-v));
          out[(size_t)mg * ldo + ng] = f2bf(v);
        }
      }
    }
  }
}

// -------- split-K GEMM: fp32 partials, no epilogue; chunk = blockIdx.z --------
__global__ __launch_bounds__(256)
void gemm_splitk(const unsigned short* __restrict__ W, const unsigned short* __restrict__ Ht,
                 float* __restrict__ part, int ldo /*Mp*/, int Kp, int chunkK) {
  __shared__ unsigned short As[2][128 * 32];
  __shared__ unsigned short Bs[2][128 * 32];
  int bx, by; xcd_swz(bx, by);
  const int z = blockIdx.z;
  const int tid = threadIdx.x;
  const int w = tid >> 6, lane = tid & 63;
  const int m0 = bx * 128, n0 = by * 128;
  const int wr = w >> 1, wc = w & 1;
  const int lhi = lane >> 4, llo = lane & 15;

  f32x4 acc[4][4];
#pragma unroll
  for (int i = 0; i < 4; ++i)
#pragma unroll
    for (int j = 0; j < 4; ++j) acc[i][j] = f32x4{0.f, 0.f, 0.f, 0.f};

  gemm_core<1>(W, Ht, As, Bs, m0, n0, Kp, z * chunkK, chunkK >> 5, w, lane, acc);

  float* pz = part + (size_t)z * NTOK * ldo;
#pragma unroll
  for (int mi = 0; mi < 4; ++mi) {
    const int mg = m0 + wr * 64 + mi * 16 + llo;
#pragma unroll
    for (int ni = 0; ni < 4; ++ni) {
      const int ng = n0 + wc * 64 + ni * 16 + lhi * 4;
#pragma unroll
      for (int r = 0; r < 4; ++r)
        pz[(size_t)(ng + r) * ldo + mg] = acc[mi][ni][r];
    }
  }
}

// -------- split-K reduce + bias + ReLU -> bf16 [n][m] --------
__global__ __launch_bounds__(256)
void reduce_act(const float* __restrict__ part, const float* __restrict__ bias,
                unsigned short* __restrict__ out, int Mp, int Mreal, int nch) {
  const int i4 = blockIdx.x * 256 + threadIdx.x;
  const int total = NTOK * Mp / 4;
  if (i4 >= total) return;
  const size_t off = (size_t)i4 * 4;
  const int m0 = (int)(off % Mp);
  float s0 = 0.f, s1 = 0.f, s2 = 0.f, s3 = 0.f;
  for (int z = 0; z < nch; ++z) {
    const float4 v = *(const float4*)(part + (size_t)z * NTOK * Mp + off);
    s0 += v.x; s1 += v.y; s2 += v.z; s3 += v.w;
  }
  s0 += (m0 + 0 < Mreal) ? bias[m0 + 0] : 0.f;
  s1 += (m0 + 1 < Mreal) ? bias[m0 + 1] : 0.f;
  s2 += (m0 + 2 < Mreal) ? bias[m0 + 2] : 0.f;
  s3 += (m0 + 3 < Mreal) ? bias[m0 + 3] : 0.f;
  s0 = fmaxf(s0, 0.f); s1 = fmaxf(s1, 0.f); s2 = fmaxf(s2, 0.f); s3 = fmaxf(s3, 0.f);
  uint2 pk;
  pk.x = (unsigned)f2bf(s0) | ((unsigned)f2bf(s1) << 16);
  pk.y = (unsigned)f2bf(s2) | ((unsigned)f2bf(s3) << 16);
  *(uint2*)&out[off] = pk;
}

// -------- recompute fp32 DCT, multiply by mask, IDCT, write clean tiles (bf16) --------
__global__ __launch_bounds__(256)
void mask_idct(const float* __restrict__ x, const unsigned short* __restrict__ masks,
               unsigned short* __restrict__ clean) {
  __shared__ float Dm[256];   // D[k][m]
  __shared__ float Din[256];  // Di[n][k]
  __shared__ float patch[16 * 272];
  __shared__ float cd[16 * 272];
  const int tid = threadIdx.x;
  const int b   = blockIdx.y;
  const int c0  = blockIdx.x * 16;
  {
    const int k = tid >> 4, m = tid & 15;
    Dm[tid] = 2.f * cosf(PI_F * (float)((2 * m + 1) * k) / 32.f);
    const int n = tid >> 4, kk = tid & 15;
    Din[tid] = cosf(PI_F * (float)((2 * n + 1) * kk) / 32.f) * ((kk == 0) ? 0.5f : 1.f) * (1.f / 16.f);
  }
  __syncthreads();
  const int t = tid >> 4, q = tid & 15;
  const int c = c0 + t;
  const bool valid = (c < C0R);
  {
    float4 v0{}, v1{}, v2{}, v3{};
    if (valid) {
      const int ch = c % 3, gw = (c / 3) % GD, gh = c / (3 * GD);
      const float* xr = x + ((size_t)(b * 3 + ch) * INSZ + (gh * 4 + q)) * INSZ + gw * 4;
      v0 = *(const float4*)(xr);      v1 = *(const float4*)(xr + 4);
      v2 = *(const float4*)(xr + 8);  v3 = *(const float4*)(xr + 12);
    }
    float* pr = &patch[t * 272 + q * 17];
    pr[0]=v0.x; pr[1]=v0.y; pr[2]=v0.z; pr[3]=v0.w;
    pr[4]=v1.x; pr[5]=v1.y; pr[6]=v1.z; pr[7]=v1.w;
    pr[8]=v2.x; pr[9]=v2.y; pr[10]=v2.z; pr[11]=v2.w;
    pr[12]=v3.x; pr[13]=v3.y; pr[14]=v3.z; pr[15]=v3.w;
  }
  __syncthreads();
  float Drow[16];
#pragma unroll
  for (int m = 0; m < 16; ++m) Drow[m] = Dm[q * 16 + m];
  float tmpr[16];
#pragma unroll
  for (int n = 0; n < 16; ++n) tmpr[n] = 0.f;
#pragma unroll
  for (int m = 0; m < 16; ++m) {
    const float dm = Drow[m];
    const float* pr = &patch[t * 272 + m * 17];
#pragma unroll
    for (int n = 0; n < 16; ++n) tmpr[n] += dm * pr[n];
  }
  unsigned mu[8] = {0, 0, 0, 0, 0, 0, 0, 0};
  if (valid) {
    const uint4* mp = (const uint4*)(masks + (size_t)c * NTOK + (size_t)b * 256 + q * 16);
    uint4 a = mp[0], bb = mp[1];
    mu[0]=a.x; mu[1]=a.y; mu[2]=a.z; mu[3]=a.w;
    mu[4]=bb.x; mu[5]=bb.y; mu[6]=bb.z; mu[7]=bb.w;
  }
  float mrowf[16];
#pragma unroll
  for (int l = 0; l < 8; ++l) {
    mrowf[2 * l]     = bf2f((unsigned short)(mu[l] & 0xFFFFu));
    mrowf[2 * l + 1] = bf2f((unsigned short)(mu[l] >> 16));
  }
  float* cdr = &cd[t * 272 + q * 17];
#pragma unroll
  for (int l = 0; l < 16; ++l) {
    float s = 0.f;
#pragma unroll
    for (int n = 0; n < 16; ++n) s += tmpr[n] * Dm[l * 16 + n];
    cdr[l] = s * mrowf[l];
  }
  __syncthreads();
  float Dirow[16];
#pragma unroll
  for (int k = 0; k < 16; ++k) Dirow[k] = Din[q * 16 + k];
  float t2r[16];
#pragma unroll
  for (int l = 0; l < 16; ++l) t2r[l] = 0.f;
#pragma unroll
  for (int k = 0; k < 16; ++k) {
    const float dk = Dirow[k];
    const float* cdk = &cd[t * 272 + k * 17];
#pragma unroll
    for (int l = 0; l < 16; ++l) t2r[l] += dk * cdk[l];
  }
  if (valid) {
    float orow[16];
#pragma unroll
    for (int np = 0; np < 16; ++np) {
      float s = 0.f;
#pragma unroll
      for (int l = 0; l < 16; ++l) s += t2r[l] * Din[np * 16 + l];
      orow[np] = s;
    }
    unsigned pk[8];
#pragma unroll
    for (int l = 0; l < 8; ++l)
      pk[l] = (unsigned)f2bf(orow[2 * l]) | ((unsigned)f2bf(orow[2 * l + 1]) << 16);
    unsigned short* dst = clean + ((size_t)b * C0R + c) * 256 + q * 16;
    uint4* d4 = (uint4*)dst;
    d4[0] = make_uint4(pk[0], pk[1], pk[2], pk[3]);
    d4[1] = make_uint4(pk[4], pk[5], pk[6], pk[7]);
  }
}

// -------- overlap-add gather + count normalization --------
__global__ void overlap_add(const unsigned short* __restrict__ clean, float* __restrict__ out) {
  const int px = blockIdx.x * 256 + threadIdx.x;
  if (px >= 8 * 3 * 224 * 224) return;
  const int j = px % 224;
  const int i = (px / 224) % 224;
  const int bc = px / (224 * 224);
  const int ch = bc % 3, b = bc / 3;
  const int ilo = i - 15;
  const int ghlo = ilo > 0 ? (ilo + 3) >> 2 : 0;
  const int ghhi = (i >> 2) < 52 ? (i >> 2) : 52;
  const int jlo = j - 15;
  const int gwlo = jlo > 0 ? (jlo + 3) >> 2 : 0;
  const int gwhi = (j >> 2) < 52 ? (j >> 2) : 52;
  float sum = 0.f;
  for (int gh = ghlo; gh <= ghhi; ++gh) {
    const int r = i - gh * 4;
    const size_t base = ((size_t)b * C0R + (size_t)gh * (3 * GD) + ch) * 256 + (size_t)r * 16 + j;
    for (int gw = gwlo; gw <= gwhi; ++gw) {
      sum += bf2f(clean[base + (size_t)gw * 764]); // +gw*3*256 - 4*gw
    }
  }
  const int cnt = (ghhi - ghlo + 1) * (gwhi - gwlo + 1);
  out[px] = sum / (float)cnt;
}

extern "C" void kernel_launch(void* const* d_in, const int* in_sizes, int n_in,
                              void* d_out, int out_size, void* d_ws, size_t ws_size,
                              hipStream_t stream) {
  const float* x  = (const float*)d_in[0];
  const float* w1 = (const float*)d_in[1];
  const float* b1 = (const float*)d_in[2];
  const float* w2 = (const float*)d_in[3];
  const float* b2 = (const float*)d_in[4];
  const float* w3 = (const float*)d_in[5];
  const float* b3 = (const float*)d_in[6];
  const float* w4 = (const float*)d_in[7];
  const float* b4 = (const float*)d_in[8];
  float* out = (float*)d_out;
  char* ws = (char*)d_ws;

  // ---- workspace layout (peak 133.8 MB) ----
  const size_t S_WB1  = (size_t)C1P * C0P * 2;       // 36,765,696
  const size_t S_H0   = (size_t)NTOK * C0P * 2;      // 34,603,008
  const size_t S_PART = (size_t)3 * NTOK * C1P * 4;  // 53,477,376
  const size_t OFF_WB1  = 0;
  const size_t OFF_H0   = OFF_WB1 + S_WB1;
  const size_t OFF_PART = OFF_H0 + S_H0;
  const size_t OFF_Y1   = OFF_PART + S_PART;

  unsigned short* wb1 = (unsigned short*)(ws + OFF_WB1);
  unsigned short* H0v = (unsigned short*)(ws + OFF_H0);
  float*          pt1 = (float*)(ws + OFF_PART);
  unsigned short* Y1  = (unsigned short*)(ws + OFF_Y1);
  // aliases after reduce1 (PART slot): wb2, wb3, wb4, Y2
  unsigned short* wb2 = (unsigned short*)(ws + OFF_PART);
  unsigned short* wb3 = (unsigned short*)(ws + OFF_PART + (size_t)C2P * C1P * 2);
  unsigned short* wb4 = (unsigned short*)(ws + OFF_PART + (size_t)2 * C2P * C1P * 2);
  unsigned short* Y2  = (unsigned short*)(ws + OFF_PART + (size_t)2 * C2P * C1P * 2 + (size_t)C0P * C1P * 2);
  // aliases in WB1 slot: part2 (21.0MB), part3 (35.7MB), clean bf16 (34.5MB)
  float*          pt2 = (float*)(ws + OFF_WB1);
  float*          pt3 = (float*)(ws + OFF_WB1);
  unsigned short* clean = (unsigned short*)(ws + OFF_WB1);
  // Y3 reuses Y1 slot (Y1 dead after GEMM2); masks reuse H0 slot
  unsigned short* Y3  = (unsigned short*)(ws + OFF_Y1);
  unsigned short* msk = (unsigned short*)(ws + OFF_H0);

  // 1. stage inputs for GEMM1
  cvt_pad<<<dim3((C0P + 255) / 256, C1P), 256, 0, stream>>>(w1, wb1, C1R, C0R, C0P);
  dct_h0<<<dim3(C0P / 64, 8), 256, 0, stream>>>(x, H0v);

  // 2. GEMM1 split-K x3 (chunk 2816), reduce -> Y1
  gemm_splitk<<<dim3(C1P / 128, NTOK / 128, 3), 256, 0, stream>>>(wb1, H0v, pt1, C1P, C0P, 2816);
  reduce_act<<<dim3(NTOK * C1P / 4 / 256), 256, 0, stream>>>(pt1, b1, Y1, C1P, C1R, 3);

  // 3. remaining weight conversions (into dead PART slot)
  cvt_pad<<<dim3((C1P + 255) / 256, C2P), 256, 0, stream>>>(w2, wb2, C2R, C1R, C1P);
  cvt_pad<<<dim3((C2P + 255) / 256, C1P), 256, 0, stream>>>(w3, wb3, C1R, C2R, C2P);
  cvt_pad<<<dim3((C1P + 255) / 256, C0P), 256, 0, stream>>>(w4, wb4, C0R, C1R, C1P);

  // 4. GEMM2 split-K x4 (chunk 544) -> Y2
  gemm_splitk<<<dim3(C2P / 128, NTOK / 128, 4), 256, 0, stream>>>(wb2, Y1, pt2, C2P, C1P, 544);
  reduce_act<<<dim3(NTOK * C2P / 4 / 256), 256, 0, stream>>>(pt2, b2, Y2, C2P, C2R, 4);

  // 5. GEMM3 split-K x2 (chunk 320) -> Y3 (Y1 slot)
  gemm_splitk<<<dim3(C1P / 128, NTOK / 128, 2), 256, 0, stream>>>(wb3, Y2, pt3, C1P, C2P, 320);
  reduce_act<<<dim3(NTOK * C1P / 4 / 256), 256, 0, stream>>>(pt3, b3, Y3, C1P, C1R, 2);

  // 6. GEMM4 direct (sigmoid, out [m][n]) -> masks (H0 slot)
  gemm_bt<2, 0><<<dim3(C0P / 128, NTOK / 128), 256, 0, stream>>>(wb4, Y3, b4, C0R, msk, NTOK, C1P);

  // 7. mask*DCT -> IDCT -> clean (bf16, WB1 slot)
  mask_idct<<<dim3((C0R + 15) / 16, 8), 256, 0, stream>>>(x, msk, clean);

  // 8. overlap-add + normalize
  overlap_add<<<dim3((8 * 3 * 224 * 224 + 255) / 256), 256, 0, stream>>>(clean, out);
}

// Round 4
// 579.840 us; speedup vs baseline: 1.2256x; 1.0304x over previous
//
#include <hip/hip_runtime.h>
#include <stdint.h>

#define PI_F 3.14159265358979323846f

constexpr int INSZ = 224;
constexpr int GD   = 53;
constexpr int C0R = 8427, C1R = 2106, C2R = 526;
constexpr int C0P = 8448, C1P = 2176, C2P = 640;
constexpr int NTOK = 2048; // 8 batches * 256 DCT positions

typedef __attribute__((ext_vector_type(4))) float f32x4;
typedef __attribute__((ext_vector_type(8))) short bf16x8;

__device__ __forceinline__ unsigned short f2bf(float f) {
  union { float f; unsigned u; } v; v.f = f;
  return (unsigned short)((v.u + 0x7FFFu + ((v.u >> 16) & 1u)) >> 16);
}
__device__ __forceinline__ float bf2f(unsigned short b) {
  union { unsigned u; float f; } v; v.u = ((unsigned)b) << 16;
  return v.f;
}

// global -> LDS async copy, 16B per lane; LDS dest is wave-uniform base + lane*16
__device__ __forceinline__ void gload_lds16(const void* g, void* l) {
  __builtin_amdgcn_global_load_lds(
      (__attribute__((address_space(1))) unsigned int*)(uintptr_t)g,
      (__attribute__((address_space(3))) unsigned int*)(unsigned int)(uintptr_t)l,
      16, 0, 0);
}

// XCD-aware block swizzle, n-fastest within each XCD chunk (L2 panel locality):
// each XCD gets a contiguous logical range walking by (N) fastest, so its
// A-panel footprint is ~gx/8 M-tiles instead of all of them. requires (gx*gy)%8==0
__device__ __forceinline__ void xcd_swz(int& bx, int& by) {
  const int gx = gridDim.x, gy = gridDim.y;
  const int nwg = gx * gy;
  const int bid = blockIdx.y * gx + blockIdx.x;
  const int cpx = nwg >> 3;
  const int swz = (bid & 7) * cpx + (bid >> 3);
  by = swz % gy;
  bx = swz / gy;
}

// -------- weight fp32 -> bf16 with zero padding --------
__global__ void cvt_pad(const float* __restrict__ src, unsigned short* __restrict__ dst,
                        int M, int K, int Kp) {
  const int k = blockIdx.x * 256 + threadIdx.x;
  const int m = blockIdx.y;
  if (k >= Kp) return;
  const float v = (m < M && k < K) ? src[(size_t)m * K + k] : 0.f;
  dst[(size_t)m * Kp + k] = f2bf(v);
}

// -------- DCT: x -> H0 bf16 [n=2048][c=8448]  (h = dct/256) --------
__global__ __launch_bounds__(256)
void dct_h0(const float* __restrict__ x, unsigned short* __restrict__ H0) {
  __shared__ float Dm[256];               // D[k][m] = 2*cos(pi*(2m+1)k/32)
  __shared__ float patch[16 * 272];       // [tile][row][17] padded
  __shared__ unsigned short hst[256 * 64];// [kl][tile_local]
  const int tid = threadIdx.x;
  const int b   = blockIdx.y;
  const int c0  = blockIdx.x * 64;
  {
    const int k = tid >> 4, m = tid & 15;
    Dm[tid] = 2.f * cosf(PI_F * (float)((2 * m + 1) * k) / 32.f);
  }
  __syncthreads();
  const int t = tid >> 4, q = tid & 15;
  float Drow[16];
#pragma unroll
  for (int m = 0; m < 16; ++m) Drow[m] = Dm[q * 16 + m];

  for (int g = 0; g < 4; ++g) {
    const int c = c0 + g * 16 + t;
    { // stage A: load row q of tile t's 16x16 patch
      float4 v0{}, v1{}, v2{}, v3{};
      if (c < C0R) {
        const int ch = c % 3, gw = (c / 3) % GD, gh = c / (3 * GD);
        const float* xr = x + ((size_t)(b * 3 + ch) * INSZ + (gh * 4 + q)) * INSZ + gw * 4;
        v0 = *(const float4*)(xr);      v1 = *(const float4*)(xr + 4);
        v2 = *(const float4*)(xr + 8);  v3 = *(const float4*)(xr + 12);
      }
      float* pr = &patch[t * 272 + q * 17];
      pr[0]=v0.x; pr[1]=v0.y; pr[2]=v0.z; pr[3]=v0.w;
      pr[4]=v1.x; pr[5]=v1.y; pr[6]=v1.z; pr[7]=v1.w;
      pr[8]=v2.x; pr[9]=v2.y; pr[10]=v2.z; pr[11]=v2.w;
      pr[12]=v3.x; pr[13]=v3.y; pr[14]=v3.z; pr[15]=v3.w;
    }
    __syncthreads();
    // stage B: tmpr[n] = sum_m D[q][m] * P[m][n]
    float tmpr[16];
#pragma unroll
    for (int n = 0; n < 16; ++n) tmpr[n] = 0.f;
#pragma unroll
    for (int m = 0; m < 16; ++m) {
      const float dm = Drow[m];
      const float* pr = &patch[t * 272 + m * 17];
#pragma unroll
      for (int n = 0; n < 16; ++n) tmpr[n] += dm * pr[n];
    }
    // stage C: dct[q][l] = sum_n tmpr[n]*D[l][n]; stage to LDS transposed
#pragma unroll
    for (int l = 0; l < 16; ++l) {
      float s = 0.f;
#pragma unroll
      for (int n = 0; n < 16; ++n) s += tmpr[n] * Dm[l * 16 + n];
      hst[(q * 16 + l) * 64 + g * 16 + t] = f2bf(s * (1.f / 256.f));
    }
    __syncthreads();
  }
  // write H0[n][c] as uint4 (16B per lane)
  const size_t base = ((size_t)b * 256) * C0P + c0;
#pragma unroll
  for (int i = 0; i < 8; ++i) {
    const int s = i * 256 + tid;        // 2048 uint4 stores total
    const int kl = s >> 3, c16 = s & 7;
    *(uint4*)&H0[base + (size_t)kl * C0P + c16 * 8] = *(const uint4*)&hst[kl * 64 + c16 * 8];
  }
}

// ======== shared GEMM core: 128x128 tile, BK=32, TRIPLE-buffered LDS,
// ======== depth-2 prefetch with counted vmcnt (T4: never vmcnt(0) in main loop),
// ======== XOR-swizzled LDS both-sides (rule #21), one barrier per K-step.
template<int OUT_NM>
__device__ __forceinline__ void gemm_core(
    const unsigned short* __restrict__ W, const unsigned short* __restrict__ Ht,
    unsigned short (*As)[128 * 32], unsigned short (*Bs)[128 * 32],
    int m0, int n0, int Kp, int kbase, int nkt, int w, int lane, f32x4 acc[4][4]) {
  const int wr = w >> 1, wc = w & 1;
  const int lhi = lane >> 4, llo = lane & 15;

  // per-thread stage coords (2 chunks per matrix per K-step)
  const int chunk0 = w * 64 + lane;          // it=0
  const int row0 = chunk0 >> 2, kc0 = chunk0 & 3;
  const int kcg0 = kc0 ^ ((row0 >> 1) & 3);
  const int chunk1 = 256 + w * 64 + lane;    // it=1
  const int row1 = chunk1 >> 2, kc1 = chunk1 & 3;
  const int kcg1 = kc1 ^ ((row1 >> 1) & 3);

  auto STAGE = [&](int kt, int sel) {   // 4 vmem ops per wave
    const int kb = kbase + kt * 32;
    gload_lds16(W  + (size_t)(m0 + row0) * Kp + kb + kcg0 * 8, &As[sel][(w * 64) * 8]);
    gload_lds16(Ht + (size_t)(n0 + row0) * Kp + kb + kcg0 * 8, &Bs[sel][(w * 64) * 8]);
    gload_lds16(W  + (size_t)(m0 + row1) * Kp + kb + kcg1 * 8, &As[sel][(256 + w * 64) * 8]);
    gload_lds16(Ht + (size_t)(n0 + row1) * Kp + kb + kcg1 * 8, &Bs[sel][(256 + w * 64) * 8]);
  };

  STAGE(0, 0);
  if (nkt > 1) STAGE(1, 1);

  int cur = 0, nxt = 1, nx2 = 2;
  for (int kt = 0; kt < nkt; ++kt) {
    if (kt + 1 < nkt) {
      // STAGE(kt) complete; STAGE(kt+1) stays in flight across the barrier
      asm volatile("s_waitcnt vmcnt(4)" ::: "memory");
      __builtin_amdgcn_s_barrier();
      __builtin_amdgcn_sched_barrier(0);
      if (kt + 2 < nkt) STAGE(kt + 2, nx2);
    } else {
      asm volatile("s_waitcnt vmcnt(0)" ::: "memory");
      __builtin_amdgcn_s_barrier();
      __builtin_amdgcn_sched_barrier(0);
    }
    bf16x8 af[4], bfr[4];
#pragma unroll
    for (int mi = 0; mi < 4; ++mi) {
      const int row = wr * 64 + mi * 16 + llo;
      af[mi] = *(const bf16x8*)(&As[cur][row * 32 + (lhi ^ ((row >> 1) & 3)) * 8]);
    }
#pragma unroll
    for (int ni = 0; ni < 4; ++ni) {
      const int row = wc * 64 + ni * 16 + llo;
      bfr[ni] = *(const bf16x8*)(&Bs[cur][row * 32 + (lhi ^ ((row >> 1) & 3)) * 8]);
    }
#pragma unroll
    for (int mi = 0; mi < 4; ++mi)
#pragma unroll
      for (int ni = 0; ni < 4; ++ni) {
        if (OUT_NM)
          acc[mi][ni] = __builtin_amdgcn_mfma_f32_16x16x32_bf16(bfr[ni], af[mi], acc[mi][ni], 0, 0, 0);
        else
          acc[mi][ni] = __builtin_amdgcn_mfma_f32_16x16x32_bf16(af[mi], bfr[ni], acc[mi][ni], 0, 0, 0);
      }
    const int t = cur; cur = nxt; nxt = nx2; nx2 = t;
  }
}

// -------- direct GEMM with fused epilogue --------
template<int ACT, int OUT_NM>
__global__ __launch_bounds__(256)
void gemm_bt(const unsigned short* __restrict__ W, const unsigned short* __restrict__ Ht,
             const float* __restrict__ bias, int Mreal,
             unsigned short* __restrict__ out, int ldo, int Kp) {
  __shared__ unsigned short As[3][128 * 32];
  __shared__ unsigned short Bs[3][128 * 32];
  int bx, by; xcd_swz(bx, by);
  const int tid = threadIdx.x;
  const int w = tid >> 6, lane = tid & 63;
  const int m0 = bx * 128, n0 = by * 128;
  const int wr = w >> 1, wc = w & 1;
  const int lhi = lane >> 4, llo = lane & 15;

  f32x4 acc[4][4];
#pragma unroll
  for (int i = 0; i < 4; ++i)
#pragma unroll
    for (int j = 0; j < 4; ++j) acc[i][j] = f32x4{0.f, 0.f, 0.f, 0.f};

  gemm_core<OUT_NM>(W, Ht, As, Bs, m0, n0, Kp, 0, Kp >> 5, w, lane, acc);

  if (OUT_NM) {
#pragma unroll
    for (int mi = 0; mi < 4; ++mi) {
      const int mg = m0 + wr * 64 + mi * 16 + llo;
      const float bv = (mg < Mreal) ? bias[mg] : 0.f;
#pragma unroll
      for (int ni = 0; ni < 4; ++ni) {
        const int ng = n0 + wc * 64 + ni * 16 + lhi * 4;
#pragma unroll
        for (int r = 0; r < 4; ++r) {
          float v = acc[mi][ni][r] + bv;
          if (ACT == 1) v = fmaxf(v, 0.f);
          else if (ACT == 2) v = 1.f / (1.f + expf(-v));
          out[(size_t)(ng + r) * ldo + mg] = f2bf(v);
        }
      }
    }
  } else {
#pragma unroll
    for (int mi = 0; mi < 4; ++mi) {
      const int mgb = m0 + wr * 64 + mi * 16 + lhi * 4;
#pragma unroll
      for (int ni = 0; ni < 4; ++ni) {
        const int ng = n0 + wc * 64 + ni * 16 + llo;
#pragma unroll
        for (int r = 0; r < 4; ++r) {
          const int mg = mgb + r;
          float v = acc[mi][ni][r] + ((mg < Mreal) ? bias[mg] : 0.f);
          if (ACT == 1) v = fmaxf(v, 0.f);
          else if (ACT == 2) v = 1.f / (1.f + expf(-v));
          out[(size_t)mg * ldo + ng] = f2bf(v);
        }
      }
    }
  }
}

// -------- split-K GEMM: fp32 partials, no epilogue; chunk = blockIdx.z --------
__global__ __launch_bounds__(256)
void gemm_splitk(const unsigned short* __restrict__ W, const unsigned short* __restrict__ Ht,
                 float* __restrict__ part, int ldo /*Mp*/, int Kp, int chunkK) {
  __shared__ unsigned short As[3][128 * 32];
  __shared__ unsigned short Bs[3][128 * 32];
  int bx, by; xcd_swz(bx, by);
  const int z = blockIdx.z;
  const int tid = threadIdx.x;
  const int w = tid >> 6, lane = tid & 63;
  const int m0 = bx * 128, n0 = by * 128;
  const int wr = w >> 1, wc = w & 1;
  const int lhi = lane >> 4, llo = lane & 15;

  f32x4 acc[4][4];
#pragma unroll
  for (int i = 0; i < 4; ++i)
#pragma unroll
    for (int j = 0; j < 4; ++j) acc[i][j] = f32x4{0.f, 0.f, 0.f, 0.f};

  gemm_core<1>(W, Ht, As, Bs, m0, n0, Kp, z * chunkK, chunkK >> 5, w, lane, acc);

  float* pz = part + (size_t)z * NTOK * ldo;
#pragma unroll
  for (int mi = 0; mi < 4; ++mi) {
    const int mg = m0 + wr * 64 + mi * 16 + llo;
#pragma unroll
    for (int ni = 0; ni < 4; ++ni) {
      const int ng = n0 + wc * 64 + ni * 16 + lhi * 4;
#pragma unroll
      for (int r = 0; r < 4; ++r)
        pz[(size_t)(ng + r) * ldo + mg] = acc[mi][ni][r];
    }
  }
}

// -------- split-K reduce + bias + ReLU -> bf16 [n][m] --------
__global__ __launch_bounds__(256)
void reduce_act(const float* __restrict__ part, const float* __restrict__ bias,
                unsigned short* __restrict__ out, int Mp, int Mreal, int nch) {
  const int i4 = blockIdx.x * 256 + threadIdx.x;
  const int total = NTOK * Mp / 4;
  if (i4 >= total) return;
  const size_t off = (size_t)i4 * 4;
  const int m0 = (int)(off % Mp);
  float s0 = 0.f, s1 = 0.f, s2 = 0.f, s3 = 0.f;
  for (int z = 0; z < nch; ++z) {
    const float4 v = *(const float4*)(part + (size_t)z * NTOK * Mp + off);
    s0 += v.x; s1 += v.y; s2 += v.z; s3 += v.w;
  }
  s0 += (m0 + 0 < Mreal) ? bias[m0 + 0] : 0.f;
  s1 += (m0 + 1 < Mreal) ? bias[m0 + 1] : 0.f;
  s2 += (m0 + 2 < Mreal) ? bias[m0 + 2] : 0.f;
  s3 += (m0 + 3 < Mreal) ? bias[m0 + 3] : 0.f;
  s0 = fmaxf(s0, 0.f); s1 = fmaxf(s1, 0.f); s2 = fmaxf(s2, 0.f); s3 = fmaxf(s3, 0.f);
  uint2 pk;
  pk.x = (unsigned)f2bf(s0) | ((unsigned)f2bf(s1) << 16);
  pk.y = (unsigned)f2bf(s2) | ((unsigned)f2bf(s3) << 16);
  *(uint2*)&out[off] = pk;
}

// -------- recompute fp32 DCT, multiply by mask, IDCT, write clean tiles (bf16) --------
__global__ __launch_bounds__(256)
void mask_idct(const float* __restrict__ x, const unsigned short* __restrict__ masks,
               unsigned short* __restrict__ clean) {
  __shared__ float Dm[256];   // D[k][m]
  __shared__ float Din[256];  // Di[n][k]
  __shared__ float patch[16 * 272];
  __shared__ float cd[16 * 272];
  const int tid = threadIdx.x;
  const int b   = blockIdx.y;
  const int c0  = blockIdx.x * 16;
  {
    const int k = tid >> 4, m = tid & 15;
    Dm[tid] = 2.f * cosf(PI_F * (float)((2 * m + 1) * k) / 32.f);
    const int n = tid >> 4, kk = tid & 15;
    Din[tid] = cosf(PI_F * (float)((2 * n + 1) * kk) / 32.f) * ((kk == 0) ? 0.5f : 1.f) * (1.f / 16.f);
  }
  __syncthreads();
  const int t = tid >> 4, q = tid & 15;
  const int c = c0 + t;
  const bool valid = (c < C0R);
  {
    float4 v0{}, v1{}, v2{}, v3{};
    if (valid) {
      const int ch = c % 3, gw = (c / 3) % GD, gh = c / (3 * GD);
      const float* xr = x + ((size_t)(b * 3 + ch) * INSZ + (gh * 4 + q)) * INSZ + gw * 4;
      v0 = *(const float4*)(xr);      v1 = *(const float4*)(xr + 4);
      v2 = *(const float4*)(xr + 8);  v3 = *(const float4*)(xr + 12);
    }
    float* pr = &patch[t * 272 + q * 17];
    pr[0]=v0.x; pr[1]=v0.y; pr[2]=v0.z; pr[3]=v0.w;
    pr[4]=v1.x; pr[5]=v1.y; pr[6]=v1.z; pr[7]=v1.w;
    pr[8]=v2.x; pr[9]=v2.y; pr[10]=v2.z; pr[11]=v2.w;
    pr[12]=v3.x; pr[13]=v3.y; pr[14]=v3.z; pr[15]=v3.w;
  }
  __syncthreads();
  float Drow[16];
#pragma unroll
  for (int m = 0; m < 16; ++m) Drow[m] = Dm[q * 16 + m];
  float tmpr[16];
#pragma unroll
  for (int n = 0; n < 16; ++n) tmpr[n] = 0.f;
#pragma unroll
  for (int m = 0; m < 16; ++m) {
    const float dm = Drow[m];
    const float* pr = &patch[t * 272 + m * 17];
#pragma unroll
    for (int n = 0; n < 16; ++n) tmpr[n] += dm * pr[n];
  }
  unsigned mu[8] = {0, 0, 0, 0, 0, 0, 0, 0};
  if (valid) {
    const uint4* mp = (const uint4*)(masks + (size_t)c * NTOK + (size_t)b * 256 + q * 16);
    uint4 a = mp[0], bb = mp[1];
    mu[0]=a.x; mu[1]=a.y; mu[2]=a.z; mu[3]=a.w;
    mu[4]=bb.x; mu[5]=bb.y; mu[6]=bb.z; mu[7]=bb.w;
  }
  float mrowf[16];
#pragma unroll
  for (int l = 0; l < 8; ++l) {
    mrowf[2 * l]     = bf2f((unsigned short)(mu[l] & 0xFFFFu));
    mrowf[2 * l + 1] = bf2f((unsigned short)(mu[l] >> 16));
  }
  float* cdr = &cd[t * 272 + q * 17];
#pragma unroll
  for (int l = 0; l < 16; ++l) {
    float s = 0.f;
#pragma unroll
    for (int n = 0; n < 16; ++n) s += tmpr[n] * Dm[l * 16 + n];
    cdr[l] = s * mrowf[l];
  }
  __syncthreads();
  float Dirow[16];
#pragma unroll
  for (int k = 0; k < 16; ++k) Dirow[k] = Din[q * 16 + k];
  float t2r[16];
#pragma unroll
  for (int l = 0; l < 16; ++l) t2r[l] = 0.f;
#pragma unroll
  for (int k = 0; k < 16; ++k) {
    const float dk = Dirow[k];
    const float* cdk = &cd[t * 272 + k * 17];
#pragma unroll
    for (int l = 0; l < 16; ++l) t2r[l] += dk * cdk[l];
  }
  if (valid) {
    float orow[16];
#pragma unroll
    for (int np = 0; np < 16; ++np) {
      float s = 0.f;
#pragma unroll
      for (int l = 0; l < 16; ++l) s += t2r[l] * Din[np * 16 + l];
      orow[np] = s;
    }
    unsigned pk[8];
#pragma unroll
    for (int l = 0; l < 8; ++l)
      pk[l] = (unsigned)f2bf(orow[2 * l]) | ((unsigned)f2bf(orow[2 * l + 1]) << 16);
    unsigned short* dst = clean + ((size_t)b * C0R + c) * 256 + q * 16;
    uint4* d4 = (uint4*)dst;
    d4[0] = make_uint4(pk[0], pk[1], pk[2], pk[3]);
    d4[1] = make_uint4(pk[4], pk[5], pk[6], pk[7]);
  }
}

// -------- overlap-add gather + count normalization --------
__global__ void overlap_add(const unsigned short* __restrict__ clean, float* __restrict__ out) {
  const int px = blockIdx.x * 256 + threadIdx.x;
  if (px >= 8 * 3 * 224 * 224) return;
  const int j = px % 224;
  const int i = (px / 224) % 224;
  const int bc = px / (224 * 224);
  const int ch = bc % 3, b = bc / 3;
  const int ilo = i - 15;
  const int ghlo = ilo > 0 ? (ilo + 3) >> 2 : 0;
  const int ghhi = (i >> 2) < 52 ? (i >> 2) : 52;
  const int jlo = j - 15;
  const int gwlo = jlo > 0 ? (jlo + 3) >> 2 : 0;
  const int gwhi = (j >> 2) < 52 ? (j >> 2) : 52;
  float sum = 0.f;
  for (int gh = ghlo; gh <= ghhi; ++gh) {
    const int r = i - gh * 4;
    const size_t base = ((size_t)b * C0R + (size_t)gh * (3 * GD) + ch) * 256 + (size_t)r * 16 + j;
    for (int gw = gwlo; gw <= gwhi; ++gw) {
      sum += bf2f(clean[base + (size_t)gw * 764]); // +gw*3*256 - 4*gw
    }
  }
  const int cnt = (ghhi - ghlo + 1) * (gwhi - gwlo + 1);
  out[px] = sum / (float)cnt;
}

extern "C" void kernel_launch(void* const* d_in, const int* in_sizes, int n_in,
                              void* d_out, int out_size, void* d_ws, size_t ws_size,
                              hipStream_t stream) {
  const float* x  = (const float*)d_in[0];
  const float* w1 = (const float*)d_in[1];
  const float* b1 = (const float*)d_in[2];
  const float* w2 = (const float*)d_in[3];
  const float* b2 = (const float*)d_in[4];
  const float* w3 = (const float*)d_in[5];
  const float* b3 = (const float*)d_in[6];
  const float* w4 = (const float*)d_in[7];
  const float* b4 = (const float*)d_in[8];
  float* out = (float*)d_out;
  char* ws = (char*)d_ws;

  // ---- workspace layout (peak 133.8 MB) ----
  const size_t S_WB1  = (size_t)C1P * C0P * 2;       // 36,765,696
  const size_t S_H0   = (size_t)NTOK * C0P * 2;      // 34,603,008
  const size_t S_PART = (size_t)3 * NTOK * C1P * 4;  // 53,477,376
  const size_t OFF_WB1  = 0;
  const size_t OFF_H0   = OFF_WB1 + S_WB1;
  const size_t OFF_PART = OFF_H0 + S_H0;
  const size_t OFF_Y1   = OFF_PART + S_PART;

  unsigned short* wb1 = (unsigned short*)(ws + OFF_WB1);
  unsigned short* H0v = (unsigned short*)(ws + OFF_H0);
  float*          pt1 = (float*)(ws + OFF_PART);
  unsigned short* Y1  = (unsigned short*)(ws + OFF_Y1);
  // aliases after reduce1 (PART slot): wb2, wb3, wb4, Y2
  unsigned short* wb2 = (unsigned short*)(ws + OFF_PART);
  unsigned short* wb3 = (unsigned short*)(ws + OFF_PART + (size_t)C2P * C1P * 2);
  unsigned short* wb4 = (unsigned short*)(ws + OFF_PART + (size_t)2 * C2P * C1P * 2);
  unsigned short* Y2  = (unsigned short*)(ws + OFF_PART + (size_t)2 * C2P * C1P * 2 + (size_t)C0P * C1P * 2);
  // aliases in WB1 slot: part2 (21.0MB), part3 (35.7MB), clean bf16 (34.5MB)
  float*          pt2 = (float*)(ws + OFF_WB1);
  float*          pt3 = (float*)(ws + OFF_WB1);
  unsigned short* clean = (unsigned short*)(ws + OFF_WB1);
  // Y3 reuses Y1 slot (Y1 dead after GEMM2); masks reuse H0 slot
  unsigned short* Y3  = (unsigned short*)(ws + OFF_Y1);
  unsigned short* msk = (unsigned short*)(ws + OFF_H0);

  // 1. stage inputs for GEMM1
  cvt_pad<<<dim3((C0P + 255) / 256, C1P), 256, 0, stream>>>(w1, wb1, C1R, C0R, C0P);
  dct_h0<<<dim3(C0P / 64, 8), 256, 0, stream>>>(x, H0v);

  // 2. GEMM1 split-K x3 (chunk 2816), reduce -> Y1
  gemm_splitk<<<dim3(C1P / 128, NTOK / 128, 3), 256, 0, stream>>>(wb1, H0v, pt1, C1P, C0P, 2816);
  reduce_act<<<dim3(NTOK * C1P / 4 / 256), 256, 0, stream>>>(pt1, b1, Y1, C1P, C1R, 3);

  // 3. remaining weight conversions (into dead PART slot)
  cvt_pad<<<dim3((C1P + 255) / 256, C2P), 256, 0, stream>>>(w2, wb2, C2R, C1R, C1P);
  cvt_pad<<<dim3((C2P + 255) / 256, C1P), 256, 0, stream>>>(w3, wb3, C1R, C2R, C2P);
  cvt_pad<<<dim3((C1P + 255) / 256, C0P), 256, 0, stream>>>(w4, wb4, C0R, C1R, C1P);

  // 4. GEMM2 split-K x4 (chunk 544) -> Y2
  gemm_splitk<<<dim3(C2P / 128, NTOK / 128, 4), 256, 0, stream>>>(wb2, Y1, pt2, C2P, C1P, 544);
  reduce_act<<<dim3(NTOK * C2P / 4 / 256), 256, 0, stream>>>(pt2, b2, Y2, C2P, C2R, 4);

  // 5. GEMM3 split-K x2 (chunk 320) -> Y3 (Y1 slot)
  gemm_splitk<<<dim3(C1P / 128, NTOK / 128, 2), 256, 0, stream>>>(wb3, Y2, pt3, C1P, C2P, 320);
  reduce_act<<<dim3(NTOK * C1P / 4 / 256), 256, 0, stream>>>(pt3, b3, Y3, C1P, C1R, 2);

  // 6. GEMM4 direct (sigmoid, out [m][n]) -> masks (H0 slot)
  gemm_bt<2, 0><<<dim3(C0P / 128, NTOK / 128), 256, 0, stream>>>(wb4, Y3, b4, C0R, msk, NTOK, C1P);

  // 7. mask*DCT -> IDCT -> clean (bf16, WB1 slot)
  mask_idct<<<dim3((C0R + 15) / 16, 8), 256, 0, stream>>>(x, msk, clean);

  // 8. overlap-add + normalize
  overlap_add<<<dim3((8 * 3 * 224 * 224 + 255) / 256), 256, 0, stream>>>(clean, out);
}

// Round 5
// 480.085 us; speedup vs baseline: 1.4803x; 1.2078x over previous
//
#include <hip/hip_runtime.h>
#include <stdint.h>

constexpr int INSZ = 224;
constexpr int GD   = 53;
constexpr int C0R = 8427, C1R = 2106, C2R = 526;
constexpr int C0P = 8448, C1P = 2176, C2P = 640;
constexpr int NTOK = 2048; // 8 batches * 256 DCT positions

typedef __attribute__((ext_vector_type(4))) float f32x4;
typedef __attribute__((ext_vector_type(8))) short bf16x8;

// cos(pi*j/32) for j=0..63 (period 64)
constexpr float CT[64] = {
  1.00000000f,  0.99518473f,  0.98078528f,  0.95694034f,
  0.92387953f,  0.88192126f,  0.83146961f,  0.77301045f,
  0.70710678f,  0.63439328f,  0.55557023f,  0.47139674f,
  0.38268343f,  0.29028468f,  0.19509032f,  0.09801714f,
  0.00000000f, -0.09801714f, -0.19509032f, -0.29028468f,
 -0.38268343f, -0.47139674f, -0.55557023f, -0.63439328f,
 -0.70710678f, -0.77301045f, -0.83146961f, -0.88192126f,
 -0.92387953f, -0.95694034f, -0.98078528f, -0.99518473f,
 -1.00000000f, -0.99518473f, -0.98078528f, -0.95694034f,
 -0.92387953f, -0.88192126f, -0.83146961f, -0.77301045f,
 -0.70710678f, -0.63439328f, -0.55557023f, -0.47139674f,
 -0.38268343f, -0.29028468f, -0.19509032f, -0.09801714f,
 -0.00000000f,  0.09801714f,  0.19509032f,  0.29028468f,
  0.38268343f,  0.47139674f,  0.55557023f,  0.63439328f,
  0.70710678f,  0.77301045f,  0.83146961f,  0.88192126f,
  0.92387953f,  0.95694034f,  0.98078528f,  0.99518473f
};
// forward DCT matrix D[k][n] = 2*cos(pi*(2n+1)k/32)
constexpr float Dfwd(int k, int n) { return 2.0f * CT[((2 * n + 1) * k) & 63]; }
// inverse matrix Di[n][k] = cos(pi*(2n+1)k/32)*w[k]/16, w[0]=0.5
constexpr float Dinv(int n, int k) { return CT[((2 * n + 1) * k) & 63] * (k == 0 ? 0.03125f : 0.0625f); }

// transpose scratch strides (floats): row stride 20 (16B-aligned), tile stride 336
constexpr int TRS_R = 20, TRS_T = 336;
constexpr int TRS_SZ = 15 * TRS_T + 15 * TRS_R + 16; // floats

__device__ __forceinline__ unsigned short f2bf(float f) {
  union { float f; unsigned u; } v; v.f = f;
  return (unsigned short)((v.u + 0x7FFFu + ((v.u >> 16) & 1u)) >> 16);
}
__device__ __forceinline__ float bf2f(unsigned short b) {
  union { unsigned u; float f; } v; v.u = ((unsigned)b) << 16;
  return v.f;
}

// global -> LDS async copy, 16B per lane; LDS dest is wave-uniform base + lane*16
__device__ __forceinline__ void gload_lds16(const void* g, void* l) {
  __builtin_amdgcn_global_load_lds(
      (__attribute__((address_space(1))) unsigned int*)(uintptr_t)g,
      (__attribute__((address_space(3))) unsigned int*)(unsigned int)(uintptr_t)l,
      16, 0, 0);
}

// XCD-aware block swizzle, n-fastest within each XCD chunk (L2 panel locality)
__device__ __forceinline__ void xcd_swz(int& bx, int& by) {
  const int gx = gridDim.x, gy = gridDim.y;
  const int nwg = gx * gy;
  const int bid = blockIdx.y * gx + blockIdx.x;
  const int cpx = nwg >> 3;
  const int swz = (bid & 7) * cpx + (bid >> 3);
  by = swz % gy;
  bx = swz / gy;
}

// -------- weight fp32 -> bf16 with zero padding --------
__global__ void cvt_pad(const float* __restrict__ src, unsigned short* __restrict__ dst,
                        int M, int K, int Kp) {
  const int k = blockIdx.x * 256 + threadIdx.x;
  const int m = blockIdx.y;
  if (k >= Kp) return;
  const float v = (m < M && k < K) ? src[(size_t)m * K + k] : 0.f;
  dst[(size_t)m * Kp + k] = f2bf(v);
}

// -------- DCT: x -> H0 bf16 [n=2048][c=8448]  (h = dct/256) --------
// constant-folded DCT coefficients; registers + one LDS transpose per pass pair
__global__ __launch_bounds__(256)
void dct_h0(const float* __restrict__ x, unsigned short* __restrict__ H0) {
  __shared__ float trp[TRS_SZ];
  __shared__ unsigned short hst[256 * 64];   // [token_kl][local_c]
  const int tid = threadIdx.x;
  const int b   = blockIdx.y;
  const int c0  = blockIdx.x * 64;
  const int t = tid >> 4, q = tid & 15;      // tile-in-group, row/col slot

  for (int g = 0; g < 4; ++g) {
    const int c = c0 + g * 16 + t;
    float p[16];
    {
      float4 v0{}, v1{}, v2{}, v3{};
      if (c < C0R) {
        const int ch = c % 3, gw = (c / 3) % GD, gh = c / (3 * GD);
        const float* xr = x + ((size_t)(b * 3 + ch) * INSZ + (gh * 4 + q)) * INSZ + gw * 4;
        v0 = *(const float4*)(xr);      v1 = *(const float4*)(xr + 4);
        v2 = *(const float4*)(xr + 8);  v3 = *(const float4*)(xr + 12);
      }
      p[0]=v0.x; p[1]=v0.y; p[2]=v0.z; p[3]=v0.w;
      p[4]=v1.x; p[5]=v1.y; p[6]=v1.z; p[7]=v1.w;
      p[8]=v2.x; p[9]=v2.y; p[10]=v2.z; p[11]=v2.w;
      p[12]=v3.x; p[13]=v3.y; p[14]=v3.z; p[15]=v3.w;
    }
    // pass 1: R[q][k] = sum_n p[n]*D[k][n]  (thread owns row q)
    float r[16];
#pragma unroll
    for (int k = 0; k < 16; ++k) {
      float s = 0.f;
#pragma unroll
      for (int n = 0; n < 16; ++n) s += p[n] * Dfwd(k, n);
      r[k] = s;
    }
    // transpose: write row q, read column j(=q slot)
    float* wr = &trp[t * TRS_T + q * TRS_R];
#pragma unroll
    for (int k = 0; k < 16; k += 4)
      *(float4*)(wr + k) = make_float4(r[k], r[k+1], r[k+2], r[k+3]);
    __syncthreads();
    const int j = q;
    float rr[16];
#pragma unroll
    for (int i = 0; i < 16; ++i) rr[i] = trp[t * TRS_T + i * TRS_R + j];
    // pass 2: dct[k][j] = sum_i D[k][i]*R[i][j];  h = dct/256 -> bf16 stage
#pragma unroll
    for (int k = 0; k < 16; ++k) {
      float s = 0.f;
#pragma unroll
      for (int i = 0; i < 16; ++i) s += rr[i] * Dfwd(k, i);
      hst[(k * 16 + j) * 64 + g * 16 + t] = f2bf(s * (1.f / 256.f));
    }
    __syncthreads();
  }
  // write H0[n][c] as uint4 (16B per lane)
  const size_t base = ((size_t)b * 256) * C0P + c0;
#pragma unroll
  for (int i = 0; i < 8; ++i) {
    const int s = i * 256 + tid;
    const int kl = s >> 3, c16 = s & 7;
    *(uint4*)&H0[base + (size_t)kl * C0P + c16 * 8] = *(const uint4*)&hst[kl * 64 + c16 * 8];
  }
}

// ======== shared GEMM core: 128x128 tile, BK=32, TRIPLE-buffered LDS,
// ======== depth-2 prefetch, counted vmcnt, XOR-swizzled LDS both-sides ========
template<int OUT_NM>
__device__ __forceinline__ void gemm_core(
    const unsigned short* __restrict__ W, const unsigned short* __restrict__ Ht,
    unsigned short (*As)[128 * 32], unsigned short (*Bs)[128 * 32],
    int m0, int n0, int Kp, int kbase, int nkt, int w, int lane, f32x4 acc[4][4]) {
  const int wr = w >> 1, wc = w & 1;
  const int lhi = lane >> 4, llo = lane & 15;

  const int chunk0 = w * 64 + lane;
  const int row0 = chunk0 >> 2, kc0 = chunk0 & 3;
  const int kcg0 = kc0 ^ ((row0 >> 1) & 3);
  const int chunk1 = 256 + w * 64 + lane;
  const int row1 = chunk1 >> 2, kc1 = chunk1 & 3;
  const int kcg1 = kc1 ^ ((row1 >> 1) & 3);

  auto STAGE = [&](int kt, int sel) {   // 4 vmem ops per wave
    const int kb = kbase + kt * 32;
    gload_lds16(W  + (size_t)(m0 + row0) * Kp + kb + kcg0 * 8, &As[sel][(w * 64) * 8]);
    gload_lds16(Ht + (size_t)(n0 + row0) * Kp + kb + kcg0 * 8, &Bs[sel][(w * 64) * 8]);
    gload_lds16(W  + (size_t)(m0 + row1) * Kp + kb + kcg1 * 8, &As[sel][(256 + w * 64) * 8]);
    gload_lds16(Ht + (size_t)(n0 + row1) * Kp + kb + kcg1 * 8, &Bs[sel][(256 + w * 64) * 8]);
  };

  STAGE(0, 0);
  if (nkt > 1) STAGE(1, 1);

  int cur = 0, nxt = 1, nx2 = 2;
  for (int kt = 0; kt < nkt; ++kt) {
    if (kt + 1 < nkt) {
      asm volatile("s_waitcnt vmcnt(4)" ::: "memory");
      __builtin_amdgcn_s_barrier();
      __builtin_amdgcn_sched_barrier(0);
      if (kt + 2 < nkt) STAGE(kt + 2, nx2);
    } else {
      asm volatile("s_waitcnt vmcnt(0)" ::: "memory");
      __builtin_amdgcn_s_barrier();
      __builtin_amdgcn_sched_barrier(0);
    }
    bf16x8 af[4], bfr[4];
#pragma unroll
    for (int mi = 0; mi < 4; ++mi) {
      const int row = wr * 64 + mi * 16 + llo;
      af[mi] = *(const bf16x8*)(&As[cur][row * 32 + (lhi ^ ((row >> 1) & 3)) * 8]);
    }
#pragma unroll
    for (int ni = 0; ni < 4; ++ni) {
      const int row = wc * 64 + ni * 16 + llo;
      bfr[ni] = *(const bf16x8*)(&Bs[cur][row * 32 + (lhi ^ ((row >> 1) & 3)) * 8]);
    }
#pragma unroll
    for (int mi = 0; mi < 4; ++mi)
#pragma unroll
      for (int ni = 0; ni < 4; ++ni) {
        if (OUT_NM)
          acc[mi][ni] = __builtin_amdgcn_mfma_f32_16x16x32_bf16(bfr[ni], af[mi], acc[mi][ni], 0, 0, 0);
        else
          acc[mi][ni] = __builtin_amdgcn_mfma_f32_16x16x32_bf16(af[mi], bfr[ni], acc[mi][ni], 0, 0, 0);
      }
    const int tmp = cur; cur = nxt; nxt = nx2; nx2 = tmp;
  }
}

// -------- direct GEMM with fused epilogue --------
template<int ACT, int OUT_NM>
__global__ __launch_bounds__(256)
void gemm_bt(const unsigned short* __restrict__ W, const unsigned short* __restrict__ Ht,
             const float* __restrict__ bias, int Mreal,
             unsigned short* __restrict__ out, int ldo, int Kp) {
  __shared__ unsigned short As[3][128 * 32];
  __shared__ unsigned short Bs[3][128 * 32];
  int bx, by; xcd_swz(bx, by);
  const int tid = threadIdx.x;
  const int w = tid >> 6, lane = tid & 63;
  const int m0 = bx * 128, n0 = by * 128;
  const int wr = w >> 1, wc = w & 1;
  const int lhi = lane >> 4, llo = lane & 15;

  f32x4 acc[4][4];
#pragma unroll
  for (int i = 0; i < 4; ++i)
#pragma unroll
    for (int j = 0; j < 4; ++j) acc[i][j] = f32x4{0.f, 0.f, 0.f, 0.f};

  gemm_core<OUT_NM>(W, Ht, As, Bs, m0, n0, Kp, 0, Kp >> 5, w, lane, acc);

  if (OUT_NM) {
#pragma unroll
    for (int mi = 0; mi < 4; ++mi) {
      const int mg = m0 + wr * 64 + mi * 16 + llo;
      const float bv = (mg < Mreal) ? bias[mg] : 0.f;
#pragma unroll
      for (int ni = 0; ni < 4; ++ni) {
        const int ng = n0 + wc * 64 + ni * 16 + lhi * 4;
#pragma unroll
        for (int r = 0; r < 4; ++r) {
          float v = acc[mi][ni][r] + bv;
          if (ACT == 1) v = fmaxf(v, 0.f);
          else if (ACT == 2) v = 1.f / (1.f + expf(-v));
          out[(size_t)(ng + r) * ldo + mg] = f2bf(v);
        }
      }
    }
  } else {
#pragma unroll
    for (int mi = 0; mi < 4; ++mi) {
      const int mgb = m0 + wr * 64 + mi * 16 + lhi * 4;
#pragma unroll
      for (int ni = 0; ni < 4; ++ni) {
        const int ng = n0 + wc * 64 + ni * 16 + llo;
#pragma unroll
        for (int r = 0; r < 4; ++r) {
          const int mg = mgb + r;
          float v = acc[mi][ni][r] + ((mg < Mreal) ? bias[mg] : 0.f);
          if (ACT == 1) v = fmaxf(v, 0.f);
          else if (ACT == 2) v = 1.f / (1.f + expf(-v));
          out[(size_t)mg * ldo + ng] = f2bf(v);
        }
      }
    }
  }
}

// -------- split-K GEMM: fp32 partials, no epilogue; chunk = blockIdx.z --------
__global__ __launch_bounds__(256)
void gemm_splitk(const unsigned short* __restrict__ W, const unsigned short* __restrict__ Ht,
                 float* __restrict__ part, int ldo /*Mp*/, int Kp, int chunkK) {
  __shared__ unsigned short As[3][128 * 32];
  __shared__ unsigned short Bs[3][128 * 32];
  int bx, by; xcd_swz(bx, by);
  const int z = blockIdx.z;
  const int tid = threadIdx.x;
  const int w = tid >> 6, lane = tid & 63;
  const int m0 = bx * 128, n0 = by * 128;
  const int wr = w >> 1, wc = w & 1;
  const int lhi = lane >> 4, llo = lane & 15;

  f32x4 acc[4][4];
#pragma unroll
  for (int i = 0; i < 4; ++i)
#pragma unroll
    for (int j = 0; j < 4; ++j) acc[i][j] = f32x4{0.f, 0.f, 0.f, 0.f};

  gemm_core<1>(W, Ht, As, Bs, m0, n0, Kp, z * chunkK, chunkK >> 5, w, lane, acc);

  float* pz = part + (size_t)z * NTOK * ldo;
#pragma unroll
  for (int mi = 0; mi < 4; ++mi) {
    const int mg = m0 + wr * 64 + mi * 16 + llo;
#pragma unroll
    for (int ni = 0; ni < 4; ++ni) {
      const int ng = n0 + wc * 64 + ni * 16 + lhi * 4;
#pragma unroll
      for (int r = 0; r < 4; ++r)
        pz[(size_t)(ng + r) * ldo + mg] = acc[mi][ni][r];
    }
  }
}

// -------- split-K reduce + bias + ReLU -> bf16 [n][m] --------
__global__ __launch_bounds__(256)
void reduce_act(const float* __restrict__ part, const float* __restrict__ bias,
                unsigned short* __restrict__ out, int Mp, int Mreal, int nch) {
  const int i4 = blockIdx.x * 256 + threadIdx.x;
  const int total = NTOK * Mp / 4;
  if (i4 >= total) return;
  const size_t off = (size_t)i4 * 4;
  const int m0 = (int)(off % Mp);
  float s0 = 0.f, s1 = 0.f, s2 = 0.f, s3 = 0.f;
  for (int z = 0; z < nch; ++z) {
    const float4 v = *(const float4*)(part + (size_t)z * NTOK * Mp + off);
    s0 += v.x; s1 += v.y; s2 += v.z; s3 += v.w;
  }
  s0 += (m0 + 0 < Mreal) ? bias[m0 + 0] : 0.f;
  s1 += (m0 + 1 < Mreal) ? bias[m0 + 1] : 0.f;
  s2 += (m0 + 2 < Mreal) ? bias[m0 + 2] : 0.f;
  s3 += (m0 + 3 < Mreal) ? bias[m0 + 3] : 0.f;
  s0 = fmaxf(s0, 0.f); s1 = fmaxf(s1, 0.f); s2 = fmaxf(s2, 0.f); s3 = fmaxf(s3, 0.f);
  uint2 pk;
  pk.x = (unsigned)f2bf(s0) | ((unsigned)f2bf(s1) << 16);
  pk.y = (unsigned)f2bf(s2) | ((unsigned)f2bf(s3) << 16);
  *(uint2*)&out[off] = pk;
}

// -------- recompute fp32 DCT, mask, IDCT, write clean tiles (bf16) --------
// constant-folded coefficients; registers + 2 LDS transposes; no table LDS reads
__global__ __launch_bounds__(256)
void mask_idct(const float* __restrict__ x, const unsigned short* __restrict__ masks,
               unsigned short* __restrict__ clean) {
  __shared__ float trp[TRS_SZ];
  const int tid = threadIdx.x;
  const int b   = blockIdx.y;
  const int c0  = blockIdx.x * 16;
  const int t = tid >> 4, q = tid & 15;   // q doubles as column slot j
  const int c = c0 + t;
  const bool valid = (c < C0R);

  float p[16];
  {
    float4 v0{}, v1{}, v2{}, v3{};
    if (valid) {
      const int ch = c % 3, gw = (c / 3) % GD, gh = c / (3 * GD);
      const float* xr = x + ((size_t)(b * 3 + ch) * INSZ + (gh * 4 + q)) * INSZ + gw * 4;
      v0 = *(const float4*)(xr);      v1 = *(const float4*)(xr + 4);
      v2 = *(const float4*)(xr + 8);  v3 = *(const float4*)(xr + 12);
    }
    p[0]=v0.x; p[1]=v0.y; p[2]=v0.z; p[3]=v0.w;
    p[4]=v1.x; p[5]=v1.y; p[6]=v1.z; p[7]=v1.w;
    p[8]=v2.x; p[9]=v2.y; p[10]=v2.z; p[11]=v2.w;
    p[12]=v3.x; p[13]=v3.y; p[14]=v3.z; p[15]=v3.w;
  }
  // pass 1: R[q][k] = sum_n p[n]*D[k][n]
  float r[16];
#pragma unroll
  for (int k = 0; k < 16; ++k) {
    float s = 0.f;
#pragma unroll
    for (int n = 0; n < 16; ++n) s += p[n] * Dfwd(k, n);
    r[k] = s;
  }
  // transpose A: thread q writes row q; thread j reads column j
  {
    float* wr = &trp[t * TRS_T + q * TRS_R];
#pragma unroll
    for (int k = 0; k < 16; k += 4)
      *(float4*)(wr + k) = make_float4(r[k], r[k+1], r[k+2], r[k+3]);
  }
  __syncthreads();
  const int j = q;
  float rr[16];
#pragma unroll
  for (int i = 0; i < 16; ++i) rr[i] = trp[t * TRS_T + i * TRS_R + j];
  // pass 2: dct[k][j] = sum_i D[k][i]*R[i][j]; multiply by mask (bf16)
  float cd[16];
  const unsigned short* mrow = masks + (size_t)c * NTOK + (size_t)b * 256 + j;
#pragma unroll
  for (int k = 0; k < 16; ++k) {
    float s = 0.f;
#pragma unroll
    for (int i = 0; i < 16; ++i) s += rr[i] * Dfwd(k, i);
    const float mv = valid ? bf2f(mrow[k * 16]) : 0.f;
    cd[k] = s * mv;
  }
  // pass 3: T[m][j] = sum_k Di[m][k]*cd[k]
  float t3[16];
#pragma unroll
  for (int m = 0; m < 16; ++m) {
    float s = 0.f;
#pragma unroll
    for (int k = 0; k < 16; ++k) s += cd[k] * Dinv(m, k);
    t3[m] = s;
  }
  // transpose B: thread j writes T[:,j] as row j; thread q reads row q of T
  __syncthreads();
  {
    float* wr = &trp[t * TRS_T + j * TRS_R];
#pragma unroll
    for (int m = 0; m < 16; m += 4)
      *(float4*)(wr + m) = make_float4(t3[m], t3[m+1], t3[m+2], t3[m+3]);
  }
  __syncthreads();
  float tr[16];
#pragma unroll
  for (int l = 0; l < 16; ++l) tr[l] = trp[t * TRS_T + l * TRS_R + q];
  // pass 4: out[q][n] = sum_l T[q][l]*Di[n][l]
  if (valid) {
    unsigned pk[8];
#pragma unroll
    for (int n2 = 0; n2 < 8; ++n2) {
      float s0 = 0.f, s1 = 0.f;
#pragma unroll
      for (int l = 0; l < 16; ++l) {
        s0 += tr[l] * Dinv(2 * n2, l);
        s1 += tr[l] * Dinv(2 * n2 + 1, l);
      }
      pk[n2] = (unsigned)f2bf(s0) | ((unsigned)f2bf(s1) << 16);
    }
    unsigned short* dst = clean + ((size_t)b * C0R + c) * 256 + q * 16;
    uint4* d4 = (uint4*)dst;
    d4[0] = make_uint4(pk[0], pk[1], pk[2], pk[3]);
    d4[1] = make_uint4(pk[4], pk[5], pk[6], pk[7]);
  }
}

// -------- overlap-add gather + count normalization --------
__global__ void overlap_add(const unsigned short* __restrict__ clean, float* __restrict__ out) {
  const int px = blockIdx.x * 256 + threadIdx.x;
  if (px >= 8 * 3 * 224 * 224) return;
  const int j = px % 224;
  const int i = (px / 224) % 224;
  const int bc = px / (224 * 224);
  const int ch = bc % 3, b = bc / 3;
  const int ilo = i - 15;
  const int ghlo = ilo > 0 ? (ilo + 3) >> 2 : 0;
  const int ghhi = (i >> 2) < 52 ? (i >> 2) : 52;
  const int jlo = j - 15;
  const int gwlo = jlo > 0 ? (jlo + 3) >> 2 : 0;
  const int gwhi = (j >> 2) < 52 ? (j >> 2) : 52;
  float sum = 0.f;
  for (int gh = ghlo; gh <= ghhi; ++gh) {
    const int r = i - gh * 4;
    const size_t base = ((size_t)b * C0R + (size_t)gh * (3 * GD) + ch) * 256 + (size_t)r * 16 + j;
    for (int gw = gwlo; gw <= gwhi; ++gw) {
      sum += bf2f(clean[base + (size_t)gw * 764]); // +gw*3*256 - 4*gw
    }
  }
  const int cnt = (ghhi - ghlo + 1) * (gwhi - gwlo + 1);
  out[px] = sum / (float)cnt;
}

extern "C" void kernel_launch(void* const* d_in, const int* in_sizes, int n_in,
                              void* d_out, int out_size, void* d_ws, size_t ws_size,
                              hipStream_t stream) {
  const float* x  = (const float*)d_in[0];
  const float* w1 = (const float*)d_in[1];
  const float* b1 = (const float*)d_in[2];
  const float* w2 = (const float*)d_in[3];
  const float* b2 = (const float*)d_in[4];
  const float* w3 = (const float*)d_in[5];
  const float* b3 = (const float*)d_in[6];
  const float* w4 = (const float*)d_in[7];
  const float* b4 = (const float*)d_in[8];
  float* out = (float*)d_out;
  char* ws = (char*)d_ws;

  // ---- workspace layout (peak 133.8 MB) ----
  const size_t S_WB1  = (size_t)C1P * C0P * 2;       // 36,765,696
  const size_t S_H0   = (size_t)NTOK * C0P * 2;      // 34,603,008
  const size_t S_PART = (size_t)3 * NTOK * C1P * 4;  // 53,477,376
  const size_t OFF_WB1  = 0;
  const size_t OFF_H0   = OFF_WB1 + S_WB1;
  const size_t OFF_PART = OFF_H0 + S_H0;
  const size_t OFF_Y1   = OFF_PART + S_PART;

  unsigned short* wb1 = (unsigned short*)(ws + OFF_WB1);
  unsigned short* H0v = (unsigned short*)(ws + OFF_H0);
  float*          pt1 = (float*)(ws + OFF_PART);
  unsigned short* Y1  = (unsigned short*)(ws + OFF_Y1);
  unsigned short* wb2 = (unsigned short*)(ws + OFF_PART);
  unsigned short* wb3 = (unsigned short*)(ws + OFF_PART + (size_t)C2P * C1P * 2);
  unsigned short* wb4 = (unsigned short*)(ws + OFF_PART + (size_t)2 * C2P * C1P * 2);
  unsigned short* Y2  = (unsigned short*)(ws + OFF_PART + (size_t)2 * C2P * C1P * 2 + (size_t)C0P * C1P * 2);
  float*          pt2 = (float*)(ws + OFF_WB1);
  float*          pt3 = (float*)(ws + OFF_WB1);
  unsigned short* clean = (unsigned short*)(ws + OFF_WB1);
  unsigned short* Y3  = (unsigned short*)(ws + OFF_Y1);
  unsigned short* msk = (unsigned short*)(ws + OFF_H0);

  // 1. stage inputs for GEMM1
  cvt_pad<<<dim3((C0P + 255) / 256, C1P), 256, 0, stream>>>(w1, wb1, C1R, C0R, C0P);
  dct_h0<<<dim3(C0P / 64, 8), 256, 0, stream>>>(x, H0v);

  // 2. GEMM1 split-K x3 (chunk 2816), reduce -> Y1
  gemm_splitk<<<dim3(C1P / 128, NTOK / 128, 3), 256, 0, stream>>>(wb1, H0v, pt1, C1P, C0P, 2816);
  reduce_act<<<dim3(NTOK * C1P / 4 / 256), 256, 0, stream>>>(pt1, b1, Y1, C1P, C1R, 3);

  // 3. remaining weight conversions (into dead PART slot)
  cvt_pad<<<dim3((C1P + 255) / 256, C2P), 256, 0, stream>>>(w2, wb2, C2R, C1R, C1P);
  cvt_pad<<<dim3((C2P + 255) / 256, C1P), 256, 0, stream>>>(w3, wb3, C1R, C2R, C2P);
  cvt_pad<<<dim3((C1P + 255) / 256, C0P), 256, 0, stream>>>(w4, wb4, C0R, C1R, C1P);

  // 4. GEMM2 split-K x4 (chunk 544) -> Y2
  gemm_splitk<<<dim3(C2P / 128, NTOK / 128, 4), 256, 0, stream>>>(wb2, Y1, pt2, C2P, C1P, 544);
  reduce_act<<<dim3(NTOK * C2P / 4 / 256), 256, 0, stream>>>(pt2, b2, Y2, C2P, C2R, 4);

  // 5. GEMM3 split-K x2 (chunk 320) -> Y3 (Y1 slot)
  gemm_splitk<<<dim3(C1P / 128, NTOK / 128, 2), 256, 0, stream>>>(wb3, Y2, pt3, C1P, C2P, 320);
  reduce_act<<<dim3(NTOK * C1P / 4 / 256), 256, 0, stream>>>(pt3, b3, Y3, C1P, C1R, 2);

  // 6. GEMM4 direct (sigmoid, out [m][n]) -> masks (H0 slot)
  gemm_bt<2, 0><<<dim3(C0P / 128, NTOK / 128), 256, 0, stream>>>(wb4, Y3, b4, C0R, msk, NTOK, C1P);

  // 7. mask*DCT -> IDCT -> clean (bf16, WB1 slot)
  mask_idct<<<dim3((C0R + 15) / 16, 8), 256, 0, stream>>>(x, msk, clean);

  // 8. overlap-add + normalize
  overlap_add<<<dim3((8 * 3 * 224 * 224 + 255) / 256), 256, 0, stream>>>(clean, out);
}

// Round 6
// 466.537 us; speedup vs baseline: 1.5233x; 1.0290x over previous
//
#include <hip/hip_runtime.h>
#include <stdint.h>

constexpr int INSZ = 224;
constexpr int GD   = 53;
constexpr int C0R = 8427, C1R = 2106, C2R = 526;
constexpr int C0P = 8448, C1P = 2176, C2P = 640;
constexpr int NTOK = 2048; // 8 batches * 256 DCT positions

typedef __attribute__((ext_vector_type(4))) float f32x4;
typedef __attribute__((ext_vector_type(8))) short bf16x8;

// cos(pi*j/32) for j=0..63 (period 64)
constexpr float CT[64] = {
  1.00000000f,  0.99518473f,  0.98078528f,  0.95694034f,
  0.92387953f,  0.88192126f,  0.83146961f,  0.77301045f,
  0.70710678f,  0.63439328f,  0.55557023f,  0.47139674f,
  0.38268343f,  0.29028468f,  0.19509032f,  0.09801714f,
  0.00000000f, -0.09801714f, -0.19509032f, -0.29028468f,
 -0.38268343f, -0.47139674f, -0.55557023f, -0.63439328f,
 -0.70710678f, -0.77301045f, -0.83146961f, -0.88192126f,
 -0.92387953f, -0.95694034f, -0.98078528f, -0.99518473f,
 -1.00000000f, -0.99518473f, -0.98078528f, -0.95694034f,
 -0.92387953f, -0.88192126f, -0.83146961f, -0.77301045f,
 -0.70710678f, -0.63439328f, -0.55557023f, -0.47139674f,
 -0.38268343f, -0.29028468f, -0.19509032f, -0.09801714f,
 -0.00000000f,  0.09801714f,  0.19509032f,  0.29028468f,
  0.38268343f,  0.47139674f,  0.55557023f,  0.63439328f,
  0.70710678f,  0.77301045f,  0.83146961f,  0.88192126f,
  0.92387953f,  0.95694034f,  0.98078528f,  0.99518473f
};
constexpr float Dfwd(int k, int n) { return 2.0f * CT[((2 * n + 1) * k) & 63]; }
constexpr float Dinv(int n, int k) { return CT[((2 * n + 1) * k) & 63] * (k == 0 ? 0.03125f : 0.0625f); }

// transpose scratch strides (floats)
constexpr int TRS_R = 20, TRS_T = 336;
constexpr int TRS_SZ = 15 * TRS_T + 15 * TRS_R + 16;

__device__ __forceinline__ unsigned short f2bf(float f) {
  union { float f; unsigned u; } v; v.f = f;
  return (unsigned short)((v.u + 0x7FFFu + ((v.u >> 16) & 1u)) >> 16);
}
__device__ __forceinline__ float bf2f(unsigned short b) {
  union { unsigned u; float f; } v; v.u = ((unsigned)b) << 16;
  return v.f;
}

__device__ __forceinline__ void gload_lds16(const void* g, void* l) {
  __builtin_amdgcn_global_load_lds(
      (__attribute__((address_space(1))) unsigned int*)(uintptr_t)g,
      (__attribute__((address_space(3))) unsigned int*)(unsigned int)(uintptr_t)l,
      16, 0, 0);
}

// XCD swizzle + L2 supertiling: XCD gets contiguous range of a global order
// that walks 4-wide bx stripes (by outer, bxi inner) -> resident set per step
// = 4 W-tiles + 1 B-tile (< 4MB L2). requires (gx*gy)%8==0
__device__ __forceinline__ void xcd_tile(int& bx, int& by) {
  const int gx = gridDim.x, gy = gridDim.y;
  const int nwg = gx * gy;
  const int bid = blockIdx.y * gx + blockIdx.x;
  const int cpx = nwg >> 3;
  const int l = (bid & 7) * cpx + (bid >> 3);
  const int stripe = gy << 2;
  const int bxg = l / stripe;
  const int r = l - bxg * stripe;
  const int rem = gx - (bxg << 2);
  const int w = rem < 4 ? rem : 4;
  by = r / w;
  bx = (bxg << 2) + (r - by * w);
}

// -------- weight fp32 -> bf16 with zero padding (w1) --------
__global__ void cvt_pad(const float* __restrict__ src, unsigned short* __restrict__ dst,
                        int M, int K, int Kp) {
  const int k = blockIdx.x * 256 + threadIdx.x;
  const int m = blockIdx.y;
  if (k >= Kp) return;
  const float v = (m < M && k < K) ? src[(size_t)m * K + k] : 0.f;
  dst[(size_t)m * Kp + k] = f2bf(v);
}

// -------- fused conversion for w2, w3, w4 (one launch) --------
constexpr int CVA1 = C2P * C1P;                 // 1,392,640
constexpr int CVA2 = CVA1 + C1P * C2P;          // 2,785,280
constexpr int CVTOT = CVA2 + C0P * C1P;         // 21,168,128 (/256 = 82,688)
__global__ void cvt_pad_all(const float* __restrict__ w2, const float* __restrict__ w3,
                            const float* __restrict__ w4, unsigned short* __restrict__ d2,
                            unsigned short* __restrict__ d3, unsigned short* __restrict__ d4) {
  const int i = blockIdx.x * 256 + threadIdx.x;
  if (i < CVA1) {
    const int m = i / C1P, k = i - m * C1P;
    d2[i] = f2bf((m < C2R && k < C1R) ? w2[(size_t)m * C1R + k] : 0.f);
  } else if (i < CVA2) {
    const int j = i - CVA1;
    const int m = j / C2P, k = j - m * C2P;
    d3[j] = f2bf((m < C1R && k < C2R) ? w3[(size_t)m * C2R + k] : 0.f);
  } else {
    const int j = i - CVA2;
    const int m = j / C1P, k = j - m * C1P;
    d4[j] = f2bf((m < C0R && k < C1R) ? w4[(size_t)m * C1R + k] : 0.f);
  }
}

// -------- DCT: x -> H0 bf16 [n=2048][c=8448]  (h = dct/256) --------
__global__ __launch_bounds__(256)
void dct_h0(const float* __restrict__ x, unsigned short* __restrict__ H0) {
  __shared__ float trp[TRS_SZ];
  __shared__ unsigned short hst[256 * 64];
  const int tid = threadIdx.x;
  const int b   = blockIdx.y;
  const int c0  = blockIdx.x * 64;
  const int t = tid >> 4, q = tid & 15;

  for (int g = 0; g < 4; ++g) {
    const int c = c0 + g * 16 + t;
    float p[16];
    {
      float4 v0{}, v1{}, v2{}, v3{};
      if (c < C0R) {
        const int ch = c % 3, gw = (c / 3) % GD, gh = c / (3 * GD);
        const float* xr = x + ((size_t)(b * 3 + ch) * INSZ + (gh * 4 + q)) * INSZ + gw * 4;
        v0 = *(const float4*)(xr);      v1 = *(const float4*)(xr + 4);
        v2 = *(const float4*)(xr + 8);  v3 = *(const float4*)(xr + 12);
      }
      p[0]=v0.x; p[1]=v0.y; p[2]=v0.z; p[3]=v0.w;
      p[4]=v1.x; p[5]=v1.y; p[6]=v1.z; p[7]=v1.w;
      p[8]=v2.x; p[9]=v2.y; p[10]=v2.z; p[11]=v2.w;
      p[12]=v3.x; p[13]=v3.y; p[14]=v3.z; p[15]=v3.w;
    }
    float r[16];
#pragma unroll
    for (int k = 0; k < 16; ++k) {
      float s = 0.f;
#pragma unroll
      for (int n = 0; n < 16; ++n) s += p[n] * Dfwd(k, n);
      r[k] = s;
    }
    float* wr = &trp[t * TRS_T + q * TRS_R];
#pragma unroll
    for (int k = 0; k < 16; k += 4)
      *(float4*)(wr + k) = make_float4(r[k], r[k+1], r[k+2], r[k+3]);
    __syncthreads();
    const int j = q;
    float rr[16];
#pragma unroll
    for (int i = 0; i < 16; ++i) rr[i] = trp[t * TRS_T + i * TRS_R + j];
#pragma unroll
    for (int k = 0; k < 16; ++k) {
      float s = 0.f;
#pragma unroll
      for (int i = 0; i < 16; ++i) s += rr[i] * Dfwd(k, i);
      hst[(k * 16 + j) * 64 + g * 16 + t] = f2bf(s * (1.f / 256.f));
    }
    __syncthreads();
  }
  const size_t base = ((size_t)b * 256) * C0P + c0;
#pragma unroll
  for (int i = 0; i < 8; ++i) {
    const int s = i * 256 + tid;
    const int kl = s >> 3, c16 = s & 7;
    *(uint4*)&H0[base + (size_t)kl * C0P + c16 * 8] = *(const uint4*)&hst[kl * 64 + c16 * 8];
  }
}

// ======== shared GEMM core: 128x128 tile, BK=32, TRIPLE-buffered LDS,
// ======== depth-2 prefetch, counted vmcnt, XOR-swizzled LDS both-sides ========
template<int OUT_NM>
__device__ __forceinline__ void gemm_core(
    const unsigned short* __restrict__ W, const unsigned short* __restrict__ Ht,
    unsigned short (*As)[128 * 32], unsigned short (*Bs)[128 * 32],
    int m0, int n0, int Kp, int kbase, int nkt, int w, int lane, f32x4 acc[4][4]) {
  const int wr = w >> 1, wc = w & 1;
  const int lhi = lane >> 4, llo = lane & 15;

  const int chunk0 = w * 64 + lane;
  const int row0 = chunk0 >> 2, kc0 = chunk0 & 3;
  const int kcg0 = kc0 ^ ((row0 >> 1) & 3);
  const int chunk1 = 256 + w * 64 + lane;
  const int row1 = chunk1 >> 2, kc1 = chunk1 & 3;
  const int kcg1 = kc1 ^ ((row1 >> 1) & 3);

  auto STAGE = [&](int kt, int sel) {   // 4 vmem ops per wave
    const int kb = kbase + kt * 32;
    gload_lds16(W  + (size_t)(m0 + row0) * Kp + kb + kcg0 * 8, &As[sel][(w * 64) * 8]);
    gload_lds16(Ht + (size_t)(n0 + row0) * Kp + kb + kcg0 * 8, &Bs[sel][(w * 64) * 8]);
    gload_lds16(W  + (size_t)(m0 + row1) * Kp + kb + kcg1 * 8, &As[sel][(256 + w * 64) * 8]);
    gload_lds16(Ht + (size_t)(n0 + row1) * Kp + kb + kcg1 * 8, &Bs[sel][(256 + w * 64) * 8]);
  };

  STAGE(0, 0);
  if (nkt > 1) STAGE(1, 1);

  int cur = 0, nxt = 1, nx2 = 2;
  for (int kt = 0; kt < nkt; ++kt) {
    if (kt + 1 < nkt) {
      asm volatile("s_waitcnt vmcnt(4)" ::: "memory");
      __builtin_amdgcn_s_barrier();
      __builtin_amdgcn_sched_barrier(0);
      if (kt + 2 < nkt) STAGE(kt + 2, nx2);
    } else {
      asm volatile("s_waitcnt vmcnt(0)" ::: "memory");
      __builtin_amdgcn_s_barrier();
      __builtin_amdgcn_sched_barrier(0);
    }
    bf16x8 af[4], bfr[4];
#pragma unroll
    for (int mi = 0; mi < 4; ++mi) {
      const int row = wr * 64 + mi * 16 + llo;
      af[mi] = *(const bf16x8*)(&As[cur][row * 32 + (lhi ^ ((row >> 1) & 3)) * 8]);
    }
#pragma unroll
    for (int ni = 0; ni < 4; ++ni) {
      const int row = wc * 64 + ni * 16 + llo;
      bfr[ni] = *(const bf16x8*)(&Bs[cur][row * 32 + (lhi ^ ((row >> 1) & 3)) * 8]);
    }
#pragma unroll
    for (int mi = 0; mi < 4; ++mi)
#pragma unroll
      for (int ni = 0; ni < 4; ++ni) {
        if (OUT_NM)
          acc[mi][ni] = __builtin_amdgcn_mfma_f32_16x16x32_bf16(bfr[ni], af[mi], acc[mi][ni], 0, 0, 0);
        else
          acc[mi][ni] = __builtin_amdgcn_mfma_f32_16x16x32_bf16(af[mi], bfr[ni], acc[mi][ni], 0, 0, 0);
      }
    const int tmp = cur; cur = nxt; nxt = nx2; nx2 = tmp;
  }
}

// -------- direct GEMM with fused epilogue --------
template<int ACT, int OUT_NM>
__global__ __launch_bounds__(256)
void gemm_bt(const unsigned short* __restrict__ W, const unsigned short* __restrict__ Ht,
             const float* __restrict__ bias, int Mreal,
             unsigned short* __restrict__ out, int ldo, int Kp) {
  __shared__ unsigned short As[3][128 * 32];
  __shared__ unsigned short Bs[3][128 * 32];
  int bx, by; xcd_tile(bx, by);
  const int tid = threadIdx.x;
  const int w = tid >> 6, lane = tid & 63;
  const int m0 = bx * 128, n0 = by * 128;
  const int wr = w >> 1, wc = w & 1;
  const int lhi = lane >> 4, llo = lane & 15;

  f32x4 acc[4][4];
#pragma unroll
  for (int i = 0; i < 4; ++i)
#pragma unroll
    for (int j = 0; j < 4; ++j) acc[i][j] = f32x4{0.f, 0.f, 0.f, 0.f};

  gemm_core<OUT_NM>(W, Ht, As, Bs, m0, n0, Kp, 0, Kp >> 5, w, lane, acc);

  if (OUT_NM) {
#pragma unroll
    for (int mi = 0; mi < 4; ++mi) {
      const int mg = m0 + wr * 64 + mi * 16 + llo;
      const float bv = (mg < Mreal) ? bias[mg] : 0.f;
#pragma unroll
      for (int ni = 0; ni < 4; ++ni) {
        const int ng = n0 + wc * 64 + ni * 16 + lhi * 4;
#pragma unroll
        for (int r = 0; r < 4; ++r) {
          float v = acc[mi][ni][r] + bv;
          if (ACT == 1) v = fmaxf(v, 0.f);
          else if (ACT == 2) v = 1.f / (1.f + expf(-v));
          out[(size_t)(ng + r) * ldo + mg] = f2bf(v);
        }
      }
    }
  } else {
#pragma unroll
    for (int mi = 0; mi < 4; ++mi) {
      const int mgb = m0 + wr * 64 + mi * 16 + lhi * 4;
#pragma unroll
      for (int ni = 0; ni < 4; ++ni) {
        const int ng = n0 + wc * 64 + ni * 16 + llo;
#pragma unroll
        for (int r = 0; r < 4; ++r) {
          const int mg = mgb + r;
          float v = acc[mi][ni][r] + ((mg < Mreal) ? bias[mg] : 0.f);
          if (ACT == 1) v = fmaxf(v, 0.f);
          else if (ACT == 2) v = 1.f / (1.f + expf(-v));
          out[(size_t)mg * ldo + ng] = f2bf(v);
        }
      }
    }
  }
}

// -------- split-K GEMM: fp32 partials; chunk = blockIdx.z --------
__global__ __launch_bounds__(256)
void gemm_splitk(const unsigned short* __restrict__ W, const unsigned short* __restrict__ Ht,
                 float* __restrict__ part, int ldo /*Mp*/, int Kp, int chunkK) {
  __shared__ unsigned short As[3][128 * 32];
  __shared__ unsigned short Bs[3][128 * 32];
  int bx, by; xcd_tile(bx, by);
  const int z = blockIdx.z;
  const int tid = threadIdx.x;
  const int w = tid >> 6, lane = tid & 63;
  const int m0 = bx * 128, n0 = by * 128;
  const int wr = w >> 1, wc = w & 1;
  const int lhi = lane >> 4, llo = lane & 15;

  f32x4 acc[4][4];
#pragma unroll
  for (int i = 0; i < 4; ++i)
#pragma unroll
    for (int j = 0; j < 4; ++j) acc[i][j] = f32x4{0.f, 0.f, 0.f, 0.f};

  gemm_core<1>(W, Ht, As, Bs, m0, n0, Kp, z * chunkK, chunkK >> 5, w, lane, acc);

  float* pz = part + (size_t)z * NTOK * ldo;
#pragma unroll
  for (int mi = 0; mi < 4; ++mi) {
    const int mg = m0 + wr * 64 + mi * 16 + llo;
#pragma unroll
    for (int ni = 0; ni < 4; ++ni) {
      const int ng = n0 + wc * 64 + ni * 16 + lhi * 4;
#pragma unroll
      for (int r = 0; r < 4; ++r)
        pz[(size_t)(ng + r) * ldo + mg] = acc[mi][ni][r];
    }
  }
}

// -------- split-K reduce + bias + ReLU -> bf16 [n][m] --------
__global__ __launch_bounds__(256)
void reduce_act(const float* __restrict__ part, const float* __restrict__ bias,
                unsigned short* __restrict__ out, int Mp, int Mreal, int nch) {
  const int i4 = blockIdx.x * 256 + threadIdx.x;
  const int total = NTOK * Mp / 4;
  if (i4 >= total) return;
  const size_t off = (size_t)i4 * 4;
  const int m0 = (int)(off % Mp);
  float s0 = 0.f, s1 = 0.f, s2 = 0.f, s3 = 0.f;
  for (int z = 0; z < nch; ++z) {
    const float4 v = *(const float4*)(part + (size_t)z * NTOK * Mp + off);
    s0 += v.x; s1 += v.y; s2 += v.z; s3 += v.w;
  }
  s0 += (m0 + 0 < Mreal) ? bias[m0 + 0] : 0.f;
  s1 += (m0 + 1 < Mreal) ? bias[m0 + 1] : 0.f;
  s2 += (m0 + 2 < Mreal) ? bias[m0 + 2] : 0.f;
  s3 += (m0 + 3 < Mreal) ? bias[m0 + 3] : 0.f;
  s0 = fmaxf(s0, 0.f); s1 = fmaxf(s1, 0.f); s2 = fmaxf(s2, 0.f); s3 = fmaxf(s3, 0.f);
  uint2 pk;
  pk.x = (unsigned)f2bf(s0) | ((unsigned)f2bf(s1) << 16);
  pk.y = (unsigned)f2bf(s2) | ((unsigned)f2bf(s3) << 16);
  *(uint2*)&out[off] = pk;
}

// -------- recompute fp32 DCT, mask, IDCT, write clean tiles (bf16) --------
__global__ __launch_bounds__(256)
void mask_idct(const float* __restrict__ x, const unsigned short* __restrict__ masks,
               unsigned short* __restrict__ clean) {
  __shared__ float trp[TRS_SZ];
  const int tid = threadIdx.x;
  const int b   = blockIdx.y;
  const int c0  = blockIdx.x * 16;
  const int t = tid >> 4, q = tid & 15;
  const int c = c0 + t;
  const bool valid = (c < C0R);

  float p[16];
  {
    float4 v0{}, v1{}, v2{}, v3{};
    if (valid) {
      const int ch = c % 3, gw = (c / 3) % GD, gh = c / (3 * GD);
      const float* xr = x + ((size_t)(b * 3 + ch) * INSZ + (gh * 4 + q)) * INSZ + gw * 4;
      v0 = *(const float4*)(xr);      v1 = *(const float4*)(xr + 4);
      v2 = *(const float4*)(xr + 8);  v3 = *(const float4*)(xr + 12);
    }
    p[0]=v0.x; p[1]=v0.y; p[2]=v0.z; p[3]=v0.w;
    p[4]=v1.x; p[5]=v1.y; p[6]=v1.z; p[7]=v1.w;
    p[8]=v2.x; p[9]=v2.y; p[10]=v2.z; p[11]=v2.w;
    p[12]=v3.x; p[13]=v3.y; p[14]=v3.z; p[15]=v3.w;
  }
  float r[16];
#pragma unroll
  for (int k = 0; k < 16; ++k) {
    float s = 0.f;
#pragma unroll
    for (int n = 0; n < 16; ++n) s += p[n] * Dfwd(k, n);
    r[k] = s;
  }
  {
    float* wr = &trp[t * TRS_T + q * TRS_R];
#pragma unroll
    for (int k = 0; k < 16; k += 4)
      *(float4*)(wr + k) = make_float4(r[k], r[k+1], r[k+2], r[k+3]);
  }
  __syncthreads();
  const int j = q;
  float rr[16];
#pragma unroll
  for (int i = 0; i < 16; ++i) rr[i] = trp[t * TRS_T + i * TRS_R + j];
  float cd[16];
  const unsigned short* mrow = masks + (size_t)c * NTOK + (size_t)b * 256 + j;
#pragma unroll
  for (int k = 0; k < 16; ++k) {
    float s = 0.f;
#pragma unroll
    for (int i = 0; i < 16; ++i) s += rr[i] * Dfwd(k, i);
    const float mv = valid ? bf2f(mrow[k * 16]) : 0.f;
    cd[k] = s * mv;
  }
  float t3[16];
#pragma unroll
  for (int m = 0; m < 16; ++m) {
    float s = 0.f;
#pragma unroll
    for (int k = 0; k < 16; ++k) s += cd[k] * Dinv(m, k);
    t3[m] = s;
  }
  __syncthreads();
  {
    float* wr = &trp[t * TRS_T + j * TRS_R];
#pragma unroll
    for (int m = 0; m < 16; m += 4)
      *(float4*)(wr + m) = make_float4(t3[m], t3[m+1], t3[m+2], t3[m+3]);
  }
  __syncthreads();
  float tr[16];
#pragma unroll
  for (int l = 0; l < 16; ++l) tr[l] = trp[t * TRS_T + l * TRS_R + q];
  if (valid) {
    unsigned pk[8];
#pragma unroll
    for (int n2 = 0; n2 < 8; ++n2) {
      float s0 = 0.f, s1 = 0.f;
#pragma unroll
      for (int l = 0; l < 16; ++l) {
        s0 += tr[l] * Dinv(2 * n2, l);
        s1 += tr[l] * Dinv(2 * n2 + 1, l);
      }
      pk[n2] = (unsigned)f2bf(s0) | ((unsigned)f2bf(s1) << 16);
    }
    unsigned short* dst = clean + ((size_t)b * C0R + c) * 256 + q * 16;
    uint4* d4 = (uint4*)dst;
    d4[0] = make_uint4(pk[0], pk[1], pk[2], pk[3]);
    d4[1] = make_uint4(pk[4], pk[5], pk[6], pk[7]);
  }
}

// -------- overlap-add gather + count normalization --------
__global__ void overlap_add(const unsigned short* __restrict__ clean, float* __restrict__ out) {
  const int px = blockIdx.x * 256 + threadIdx.x;
  if (px >= 8 * 3 * 224 * 224) return;
  const int j = px % 224;
  const int i = (px / 224) % 224;
  const int bc = px / (224 * 224);
  const int ch = bc % 3, b = bc / 3;
  const int ilo = i - 15;
  const int ghlo = ilo > 0 ? (ilo + 3) >> 2 : 0;
  const int ghhi = (i >> 2) < 52 ? (i >> 2) : 52;
  const int jlo = j - 15;
  const int gwlo = jlo > 0 ? (jlo + 3) >> 2 : 0;
  const int gwhi = (j >> 2) < 52 ? (j >> 2) : 52;
  float sum = 0.f;
  for (int gh = ghlo; gh <= ghhi; ++gh) {
    const int r = i - gh * 4;
    const size_t base = ((size_t)b * C0R + (size_t)gh * (3 * GD) + ch) * 256 + (size_t)r * 16 + j;
    for (int gw = gwlo; gw <= gwhi; ++gw) {
      sum += bf2f(clean[base + (size_t)gw * 764]);
    }
  }
  const int cnt = (ghhi - ghlo + 1) * (gwhi - gwlo + 1);
  out[px] = sum / (float)cnt;
}

extern "C" void kernel_launch(void* const* d_in, const int* in_sizes, int n_in,
                              void* d_out, int out_size, void* d_ws, size_t ws_size,
                              hipStream_t stream) {
  const float* x  = (const float*)d_in[0];
  const float* w1 = (const float*)d_in[1];
  const float* b1 = (const float*)d_in[2];
  const float* w2 = (const float*)d_in[3];
  const float* b2 = (const float*)d_in[4];
  const float* w3 = (const float*)d_in[5];
  const float* b3 = (const float*)d_in[6];
  const float* w4 = (const float*)d_in[7];
  const float* b4 = (const float*)d_in[8];
  float* out = (float*)d_out;
  char* ws = (char*)d_ws;

  // ---- workspace layout (peak 133.8 MB) ----
  const size_t S_WB1  = (size_t)C1P * C0P * 2;
  const size_t S_H0   = (size_t)NTOK * C0P * 2;
  const size_t S_PART = (size_t)3 * NTOK * C1P * 4;
  const size_t OFF_WB1  = 0;
  const size_t OFF_H0   = OFF_WB1 + S_WB1;
  const size_t OFF_PART = OFF_H0 + S_H0;
  const size_t OFF_Y1   = OFF_PART + S_PART;

  unsigned short* wb1 = (unsigned short*)(ws + OFF_WB1);
  unsigned short* H0v = (unsigned short*)(ws + OFF_H0);
  float*          pt1 = (float*)(ws + OFF_PART);
  unsigned short* Y1  = (unsigned short*)(ws + OFF_Y1);
  unsigned short* wb2 = (unsigned short*)(ws + OFF_PART);
  unsigned short* wb3 = (unsigned short*)(ws + OFF_PART + (size_t)C2P * C1P * 2);
  unsigned short* wb4 = (unsigned short*)(ws + OFF_PART + (size_t)2 * C2P * C1P * 2);
  unsigned short* Y2  = (unsigned short*)(ws + OFF_PART + (size_t)2 * C2P * C1P * 2 + (size_t)C0P * C1P * 2);
  float*          pt2 = (float*)(ws + OFF_WB1);
  float*          pt3 = (float*)(ws + OFF_WB1);
  unsigned short* clean = (unsigned short*)(ws + OFF_WB1);
  unsigned short* Y3  = (unsigned short*)(ws + OFF_Y1);
  unsigned short* msk = (unsigned short*)(ws + OFF_H0);

  // 1. stage inputs for GEMM1
  cvt_pad<<<dim3((C0P + 255) / 256, C1P), 256, 0, stream>>>(w1, wb1, C1R, C0R, C0P);
  dct_h0<<<dim3(C0P / 64, 8), 256, 0, stream>>>(x, H0v);

  // 2. GEMM1 split-K x3 (chunk 2816), reduce -> Y1
  gemm_splitk<<<dim3(C1P / 128, NTOK / 128, 3), 256, 0, stream>>>(wb1, H0v, pt1, C1P, C0P, 2816);
  reduce_act<<<dim3(NTOK * C1P / 4 / 256), 256, 0, stream>>>(pt1, b1, Y1, C1P, C1R, 3);

  // 3. remaining weight conversions (single launch, into dead PART slot)
  cvt_pad_all<<<dim3(CVTOT / 256), 256, 0, stream>>>(w2, w3, w4, wb2, wb3, wb4);

  // 4. GEMM2 split-K x4 (chunk 544) -> Y2
  gemm_splitk<<<dim3(C2P / 128, NTOK / 128, 4), 256, 0, stream>>>(wb2, Y1, pt2, C2P, C1P, 544);
  reduce_act<<<dim3(NTOK * C2P / 4 / 256), 256, 0, stream>>>(pt2, b2, Y2, C2P, C2R, 4);

  // 5. GEMM3 split-K x2 (chunk 320) -> Y3 (Y1 slot)
  gemm_splitk<<<dim3(C1P / 128, NTOK / 128, 2), 256, 0, stream>>>(wb3, Y2, pt3, C1P, C2P, 320);
  reduce_act<<<dim3(NTOK * C1P / 4 / 256), 256, 0, stream>>>(pt3, b3, Y3, C1P, C1R, 2);

  // 6. GEMM4 direct (sigmoid, out [m][n]) -> masks (H0 slot)
  gemm_bt<2, 0><<<dim3(C0P / 128, NTOK / 128), 256, 0, stream>>>(wb4, Y3, b4, C0R, msk, NTOK, C1P);

  // 7. mask*DCT -> IDCT -> clean (bf16, WB1 slot)
  mask_idct<<<dim3((C0R + 15) / 16, 8), 256, 0, stream>>>(x, msk, clean);

  // 8. overlap-add + normalize
  overlap_add<<<dim3((8 * 3 * 224 * 224 + 255) / 256), 256, 0, stream>>>(clean, out);
}

// Round 7
// 434.440 us; speedup vs baseline: 1.6358x; 1.0739x over previous
//
#include <hip/hip_runtime.h>
#include <stdint.h>

constexpr int INSZ = 224;
constexpr int GD   = 53;
constexpr int C0R = 8427, C1R = 2106, C2R = 526;
constexpr int C0P = 8448, C1P = 2304, C2P = 640;   // C1P padded to 9*256
constexpr int NTOK = 2048; // 8 batches * 256 DCT positions

typedef __attribute__((ext_vector_type(4))) float f32x4;
typedef __attribute__((ext_vector_type(8))) short bf16x8;

// cos(pi*j/32) for j=0..63 (period 64)
constexpr float CT[64] = {
  1.00000000f,  0.99518473f,  0.98078528f,  0.95694034f,
  0.92387953f,  0.88192126f,  0.83146961f,  0.77301045f,
  0.70710678f,  0.63439328f,  0.55557023f,  0.47139674f,
  0.38268343f,  0.29028468f,  0.19509032f,  0.09801714f,
  0.00000000f, -0.09801714f, -0.19509032f, -0.29028468f,
 -0.38268343f, -0.47139674f, -0.55557023f, -0.63439328f,
 -0.70710678f, -0.77301045f, -0.83146961f, -0.88192126f,
 -0.92387953f, -0.95694034f, -0.98078528f, -0.99518473f,
 -1.00000000f, -0.99518473f, -0.98078528f, -0.95694034f,
 -0.92387953f, -0.88192126f, -0.83146961f, -0.77301045f,
 -0.70710678f, -0.63439328f, -0.55557023f, -0.47139674f,
 -0.38268343f, -0.29028468f, -0.19509032f, -0.09801714f,
 -0.00000000f,  0.09801714f,  0.19509032f,  0.29028468f,
  0.38268343f,  0.47139674f,  0.55557023f,  0.63439328f,
  0.70710678f,  0.77301045f,  0.83146961f,  0.88192126f,
  0.92387953f,  0.95694034f,  0.98078528f,  0.99518473f
};
constexpr float Dfwd(int k, int n) { return 2.0f * CT[((2 * n + 1) * k) & 63]; }
constexpr float Dinv(int n, int k) { return CT[((2 * n + 1) * k) & 63] * (k == 0 ? 0.03125f : 0.0625f); }

// transpose scratch strides (floats)
constexpr int TRS_R = 20, TRS_T = 336;
constexpr int TRS_SZ = 15 * TRS_T + 15 * TRS_R + 16;

__device__ __forceinline__ unsigned short f2bf(float f) {
  union { float f; unsigned u; } v; v.f = f;
  return (unsigned short)((v.u + 0x7FFFu + ((v.u >> 16) & 1u)) >> 16);
}
__device__ __forceinline__ float bf2f(unsigned short b) {
  union { unsigned u; float f; } v; v.u = ((unsigned)b) << 16;
  return v.f;
}

__device__ __forceinline__ void gload_lds16(const void* g, void* l) {
  __builtin_amdgcn_global_load_lds(
      (__attribute__((address_space(1))) unsigned int*)(uintptr_t)g,
      (__attribute__((address_space(3))) unsigned int*)(unsigned int)(uintptr_t)l,
      16, 0, 0);
}

// XCD swizzle + L2 supertiling (4-wide bx stripes, by inner). requires (gx*gy)%8==0
__device__ __forceinline__ void xcd_tile(int& bx, int& by) {
  const int gx = gridDim.x, gy = gridDim.y;
  const int nwg = gx * gy;
  const int bid = blockIdx.y * gx + blockIdx.x;
  const int cpx = nwg >> 3;
  const int l = (bid & 7) * cpx + (bid >> 3);
  const int stripe = gy << 2;
  const int bxg = l / stripe;
  const int r = l - bxg * stripe;
  const int rem = gx - (bxg << 2);
  const int w = rem < 4 ? rem : 4;
  by = r / w;
  bx = (bxg << 2) + (r - by * w);
}

// -------- weight fp32 -> bf16 with zero padding (w1) --------
__global__ void cvt_pad(const float* __restrict__ src, unsigned short* __restrict__ dst,
                        int M, int K, int Kp) {
  const int k = blockIdx.x * 256 + threadIdx.x;
  const int m = blockIdx.y;
  if (k >= Kp) return;
  const float v = (m < M && k < K) ? src[(size_t)m * K + k] : 0.f;
  dst[(size_t)m * Kp + k] = f2bf(v);
}

// -------- fused conversion for w2, w3, w4 (one launch) --------
constexpr int CVA1 = C2P * C1P;
constexpr int CVA2 = CVA1 + C1P * C2P;
constexpr int CVTOT = CVA2 + C0P * C1P;   // divisible by 256
__global__ void cvt_pad_all(const float* __restrict__ w2, const float* __restrict__ w3,
                            const float* __restrict__ w4, unsigned short* __restrict__ d2,
                            unsigned short* __restrict__ d3, unsigned short* __restrict__ d4) {
  const int i = blockIdx.x * 256 + threadIdx.x;
  if (i < CVA1) {
    const int m = i / C1P, k = i - m * C1P;
    d2[i] = f2bf((m < C2R && k < C1R) ? w2[(size_t)m * C1R + k] : 0.f);
  } else if (i < CVA2) {
    const int j = i - CVA1;
    const int m = j / C2P, k = j - m * C2P;
    d3[j] = f2bf((m < C1R && k < C2R) ? w3[(size_t)m * C2R + k] : 0.f);
  } else {
    const int j = i - CVA2;
    const int m = j / C1P, k = j - m * C1P;
    d4[j] = f2bf((m < C0R && k < C1R) ? w4[(size_t)m * C1R + k] : 0.f);
  }
}

// -------- DCT: x -> H0 bf16 [n=2048][c=8448]  (h = dct/256) --------
__global__ __launch_bounds__(256)
void dct_h0(const float* __restrict__ x, unsigned short* __restrict__ H0) {
  __shared__ float trp[TRS_SZ];
  __shared__ unsigned short hst[256 * 64];
  const int tid = threadIdx.x;
  const int b   = blockIdx.y;
  const int c0  = blockIdx.x * 64;
  const int t = tid >> 4, q = tid & 15;

  for (int g = 0; g < 4; ++g) {
    const int c = c0 + g * 16 + t;
    float p[16];
    {
      float4 v0{}, v1{}, v2{}, v3{};
      if (c < C0R) {
        const int ch = c % 3, gw = (c / 3) % GD, gh = c / (3 * GD);
        const float* xr = x + ((size_t)(b * 3 + ch) * INSZ + (gh * 4 + q)) * INSZ + gw * 4;
        v0 = *(const float4*)(xr);      v1 = *(const float4*)(xr + 4);
        v2 = *(const float4*)(xr + 8);  v3 = *(const float4*)(xr + 12);
      }
      p[0]=v0.x; p[1]=v0.y; p[2]=v0.z; p[3]=v0.w;
      p[4]=v1.x; p[5]=v1.y; p[6]=v1.z; p[7]=v1.w;
      p[8]=v2.x; p[9]=v2.y; p[10]=v2.z; p[11]=v2.w;
      p[12]=v3.x; p[13]=v3.y; p[14]=v3.z; p[15]=v3.w;
    }
    float r[16];
#pragma unroll
    for (int k = 0; k < 16; ++k) {
      float s = 0.f;
#pragma unroll
      for (int n = 0; n < 16; ++n) s += p[n] * Dfwd(k, n);
      r[k] = s;
    }
    float* wr = &trp[t * TRS_T + q * TRS_R];
#pragma unroll
    for (int k = 0; k < 16; k += 4)
      *(float4*)(wr + k) = make_float4(r[k], r[k+1], r[k+2], r[k+3]);
    __syncthreads();
    const int j = q;
    float rr[16];
#pragma unroll
    for (int i = 0; i < 16; ++i) rr[i] = trp[t * TRS_T + i * TRS_R + j];
#pragma unroll
    for (int k = 0; k < 16; ++k) {
      float s = 0.f;
#pragma unroll
      for (int i = 0; i < 16; ++i) s += rr[i] * Dfwd(k, i);
      hst[(k * 16 + j) * 64 + g * 16 + t] = f2bf(s * (1.f / 256.f));
    }
    __syncthreads();
  }
  const size_t base = ((size_t)b * 256) * C0P + c0;
#pragma unroll
  for (int i = 0; i < 8; ++i) {
    const int s = i * 256 + tid;
    const int kl = s >> 3, c16 = s & 7;
    *(uint4*)&H0[base + (size_t)kl * C0P + c16 * 8] = *(const uint4*)&hst[kl * 64 + c16 * 8];
  }
}

// ======== 256x256 deep-pipelined GEMM: BK=32, 8 waves (2M x 4N), wave tile 128x64,
// ======== 3 LDS bufs, stage distance 2 K-tiles, counted vmcnt(4) (never 0 in loop),
// ======== 2 phases/K-tile (m-half), B-frags reused, XOR swizzle both-sides, setprio.
template<int ACT, int OUT_NM, int SPLITK>
__global__ __launch_bounds__(512, 2)
void gemm256(const unsigned short* __restrict__ W, const unsigned short* __restrict__ Ht,
             const float* __restrict__ bias, void* __restrict__ outp,
             int ldo, int Kp, int chunkK) {
  __shared__ unsigned short As[3][8192];  // [buf][256 rows][32 K] (16B-chunk swizzled)
  __shared__ unsigned short Bs[3][8192];
  int bx, by; xcd_tile(bx, by);
  const int m0 = bx * 256, n0 = by * 256;
  const int tid = threadIdx.x;
  const int w = tid >> 6, lane = tid & 63;
  const int wr = w >> 2, wc = w & 3;
  const int lhi = lane >> 4, llo = lane & 15;
  const int kbase = SPLITK ? blockIdx.z * chunkK : 0;
  const int nkt = chunkK >> 5;

  const int srow = tid >> 2;                                  // 0..127
  const int slgc = ((tid & 3) ^ ((srow >> 1) & 3)) * 8;       // pre-swizzled global col

  f32x4 acc[8][4];
#pragma unroll
  for (int i = 0; i < 8; ++i)
#pragma unroll
    for (int j = 0; j < 4; ++j) acc[i][j] = f32x4{0.f, 0.f, 0.f, 0.f};

  auto STAGE_A = [&](int kt, int buf) {   // 2 gloads: A rows 0-127, 128-255
    const int kb = kbase + kt * 32 + slgc;
    gload_lds16(W + (size_t)(m0 + srow) * Kp + kb,       &As[buf][w * 512]);
    gload_lds16(W + (size_t)(m0 + 128 + srow) * Kp + kb, &As[buf][4096 + w * 512]);
  };
  auto STAGE_B = [&](int kt, int buf) {
    const int kb = kbase + kt * 32 + slgc;
    gload_lds16(Ht + (size_t)(n0 + srow) * Kp + kb,       &Bs[buf][w * 512]);
    gload_lds16(Ht + (size_t)(n0 + 128 + srow) * Kp + kb, &Bs[buf][4096 + w * 512]);
  };

  STAGE_A(0, 0); STAGE_B(0, 0);
  if (nkt > 1) { STAGE_A(1, 1); STAGE_B(1, 1); }

  int buf = 0;
  for (int kt = 0; kt < nkt; ++kt) {
    const int sbuf = buf >= 1 ? buf - 1 : 2;   // (kt+2)%3
    if (kt + 1 < nkt) asm volatile("s_waitcnt vmcnt(4)" ::: "memory");
    else              asm volatile("s_waitcnt vmcnt(0)" ::: "memory");
    __builtin_amdgcn_s_barrier();
    __builtin_amdgcn_sched_barrier(0);

    bf16x8 af[4], bfr[4];
    // ---- phase A: m-half 0, read all B frags (kept for phase B) ----
#pragma unroll
    for (int mi = 0; mi < 4; ++mi) {
      const int row = wr * 128 + mi * 16 + llo;
      af[mi] = *(const bf16x8*)(&As[buf][row * 32 + ((lhi ^ ((row >> 1) & 3)) << 3)]);
    }
#pragma unroll
    for (int ni = 0; ni < 4; ++ni) {
      const int row = wc * 64 + ni * 16 + llo;
      bfr[ni] = *(const bf16x8*)(&Bs[buf][row * 32 + ((lhi ^ ((row >> 1) & 3)) << 3)]);
    }
    if (kt + 2 < nkt) STAGE_A(kt + 2, sbuf);
    __builtin_amdgcn_s_setprio(1);
#pragma unroll
    for (int mi = 0; mi < 4; ++mi)
#pragma unroll
      for (int ni = 0; ni < 4; ++ni)
        acc[mi][ni] = OUT_NM
          ? __builtin_amdgcn_mfma_f32_16x16x32_bf16(bfr[ni], af[mi], acc[mi][ni], 0, 0, 0)
          : __builtin_amdgcn_mfma_f32_16x16x32_bf16(af[mi], bfr[ni], acc[mi][ni], 0, 0, 0);
    __builtin_amdgcn_s_setprio(0);
    __builtin_amdgcn_s_barrier();
    __builtin_amdgcn_sched_barrier(0);
    // ---- phase B: m-half 1, reuse bfr ----
#pragma unroll
    for (int mi = 0; mi < 4; ++mi) {
      const int row = wr * 128 + 64 + mi * 16 + llo;
      af[mi] = *(const bf16x8*)(&As[buf][row * 32 + ((lhi ^ ((row >> 1) & 3)) << 3)]);
    }
    if (kt + 2 < nkt) STAGE_B(kt + 2, sbuf);
    __builtin_amdgcn_s_setprio(1);
#pragma unroll
    for (int mi = 0; mi < 4; ++mi)
#pragma unroll
      for (int ni = 0; ni < 4; ++ni)
        acc[4 + mi][ni] = OUT_NM
          ? __builtin_amdgcn_mfma_f32_16x16x32_bf16(bfr[ni], af[mi], acc[4 + mi][ni], 0, 0, 0)
          : __builtin_amdgcn_mfma_f32_16x16x32_bf16(af[mi], bfr[ni], acc[4 + mi][ni], 0, 0, 0);
    __builtin_amdgcn_s_setprio(0);
    buf = buf == 2 ? 0 : buf + 1;
  }

  if (SPLITK) {
    float* pz = (float*)outp + (size_t)blockIdx.z * ((size_t)NTOK * ldo);
#pragma unroll
    for (int mh = 0; mh < 2; ++mh)
#pragma unroll
      for (int mi = 0; mi < 4; ++mi) {
        const int mg = m0 + wr * 128 + mh * 64 + mi * 16 + llo;
#pragma unroll
        for (int ni = 0; ni < 4; ++ni) {
          const int ng = n0 + wc * 64 + ni * 16 + lhi * 4;
#pragma unroll
          for (int r = 0; r < 4; ++r)
            pz[(size_t)(ng + r) * ldo + mg] = acc[mh * 4 + mi][ni][r];
        }
      }
  } else {
    unsigned short* out = (unsigned short*)outp;
#pragma unroll
    for (int mh = 0; mh < 2; ++mh)
#pragma unroll
      for (int mi = 0; mi < 4; ++mi) {
        const int mgb = m0 + wr * 128 + mh * 64 + mi * 16 + lhi * 4;
#pragma unroll
        for (int ni = 0; ni < 4; ++ni) {
          const int ng = n0 + wc * 64 + ni * 16 + llo;
#pragma unroll
          for (int r = 0; r < 4; ++r) {
            const int mg = mgb + r;
            float v = acc[mh * 4 + mi][ni][r] + bias[mg];
            if (ACT == 1) v = fmaxf(v, 0.f);
            else if (ACT == 2) v = 1.f / (1.f + expf(-v));
            out[(size_t)mg * ldo + ng] = f2bf(v);
          }
        }
      }
  }
}

// ======== old 128x128 core (GEMM2/3 + GEMM4 tail) ========
template<int OUT_NM>
__device__ __forceinline__ void gemm_core(
    const unsigned short* __restrict__ W, const unsigned short* __restrict__ Ht,
    unsigned short (*As)[128 * 32], unsigned short (*Bs)[128 * 32],
    int m0, int n0, int Kp, int kbase, int nkt, int w, int lane, f32x4 acc[4][4]) {
  const int wr = w >> 1, wc = w & 1;
  const int lhi = lane >> 4, llo = lane & 15;

  const int chunk0 = w * 64 + lane;
  const int row0 = chunk0 >> 2, kc0 = chunk0 & 3;
  const int kcg0 = kc0 ^ ((row0 >> 1) & 3);
  const int chunk1 = 256 + w * 64 + lane;
  const int row1 = chunk1 >> 2, kc1 = chunk1 & 3;
  const int kcg1 = kc1 ^ ((row1 >> 1) & 3);

  auto STAGE = [&](int kt, int sel) {
    const int kb = kbase + kt * 32;
    gload_lds16(W  + (size_t)(m0 + row0) * Kp + kb + kcg0 * 8, &As[sel][(w * 64) * 8]);
    gload_lds16(Ht + (size_t)(n0 + row0) * Kp + kb + kcg0 * 8, &Bs[sel][(w * 64) * 8]);
    gload_lds16(W  + (size_t)(m0 + row1) * Kp + kb + kcg1 * 8, &As[sel][(256 + w * 64) * 8]);
    gload_lds16(Ht + (size_t)(n0 + row1) * Kp + kb + kcg1 * 8, &Bs[sel][(256 + w * 64) * 8]);
  };

  STAGE(0, 0);
  if (nkt > 1) STAGE(1, 1);

  int cur = 0, nxt = 1, nx2 = 2;
  for (int kt = 0; kt < nkt; ++kt) {
    if (kt + 1 < nkt) {
      asm volatile("s_waitcnt vmcnt(4)" ::: "memory");
      __builtin_amdgcn_s_barrier();
      __builtin_amdgcn_sched_barrier(0);
      if (kt + 2 < nkt) STAGE(kt + 2, nx2);
    } else {
      asm volatile("s_waitcnt vmcnt(0)" ::: "memory");
      __builtin_amdgcn_s_barrier();
      __builtin_amdgcn_sched_barrier(0);
    }
    bf16x8 af[4], bfr[4];
#pragma unroll
    for (int mi = 0; mi < 4; ++mi) {
      const int row = wr * 64 + mi * 16 + llo;
      af[mi] = *(const bf16x8*)(&As[cur][row * 32 + (lhi ^ ((row >> 1) & 3)) * 8]);
    }
#pragma unroll
    for (int ni = 0; ni < 4; ++ni) {
      const int row = wc * 64 + ni * 16 + llo;
      bfr[ni] = *(const bf16x8*)(&Bs[cur][row * 32 + (lhi ^ ((row >> 1) & 3)) * 8]);
    }
#pragma unroll
    for (int mi = 0; mi < 4; ++mi)
#pragma unroll
      for (int ni = 0; ni < 4; ++ni) {
        if (OUT_NM)
          acc[mi][ni] = __builtin_amdgcn_mfma_f32_16x16x32_bf16(bfr[ni], af[mi], acc[mi][ni], 0, 0, 0);
        else
          acc[mi][ni] = __builtin_amdgcn_mfma_f32_16x16x32_bf16(af[mi], bfr[ni], acc[mi][ni], 0, 0, 0);
      }
    const int tmp = cur; cur = nxt; nxt = nx2; nx2 = tmp;
  }
}

template<int ACT, int OUT_NM>
__global__ __launch_bounds__(256)
void gemm_bt(const unsigned short* __restrict__ W, const unsigned short* __restrict__ Ht,
             const float* __restrict__ bias, int Mreal,
             unsigned short* __restrict__ out, int ldo, int Kp) {
  __shared__ unsigned short As[3][128 * 32];
  __shared__ unsigned short Bs[3][128 * 32];
  int bx, by; xcd_tile(bx, by);
  const int tid = threadIdx.x;
  const int w = tid >> 6, lane = tid & 63;
  const int m0 = bx * 128, n0 = by * 128;
  const int wr = w >> 1, wc = w & 1;
  const int lhi = lane >> 4, llo = lane & 15;

  f32x4 acc[4][4];
#pragma unroll
  for (int i = 0; i < 4; ++i)
#pragma unroll
    for (int j = 0; j < 4; ++j) acc[i][j] = f32x4{0.f, 0.f, 0.f, 0.f};

  gemm_core<OUT_NM>(W, Ht, As, Bs, m0, n0, Kp, 0, Kp >> 5, w, lane, acc);

  if (OUT_NM) {
#pragma unroll
    for (int mi = 0; mi < 4; ++mi) {
      const int mg = m0 + wr * 64 + mi * 16 + llo;
      const float bv = (mg < Mreal) ? bias[mg] : 0.f;
#pragma unroll
      for (int ni = 0; ni < 4; ++ni) {
        const int ng = n0 + wc * 64 + ni * 16 + lhi * 4;
#pragma unroll
        for (int r = 0; r < 4; ++r) {
          float v = acc[mi][ni][r] + bv;
          if (ACT == 1) v = fmaxf(v, 0.f);
          else if (ACT == 2) v = 1.f / (1.f + expf(-v));
          out[(size_t)(ng + r) * ldo + mg] = f2bf(v);
        }
      }
    }
  } else {
#pragma unroll
    for (int mi = 0; mi < 4; ++mi) {
      const int mgb = m0 + wr * 64 + mi * 16 + lhi * 4;
#pragma unroll
      for (int ni = 0; ni < 4; ++ni) {
        const int ng = n0 + wc * 64 + ni * 16 + llo;
#pragma unroll
        for (int r = 0; r < 4; ++r) {
          const int mg = mgb + r;
          float v = acc[mi][ni][r] + ((mg < Mreal) ? bias[mg] : 0.f);
          if (ACT == 1) v = fmaxf(v, 0.f);
          else if (ACT == 2) v = 1.f / (1.f + expf(-v));
          out[(size_t)mg * ldo + ng] = f2bf(v);
        }
      }
    }
  }
}

__global__ __launch_bounds__(256)
void gemm_splitk(const unsigned short* __restrict__ W, const unsigned short* __restrict__ Ht,
                 float* __restrict__ part, int ldo /*Mp*/, int Kp, int chunkK) {
  __shared__ unsigned short As[3][128 * 32];
  __shared__ unsigned short Bs[3][128 * 32];
  int bx, by; xcd_tile(bx, by);
  const int z = blockIdx.z;
  const int tid = threadIdx.x;
  const int w = tid >> 6, lane = tid & 63;
  const int m0 = bx * 128, n0 = by * 128;
  const int wr = w >> 1, wc = w & 1;
  const int lhi = lane >> 4, llo = lane & 15;

  f32x4 acc[4][4];
#pragma unroll
  for (int i = 0; i < 4; ++i)
#pragma unroll
    for (int j = 0; j < 4; ++j) acc[i][j] = f32x4{0.f, 0.f, 0.f, 0.f};

  gemm_core<1>(W, Ht, As, Bs, m0, n0, Kp, z * chunkK, chunkK >> 5, w, lane, acc);

  float* pz = part + (size_t)z * NTOK * ldo;
#pragma unroll
  for (int mi = 0; mi < 4; ++mi) {
    const int mg = m0 + wr * 64 + mi * 16 + llo;
#pragma unroll
    for (int ni = 0; ni < 4; ++ni) {
      const int ng = n0 + wc * 64 + ni * 16 + lhi * 4;
#pragma unroll
      for (int r = 0; r < 4; ++r)
        pz[(size_t)(ng + r) * ldo + mg] = acc[mi][ni][r];
    }
  }
}

// -------- split-K reduce + bias + ReLU -> bf16 [n][m] --------
__global__ __launch_bounds__(256)
void reduce_act(const float* __restrict__ part, const float* __restrict__ bias,
                unsigned short* __restrict__ out, int Mp, int Mreal, int nch) {
  const int i4 = blockIdx.x * 256 + threadIdx.x;
  const int total = NTOK * Mp / 4;
  if (i4 >= total) return;
  const size_t off = (size_t)i4 * 4;
  const int m0 = (int)(off % Mp);
  float s0 = 0.f, s1 = 0.f, s2 = 0.f, s3 = 0.f;
  for (int z = 0; z < nch; ++z) {
    const float4 v = *(const float4*)(part + (size_t)z * NTOK * Mp + off);
    s0 += v.x; s1 += v.y; s2 += v.z; s3 += v.w;
  }
  s0 += (m0 + 0 < Mreal) ? bias[m0 + 0] : 0.f;
  s1 += (m0 + 1 < Mreal) ? bias[m0 + 1] : 0.f;
  s2 += (m0 + 2 < Mreal) ? bias[m0 + 2] : 0.f;
  s3 += (m0 + 3 < Mreal) ? bias[m0 + 3] : 0.f;
  s0 = fmaxf(s0, 0.f); s1 = fmaxf(s1, 0.f); s2 = fmaxf(s2, 0.f); s3 = fmaxf(s3, 0.f);
  uint2 pk;
  pk.x = (unsigned)f2bf(s0) | ((unsigned)f2bf(s1) << 16);
  pk.y = (unsigned)f2bf(s2) | ((unsigned)f2bf(s3) << 16);
  *(uint2*)&out[off] = pk;
}

// -------- recompute fp32 DCT, mask, IDCT, write clean tiles (bf16) --------
__global__ __launch_bounds__(256)
void mask_idct(const float* __restrict__ x, const unsigned short* __restrict__ masks,
               unsigned short* __restrict__ clean) {
  __shared__ float trp[TRS_SZ];
  const int tid = threadIdx.x;
  const int b   = blockIdx.y;
  const int c0  = blockIdx.x * 16;
  const int t = tid >> 4, q = tid & 15;
  const int c = c0 + t;
  const bool valid = (c < C0R);

  float p[16];
  {
    float4 v0{}, v1{}, v2{}, v3{};
    if (valid) {
      const int ch = c % 3, gw = (c / 3) % GD, gh = c / (3 * GD);
      const float* xr = x + ((size_t)(b * 3 + ch) * INSZ + (gh * 4 + q)) * INSZ + gw * 4;
      v0 = *(const float4*)(xr);      v1 = *(const float4*)(xr + 4);
      v2 = *(const float4*)(xr + 8);  v3 = *(const float4*)(xr + 12);
    }
    p[0]=v0.x; p[1]=v0.y; p[2]=v0.z; p[3]=v0.w;
    p[4]=v1.x; p[5]=v1.y; p[6]=v1.z; p[7]=v1.w;
    p[8]=v2.x; p[9]=v2.y; p[10]=v2.z; p[11]=v2.w;
    p[12]=v3.x; p[13]=v3.y; p[14]=v3.z; p[15]=v3.w;
  }
  float r[16];
#pragma unroll
  for (int k = 0; k < 16; ++k) {
    float s = 0.f;
#pragma unroll
    for (int n = 0; n < 16; ++n) s += p[n] * Dfwd(k, n);
    r[k] = s;
  }
  {
    float* wr = &trp[t * TRS_T + q * TRS_R];
#pragma unroll
    for (int k = 0; k < 16; k += 4)
      *(float4*)(wr + k) = make_float4(r[k], r[k+1], r[k+2], r[k+3]);
  }
  __syncthreads();
  const int j = q;
  float rr[16];
#pragma unroll
  for (int i = 0; i < 16; ++i) rr[i] = trp[t * TRS_T + i * TRS_R + j];
  float cd[16];
  const unsigned short* mrow = masks + (size_t)c * NTOK + (size_t)b * 256 + j;
#pragma unroll
  for (int k = 0; k < 16; ++k) {
    float s = 0.f;
#pragma unroll
    for (int i = 0; i < 16; ++i) s += rr[i] * Dfwd(k, i);
    const float mv = valid ? bf2f(mrow[k * 16]) : 0.f;
    cd[k] = s * mv;
  }
  float t3[16];
#pragma unroll
  for (int m = 0; m < 16; ++m) {
    float s = 0.f;
#pragma unroll
    for (int k = 0; k < 16; ++k) s += cd[k] * Dinv(m, k);
    t3[m] = s;
  }
  __syncthreads();
  {
    float* wr = &trp[t * TRS_T + j * TRS_R];
#pragma unroll
    for (int m = 0; m < 16; m += 4)
      *(float4*)(wr + m) = make_float4(t3[m], t3[m+1], t3[m+2], t3[m+3]);
  }
  __syncthreads();
  float tr[16];
#pragma unroll
  for (int l = 0; l < 16; ++l) tr[l] = trp[t * TRS_T + l * TRS_R + q];
  if (valid) {
    unsigned pk[8];
#pragma unroll
    for (int n2 = 0; n2 < 8; ++n2) {
      float s0 = 0.f, s1 = 0.f;
#pragma unroll
      for (int l = 0; l < 16; ++l) {
        s0 += tr[l] * Dinv(2 * n2, l);
        s1 += tr[l] * Dinv(2 * n2 + 1, l);
      }
      pk[n2] = (unsigned)f2bf(s0) | ((unsigned)f2bf(s1) << 16);
    }
    unsigned short* dst = clean + ((size_t)b * C0R + c) * 256 + q * 16;
    uint4* d4 = (uint4*)dst;
    d4[0] = make_uint4(pk[0], pk[1], pk[2], pk[3]);
    d4[1] = make_uint4(pk[4], pk[5], pk[6], pk[7]);
  }
}

// -------- overlap-add gather + count normalization --------
__global__ void overlap_add(const unsigned short* __restrict__ clean, float* __restrict__ out) {
  const int px = blockIdx.x * 256 + threadIdx.x;
  if (px >= 8 * 3 * 224 * 224) return;
  const int j = px % 224;
  const int i = (px / 224) % 224;
  const int bc = px / (224 * 224);
  const int ch = bc % 3, b = bc / 3;
  const int ilo = i - 15;
  const int ghlo = ilo > 0 ? (ilo + 3) >> 2 : 0;
  const int ghhi = (i >> 2) < 52 ? (i >> 2) : 52;
  const int jlo = j - 15;
  const int gwlo = jlo > 0 ? (jlo + 3) >> 2 : 0;
  const int gwhi = (j >> 2) < 52 ? (j >> 2) : 52;
  float sum = 0.f;
  for (int gh = ghlo; gh <= ghhi; ++gh) {
    const int r = i - gh * 4;
    const size_t base = ((size_t)b * C0R + (size_t)gh * (3 * GD) + ch) * 256 + (size_t)r * 16 + j;
    for (int gw = gwlo; gw <= gwhi; ++gw) {
      sum += bf2f(clean[base + (size_t)gw * 764]);
    }
  }
  const int cnt = (ghhi - ghlo + 1) * (gwhi - gwlo + 1);
  out[px] = sum / (float)cnt;
}

extern "C" void kernel_launch(void* const* d_in, const int* in_sizes, int n_in,
                              void* d_out, int out_size, void* d_ws, size_t ws_size,
                              hipStream_t stream) {
  const float* x  = (const float*)d_in[0];
  const float* w1 = (const float*)d_in[1];
  const float* b1 = (const float*)d_in[2];
  const float* w2 = (const float*)d_in[3];
  const float* b2 = (const float*)d_in[4];
  const float* w3 = (const float*)d_in[5];
  const float* b3 = (const float*)d_in[6];
  const float* w4 = (const float*)d_in[7];
  const float* b4 = (const float*)d_in[8];
  float* out = (float*)d_out;
  char* ws = (char*)d_ws;

  // ---- workspace regions (peak 130.15 MB) ----
  // A [0, 38928384):        wb1 -> wb4 -> clean
  // B [38928384, 73531392): H0 -> {Y1, wb2, wb3, Y2} -> msk
  // C [73531392,130154496): pt1 -> pt2 -> pt3 ; Y3 @ +37748736
  const size_t OFF_A = 0;
  const size_t OFF_B = 38928384;
  const size_t OFF_C = 73531392;

  unsigned short* wb1   = (unsigned short*)(ws + OFF_A);
  unsigned short* wb4   = (unsigned short*)(ws + OFF_A);
  unsigned short* clean = (unsigned short*)(ws + OFF_A);

  unsigned short* H0v = (unsigned short*)(ws + OFF_B);
  unsigned short* Y1  = (unsigned short*)(ws + OFF_B);
  unsigned short* wb2 = (unsigned short*)(ws + OFF_B + 9437184);
  unsigned short* wb3 = (unsigned short*)(ws + OFF_B + 12386304);
  unsigned short* Y2  = (unsigned short*)(ws + OFF_B + 15335424);
  unsigned short* msk = (unsigned short*)(ws + OFF_B);

  float* pt1 = (float*)(ws + OFF_C);
  float* pt2 = (float*)(ws + OFF_C);
  float* pt3 = (float*)(ws + OFF_C);
  unsigned short* Y3 = (unsigned short*)(ws + OFF_C + 37748736);

  // 1. stage inputs for GEMM1
  cvt_pad<<<dim3((C0P + 255) / 256, C1P), 256, 0, stream>>>(w1, wb1, C1R, C0R, C0P);
  dct_h0<<<dim3(C0P / 64, 8), 256, 0, stream>>>(x, H0v);

  // 2. GEMM1: 256^2 deep-pipelined split-K x3 (216 blocks, one round), reduce -> Y1
  gemm256<0, 1, 1><<<dim3(C1P / 256, NTOK / 256, 3), 512, 0, stream>>>(
      wb1, H0v, nullptr, pt1, C1P, C0P, 2816);
  reduce_act<<<dim3(NTOK * C1P / 4 / 256), 256, 0, stream>>>(pt1, b1, Y1, C1P, C1R, 3);

  // 3. remaining weight conversions
  cvt_pad_all<<<dim3(CVTOT / 256), 256, 0, stream>>>(w2, w3, w4, wb2, wb3, wb4);

  // 4. GEMM2 split-K x4 (chunk 576) -> Y2
  gemm_splitk<<<dim3(C2P / 128, NTOK / 128, 4), 256, 0, stream>>>(wb2, Y1, pt2, C2P, C1P, 576);
  reduce_act<<<dim3(NTOK * C2P / 4 / 256), 256, 0, stream>>>(pt2, b2, Y2, C2P, C2R, 4);

  // 5. GEMM3 split-K x2 (chunk 320) -> Y3
  gemm_splitk<<<dim3(C1P / 128, NTOK / 128, 2), 256, 0, stream>>>(wb3, Y2, pt3, C1P, C2P, 320);
  reduce_act<<<dim3(NTOK * C1P / 4 / 256), 256, 0, stream>>>(pt3, b3, Y3, C1P, C1R, 2);

  // 6. GEMM4: 256^2 main (rows 0..8191, 256 blocks = one round) + 128^2 tail (rows 8192..8447)
  gemm256<2, 0, 0><<<dim3(32, NTOK / 256), 512, 0, stream>>>(
      wb4, Y3, b4, msk, NTOK, C1P, C1P);
  gemm_bt<2, 0><<<dim3(2, NTOK / 128), 256, 0, stream>>>(
      wb4 + (size_t)8192 * C1P, Y3, b4 + 8192, C0R - 8192,
      msk + (size_t)8192 * NTOK, NTOK, C1P);

  // 7. mask*DCT -> IDCT -> clean (bf16, A region)
  mask_idct<<<dim3((C0R + 15) / 16, 8), 256, 0, stream>>>(x, msk, clean);

  // 8. overlap-add + normalize
  overlap_add<<<dim3((8 * 3 * 224 * 224 + 255) / 256), 256, 0, stream>>>(clean, out);
}

// Round 8
// 428.911 us; speedup vs baseline: 1.6569x; 1.0129x over previous
//
#include <hip/hip_runtime.h>
#include <stdint.h>

constexpr int INSZ = 224;
constexpr int GD   = 53;
constexpr int C0R = 8427, C1R = 2106, C2R = 526;
constexpr int C0P = 8448, C1P = 2304, C2P = 640;   // C1P padded to 9*256
constexpr int NTOK = 2048; // 8 batches * 256 DCT positions

typedef __attribute__((ext_vector_type(4))) float f32x4;
typedef __attribute__((ext_vector_type(8))) short bf16x8;

// cos(pi*j/32) for j=0..63 (period 64)
constexpr float CT[64] = {
  1.00000000f,  0.99518473f,  0.98078528f,  0.95694034f,
  0.92387953f,  0.88192126f,  0.83146961f,  0.77301045f,
  0.70710678f,  0.63439328f,  0.55557023f,  0.47139674f,
  0.38268343f,  0.29028468f,  0.19509032f,  0.09801714f,
  0.00000000f, -0.09801714f, -0.19509032f, -0.29028468f,
 -0.38268343f, -0.47139674f, -0.55557023f, -0.63439328f,
 -0.70710678f, -0.77301045f, -0.83146961f, -0.88192126f,
 -0.92387953f, -0.95694034f, -0.98078528f, -0.99518473f,
 -1.00000000f, -0.99518473f, -0.98078528f, -0.95694034f,
 -0.92387953f, -0.88192126f, -0.83146961f, -0.77301045f,
 -0.70710678f, -0.63439328f, -0.55557023f, -0.47139674f,
 -0.38268343f, -0.29028468f, -0.19509032f, -0.09801714f,
 -0.00000000f,  0.09801714f,  0.19509032f,  0.29028468f,
  0.38268343f,  0.47139674f,  0.55557023f,  0.63439328f,
  0.70710678f,  0.77301045f,  0.83146961f,  0.88192126f,
  0.92387953f,  0.95694034f,  0.98078528f,  0.99518473f
};
constexpr float Dfwd(int k, int n) { return 2.0f * CT[((2 * n + 1) * k) & 63]; }
constexpr float Dinv(int n, int k) { return CT[((2 * n + 1) * k) & 63] * (k == 0 ? 0.03125f : 0.0625f); }

// transpose scratch strides (floats)
constexpr int TRS_R = 20, TRS_T = 336;
constexpr int TRS_SZ = 15 * TRS_T + 15 * TRS_R + 16;

__device__ __forceinline__ unsigned short f2bf(float f) {
  union { float f; unsigned u; } v; v.f = f;
  return (unsigned short)((v.u + 0x7FFFu + ((v.u >> 16) & 1u)) >> 16);
}
__device__ __forceinline__ float bf2f(unsigned short b) {
  union { unsigned u; float f; } v; v.u = ((unsigned)b) << 16;
  return v.f;
}

__device__ __forceinline__ void gload_lds16(const void* g, void* l) {
  __builtin_amdgcn_global_load_lds(
      (__attribute__((address_space(1))) unsigned int*)(uintptr_t)g,
      (__attribute__((address_space(3))) unsigned int*)(unsigned int)(uintptr_t)l,
      16, 0, 0);
}

// XCD swizzle + L2 supertiling (4-wide bx stripes, by inner). requires (gx*gy)%8==0
__device__ __forceinline__ void xcd_tile(int& bx, int& by) {
  const int gx = gridDim.x, gy = gridDim.y;
  const int nwg = gx * gy;
  const int bid = blockIdx.y * gx + blockIdx.x;
  const int cpx = nwg >> 3;
  const int l = (bid & 7) * cpx + (bid >> 3);
  const int stripe = gy << 2;
  const int bxg = l / stripe;
  const int r = l - bxg * stripe;
  const int rem = gx - (bxg << 2);
  const int w = rem < 4 ? rem : 4;
  by = r / w;
  bx = (bxg << 2) + (r - by * w);
}

// -------- w1 fp32 -> bf16 padded, 8 elems/thread, uint4 store --------
constexpr int CV1_GPR = C0P / 8;            // 1056 groups per row
constexpr int CV1_TOT = C1P * CV1_GPR;      // 2,433,024 (/256 = 9504)
__global__ __launch_bounds__(256)
void cvt_pad8_w1(const float* __restrict__ src, unsigned short* __restrict__ dst) {
  const int i = blockIdx.x * 256 + threadIdx.x;
  if (i >= CV1_TOT) return;
  const int m = i / CV1_GPR;
  const int k0 = (i - m * CV1_GPR) * 8;
  const float* sr = src + (size_t)m * C0R + k0;
  const bool mok = (m < C1R);
  unsigned short h[8];
#pragma unroll
  for (int e = 0; e < 8; ++e)
    h[e] = f2bf((mok && k0 + e < C0R) ? sr[e] : 0.f);
  uint4 pk;
  pk.x = (unsigned)h[0] | ((unsigned)h[1] << 16);
  pk.y = (unsigned)h[2] | ((unsigned)h[3] << 16);
  pk.z = (unsigned)h[4] | ((unsigned)h[5] << 16);
  pk.w = (unsigned)h[6] | ((unsigned)h[7] << 16);
  *(uint4*)&dst[(size_t)m * C0P + k0] = pk;
}

// -------- fused w2/w3/w4 conversion, 8 elems/thread --------
constexpr int CV8_1 = C2P * C1P / 8;                 // 184320
constexpr int CV8_2 = CV8_1 + C1P * C2P / 8;         // 368640
constexpr int CV8_T = CV8_2 + C0P * C1P / 8;         // 2,801,664 (/256 = 10944)
__global__ __launch_bounds__(256)
void cvt_pad8_all(const float* __restrict__ w2, const float* __restrict__ w3,
                  const float* __restrict__ w4, unsigned short* __restrict__ d2,
                  unsigned short* __restrict__ d3, unsigned short* __restrict__ d4) {
  const int i = blockIdx.x * 256 + threadIdx.x;
  const float* src; unsigned short* dst;
  int m, k0, Kreal, Mreal, Kp;
  if (i < CV8_1) {
    const int gpr = C1P / 8;                  // 288
    m = i / gpr; k0 = (i - m * gpr) * 8;
    src = w2; dst = d2; Mreal = C2R; Kreal = C1R; Kp = C1P;
  } else if (i < CV8_2) {
    const int j = i - CV8_1;
    const int gpr = C2P / 8;                  // 80
    m = j / gpr; k0 = (j - m * gpr) * 8;
    src = w3; dst = d3; Mreal = C1R; Kreal = C2R; Kp = C2P;
  } else {
    const int j = i - CV8_2;
    const int gpr = C1P / 8;                  // 288
    m = j / gpr; k0 = (j - m * gpr) * 8;
    src = w4; dst = d4; Mreal = C0R; Kreal = C1R; Kp = C1P;
  }
  const float* sr = src + (size_t)m * Kreal + k0;
  const bool mok = (m < Mreal);
  unsigned short h[8];
#pragma unroll
  for (int e = 0; e < 8; ++e)
    h[e] = f2bf((mok && k0 + e < Kreal) ? sr[e] : 0.f);
  uint4 pk;
  pk.x = (unsigned)h[0] | ((unsigned)h[1] << 16);
  pk.y = (unsigned)h[2] | ((unsigned)h[3] << 16);
  pk.z = (unsigned)h[4] | ((unsigned)h[5] << 16);
  pk.w = (unsigned)h[6] | ((unsigned)h[7] << 16);
  *(uint4*)&dst[(size_t)m * Kp + k0] = pk;
}

// -------- DCT: x -> H0 bf16 [n=2048][c=8448]  (h = dct/256) --------
__global__ __launch_bounds__(256)
void dct_h0(const float* __restrict__ x, unsigned short* __restrict__ H0) {
  __shared__ float trp[TRS_SZ];
  __shared__ unsigned short hst[256 * 64];
  const int tid = threadIdx.x;
  const int b   = blockIdx.y;
  const int c0  = blockIdx.x * 64;
  const int t = tid >> 4, q = tid & 15;

  for (int g = 0; g < 4; ++g) {
    const int c = c0 + g * 16 + t;
    float p[16];
    {
      float4 v0{}, v1{}, v2{}, v3{};
      if (c < C0R) {
        const int ch = c % 3, gw = (c / 3) % GD, gh = c / (3 * GD);
        const float* xr = x + ((size_t)(b * 3 + ch) * INSZ + (gh * 4 + q)) * INSZ + gw * 4;
        v0 = *(const float4*)(xr);      v1 = *(const float4*)(xr + 4);
        v2 = *(const float4*)(xr + 8);  v3 = *(const float4*)(xr + 12);
      }
      p[0]=v0.x; p[1]=v0.y; p[2]=v0.z; p[3]=v0.w;
      p[4]=v1.x; p[5]=v1.y; p[6]=v1.z; p[7]=v1.w;
      p[8]=v2.x; p[9]=v2.y; p[10]=v2.z; p[11]=v2.w;
      p[12]=v3.x; p[13]=v3.y; p[14]=v3.z; p[15]=v3.w;
    }
    float r[16];
#pragma unroll
    for (int k = 0; k < 16; ++k) {
      float s = 0.f;
#pragma unroll
      for (int n = 0; n < 16; ++n) s += p[n] * Dfwd(k, n);
      r[k] = s;
    }
    float* wr = &trp[t * TRS_T + q * TRS_R];
#pragma unroll
    for (int k = 0; k < 16; k += 4)
      *(float4*)(wr + k) = make_float4(r[k], r[k+1], r[k+2], r[k+3]);
    __syncthreads();
    const int j = q;
    float rr[16];
#pragma unroll
    for (int i = 0; i < 16; ++i) rr[i] = trp[t * TRS_T + i * TRS_R + j];
#pragma unroll
    for (int k = 0; k < 16; ++k) {
      float s = 0.f;
#pragma unroll
      for (int i = 0; i < 16; ++i) s += rr[i] * Dfwd(k, i);
      hst[(k * 16 + j) * 64 + g * 16 + t] = f2bf(s * (1.f / 256.f));
    }
    __syncthreads();
  }
  const size_t base = ((size_t)b * 256) * C0P + c0;
#pragma unroll
  for (int i = 0; i < 8; ++i) {
    const int s = i * 256 + tid;
    const int kl = s >> 3, c16 = s & 7;
    *(uint4*)&H0[base + (size_t)kl * C0P + c16 * 8] = *(const uint4*)&hst[kl * 64 + c16 * 8];
  }
}

// ======== 256x256 deep-pipelined GEMM: BK=32, 8 waves (2M x 4N), wave tile 128x64,
// ======== 4 LDS bufs, stage distance 3 K-tiles, counted vmcnt(8) (never 0 in loop),
// ======== 2 phases/K-tile (m-half), B-frags reused, XOR swizzle both-sides, setprio.
template<int ACT, int OUT_NM, int SPLITK>
__global__ __launch_bounds__(512, 2)
void gemm256(const unsigned short* __restrict__ W, const unsigned short* __restrict__ Ht,
             const float* __restrict__ bias, void* __restrict__ outp,
             int ldo, int Kp, int chunkK) {
  __shared__ unsigned short As[4][8192];  // [buf][256 rows][32 K] (16B-chunk swizzled)
  __shared__ unsigned short Bs[4][8192];
  int bx, by; xcd_tile(bx, by);
  const int m0 = bx * 256, n0 = by * 256;
  const int tid = threadIdx.x;
  const int w = tid >> 6, lane = tid & 63;
  const int wr = w >> 2, wc = w & 3;
  const int lhi = lane >> 4, llo = lane & 15;
  const int kbase = SPLITK ? blockIdx.z * chunkK : 0;
  const int nkt = chunkK >> 5;

  const int srow = tid >> 2;                                  // 0..127
  const int slgc = ((tid & 3) ^ ((srow >> 1) & 3)) * 8;       // pre-swizzled global col

  f32x4 acc[8][4];
#pragma unroll
  for (int i = 0; i < 8; ++i)
#pragma unroll
    for (int j = 0; j < 4; ++j) acc[i][j] = f32x4{0.f, 0.f, 0.f, 0.f};

  auto STAGE_A = [&](int kt, int buf) {   // 2 gloads: A rows 0-127, 128-255
    const int kb = kbase + kt * 32 + slgc;
    gload_lds16(W + (size_t)(m0 + srow) * Kp + kb,       &As[buf][w * 512]);
    gload_lds16(W + (size_t)(m0 + 128 + srow) * Kp + kb, &As[buf][4096 + w * 512]);
  };
  auto STAGE_B = [&](int kt, int buf) {
    const int kb = kbase + kt * 32 + slgc;
    gload_lds16(Ht + (size_t)(n0 + srow) * Kp + kb,       &Bs[buf][w * 512]);
    gload_lds16(Ht + (size_t)(n0 + 128 + srow) * Kp + kb, &Bs[buf][4096 + w * 512]);
  };

  STAGE_A(0, 0); STAGE_B(0, 0);
  if (nkt > 1) { STAGE_A(1, 1); STAGE_B(1, 1); }
  if (nkt > 2) { STAGE_A(2, 2); STAGE_B(2, 2); }

  for (int kt = 0; kt < nkt; ++kt) {
    const int buf  = kt & 3;
    const int sbuf = (kt + 3) & 3;
    // wait for K-tile kt (4 loads/tile; up to 2 newer tiles = 8 loads stay in flight)
    if (kt + 3 <= nkt)      asm volatile("s_waitcnt vmcnt(8)" ::: "memory");
    else if (kt + 2 == nkt) asm volatile("s_waitcnt vmcnt(4)" ::: "memory");
    else                    asm volatile("s_waitcnt vmcnt(0)" ::: "memory");
    __builtin_amdgcn_s_barrier();
    __builtin_amdgcn_sched_barrier(0);

    bf16x8 af[4], bfr[4];
    // ---- phase A: m-half 0, read all B frags (kept for phase B) ----
#pragma unroll
    for (int mi = 0; mi < 4; ++mi) {
      const int row = wr * 128 + mi * 16 + llo;
      af[mi] = *(const bf16x8*)(&As[buf][row * 32 + ((lhi ^ ((row >> 1) & 3)) << 3)]);
    }
#pragma unroll
    for (int ni = 0; ni < 4; ++ni) {
      const int row = wc * 64 + ni * 16 + llo;
      bfr[ni] = *(const bf16x8*)(&Bs[buf][row * 32 + ((lhi ^ ((row >> 1) & 3)) << 3)]);
    }
    if (kt + 3 < nkt) STAGE_A(kt + 3, sbuf);
    __builtin_amdgcn_s_setprio(1);
#pragma unroll
    for (int mi = 0; mi < 4; ++mi)
#pragma unroll
      for (int ni = 0; ni < 4; ++ni)
        acc[mi][ni] = OUT_NM
          ? __builtin_amdgcn_mfma_f32_16x16x32_bf16(bfr[ni], af[mi], acc[mi][ni], 0, 0, 0)
          : __builtin_amdgcn_mfma_f32_16x16x32_bf16(af[mi], bfr[ni], acc[mi][ni], 0, 0, 0);
    __builtin_amdgcn_s_setprio(0);
    __builtin_amdgcn_s_barrier();
    __builtin_amdgcn_sched_barrier(0);
    // ---- phase B: m-half 1, reuse bfr ----
#pragma unroll
    for (int mi = 0; mi < 4; ++mi) {
      const int row = wr * 128 + 64 + mi * 16 + llo;
      af[mi] = *(const bf16x8*)(&As[buf][row * 32 + ((lhi ^ ((row >> 1) & 3)) << 3)]);
    }
    if (kt + 3 < nkt) STAGE_B(kt + 3, sbuf);
    __builtin_amdgcn_s_setprio(1);
#pragma unroll
    for (int mi = 0; mi < 4; ++mi)
#pragma unroll
      for (int ni = 0; ni < 4; ++ni)
        acc[4 + mi][ni] = OUT_NM
          ? __builtin_amdgcn_mfma_f32_16x16x32_bf16(bfr[ni], af[mi], acc[4 + mi][ni], 0, 0, 0)
          : __builtin_amdgcn_mfma_f32_16x16x32_bf16(af[mi], bfr[ni], acc[4 + mi][ni], 0, 0, 0);
    __builtin_amdgcn_s_setprio(0);
  }

  if (SPLITK) {
    float* pz = (float*)outp + (size_t)blockIdx.z * ((size_t)NTOK * ldo);
#pragma unroll
    for (int mh = 0; mh < 2; ++mh)
#pragma unroll
      for (int mi = 0; mi < 4; ++mi) {
        const int mg = m0 + wr * 128 + mh * 64 + mi * 16 + llo;
#pragma unroll
        for (int ni = 0; ni < 4; ++ni) {
          const int ng = n0 + wc * 64 + ni * 16 + lhi * 4;
#pragma unroll
          for (int r = 0; r < 4; ++r)
            pz[(size_t)(ng + r) * ldo + mg] = acc[mh * 4 + mi][ni][r];
        }
      }
  } else {
    unsigned short* out = (unsigned short*)outp;
#pragma unroll
    for (int mh = 0; mh < 2; ++mh)
#pragma unroll
      for (int mi = 0; mi < 4; ++mi) {
        const int mgb = m0 + wr * 128 + mh * 64 + mi * 16 + lhi * 4;
#pragma unroll
        for (int ni = 0; ni < 4; ++ni) {
          const int ng = n0 + wc * 64 + ni * 16 + llo;
#pragma unroll
          for (int r = 0; r < 4; ++r) {
            const int mg = mgb + r;
            float v = acc[mh * 4 + mi][ni][r] + bias[mg];
            if (ACT == 1) v = fmaxf(v, 0.f);
            else if (ACT == 2) v = 1.f / (1.f + expf(-v));
            out[(size_t)mg * ldo + ng] = f2bf(v);
          }
        }
      }
  }
}

// ======== 128x128 core (GEMM2/3 + GEMM4 tail) ========
template<int OUT_NM>
__device__ __forceinline__ void gemm_core(
    const unsigned short* __restrict__ W, const unsigned short* __restrict__ Ht,
    unsigned short (*As)[128 * 32], unsigned short (*Bs)[128 * 32],
    int m0, int n0, int Kp, int kbase, int nkt, int w, int lane, f32x4 acc[4][4]) {
  const int wr = w >> 1, wc = w & 1;
  const int lhi = lane >> 4, llo = lane & 15;

  const int chunk0 = w * 64 + lane;
  const int row0 = chunk0 >> 2, kc0 = chunk0 & 3;
  const int kcg0 = kc0 ^ ((row0 >> 1) & 3);
  const int chunk1 = 256 + w * 64 + lane;
  const int row1 = chunk1 >> 2, kc1 = chunk1 & 3;
  const int kcg1 = kc1 ^ ((row1 >> 1) & 3);

  auto STAGE = [&](int kt, int sel) {
    const int kb = kbase + kt * 32;
    gload_lds16(W  + (size_t)(m0 + row0) * Kp + kb + kcg0 * 8, &As[sel][(w * 64) * 8]);
    gload_lds16(Ht + (size_t)(n0 + row0) * Kp + kb + kcg0 * 8, &Bs[sel][(w * 64) * 8]);
    gload_lds16(W  + (size_t)(m0 + row1) * Kp + kb + kcg1 * 8, &As[sel][(256 + w * 64) * 8]);
    gload_lds16(Ht + (size_t)(n0 + row1) * Kp + kb + kcg1 * 8, &Bs[sel][(256 + w * 64) * 8]);
  };

  STAGE(0, 0);
  if (nkt > 1) STAGE(1, 1);

  int cur = 0, nxt = 1, nx2 = 2;
  for (int kt = 0; kt < nkt; ++kt) {
    if (kt + 1 < nkt) {
      asm volatile("s_waitcnt vmcnt(4)" ::: "memory");
      __builtin_amdgcn_s_barrier();
      __builtin_amdgcn_sched_barrier(0);
      if (kt + 2 < nkt) STAGE(kt + 2, nx2);
    } else {
      asm volatile("s_waitcnt vmcnt(0)" ::: "memory");
      __builtin_amdgcn_s_barrier();
      __builtin_amdgcn_sched_barrier(0);
    }
    bf16x8 af[4], bfr[4];
#pragma unroll
    for (int mi = 0; mi < 4; ++mi) {
      const int row = wr * 64 + mi * 16 + llo;
      af[mi] = *(const bf16x8*)(&As[cur][row * 32 + (lhi ^ ((row >> 1) & 3)) * 8]);
    }
#pragma unroll
    for (int ni = 0; ni < 4; ++ni) {
      const int row = wc * 64 + ni * 16 + llo;
      bfr[ni] = *(const bf16x8*)(&Bs[cur][row * 32 + (lhi ^ ((row >> 1) & 3)) * 8]);
    }
#pragma unroll
    for (int mi = 0; mi < 4; ++mi)
#pragma unroll
      for (int ni = 0; ni < 4; ++ni) {
        if (OUT_NM)
          acc[mi][ni] = __builtin_amdgcn_mfma_f32_16x16x32_bf16(bfr[ni], af[mi], acc[mi][ni], 0, 0, 0);
        else
          acc[mi][ni] = __builtin_amdgcn_mfma_f32_16x16x32_bf16(af[mi], bfr[ni], acc[mi][ni], 0, 0, 0);
      }
    const int tmp = cur; cur = nxt; nxt = nx2; nx2 = tmp;
  }
}

template<int ACT, int OUT_NM>
__global__ __launch_bounds__(256)
void gemm_bt(const unsigned short* __restrict__ W, const unsigned short* __restrict__ Ht,
             const float* __restrict__ bias, int Mreal,
             unsigned short* __restrict__ out, int ldo, int Kp) {
  __shared__ unsigned short As[3][128 * 32];
  __shared__ unsigned short Bs[3][128 * 32];
  int bx, by; xcd_tile(bx, by);
  const int tid = threadIdx.x;
  const int w = tid >> 6, lane = tid & 63;
  const int m0 = bx * 128, n0 = by * 128;
  const int wr = w >> 1, wc = w & 1;
  const int lhi = lane >> 4, llo = lane & 15;

  f32x4 acc[4][4];
#pragma unroll
  for (int i = 0; i < 4; ++i)
#pragma unroll
    for (int j = 0; j < 4; ++j) acc[i][j] = f32x4{0.f, 0.f, 0.f, 0.f};

  gemm_core<OUT_NM>(W, Ht, As, Bs, m0, n0, Kp, 0, Kp >> 5, w, lane, acc);

  if (OUT_NM) {
#pragma unroll
    for (int mi = 0; mi < 4; ++mi) {
      const int mg = m0 + wr * 64 + mi * 16 + llo;
      const float bv = (mg < Mreal) ? bias[mg] : 0.f;
#pragma unroll
      for (int ni = 0; ni < 4; ++ni) {
        const int ng = n0 + wc * 64 + ni * 16 + lhi * 4;
#pragma unroll
        for (int r = 0; r < 4; ++r) {
          float v = acc[mi][ni][r] + bv;
          if (ACT == 1) v = fmaxf(v, 0.f);
          else if (ACT == 2) v = 1.f / (1.f + expf(-v));
          out[(size_t)(ng + r) * ldo + mg] = f2bf(v);
        }
      }
    }
  } else {
#pragma unroll
    for (int mi = 0; mi < 4; ++mi) {
      const int mgb = m0 + wr * 64 + mi * 16 + lhi * 4;
#pragma unroll
      for (int ni = 0; ni < 4; ++ni) {
        const int ng = n0 + wc * 64 + ni * 16 + llo;
#pragma unroll
        for (int r = 0; r < 4; ++r) {
          const int mg = mgb + r;
          float v = acc[mi][ni][r] + ((mg < Mreal) ? bias[mg] : 0.f);
          if (ACT == 1) v = fmaxf(v, 0.f);
          else if (ACT == 2) v = 1.f / (1.f + expf(-v));
          out[(size_t)mg * ldo + ng] = f2bf(v);
        }
      }
    }
  }
}

__global__ __launch_bounds__(256)
void gemm_splitk(const unsigned short* __restrict__ W, const unsigned short* __restrict__ Ht,
                 float* __restrict__ part, int ldo /*Mp*/, int Kp, int chunkK) {
  __shared__ unsigned short As[3][128 * 32];
  __shared__ unsigned short Bs[3][128 * 32];
  int bx, by; xcd_tile(bx, by);
  const int z = blockIdx.z;
  const int tid = threadIdx.x;
  const int w = tid >> 6, lane = tid & 63;
  const int m0 = bx * 128, n0 = by * 128;
  const int wr = w >> 1, wc = w & 1;
  const int lhi = lane >> 4, llo = lane & 15;

  f32x4 acc[4][4];
#pragma unroll
  for (int i = 0; i < 4; ++i)
#pragma unroll
    for (int j = 0; j < 4; ++j) acc[i][j] = f32x4{0.f, 0.f, 0.f, 0.f};

  gemm_core<1>(W, Ht, As, Bs, m0, n0, Kp, z * chunkK, chunkK >> 5, w, lane, acc);

  float* pz = part + (size_t)z * NTOK * ldo;
#pragma unroll
  for (int mi = 0; mi < 4; ++mi) {
    const int mg = m0 + wr * 64 + mi * 16 + llo;
#pragma unroll
    for (int ni = 0; ni < 4; ++ni) {
      const int ng = n0 + wc * 64 + ni * 16 + lhi * 4;
#pragma unroll
      for (int r = 0; r < 4; ++r)
        pz[(size_t)(ng + r) * ldo + mg] = acc[mi][ni][r];
    }
  }
}

// -------- split-K reduce + bias + ReLU -> bf16 [n][m] --------
__global__ __launch_bounds__(256)
void reduce_act(const float* __restrict__ part, const float* __restrict__ bias,
                unsigned short* __restrict__ out, int Mp, int Mreal, int nch) {
  const int i4 = blockIdx.x * 256 + threadIdx.x;
  const int total = NTOK * Mp / 4;
  if (i4 >= total) return;
  const size_t off = (size_t)i4 * 4;
  const int m0 = (int)(off % Mp);
  float s0 = 0.f, s1 = 0.f, s2 = 0.f, s3 = 0.f;
  for (int z = 0; z < nch; ++z) {
    const float4 v = *(const float4*)(part + (size_t)z * NTOK * Mp + off);
    s0 += v.x; s1 += v.y; s2 += v.z; s3 += v.w;
  }
  s0 += (m0 + 0 < Mreal) ? bias[m0 + 0] : 0.f;
  s1 += (m0 + 1 < Mreal) ? bias[m0 + 1] : 0.f;
  s2 += (m0 + 2 < Mreal) ? bias[m0 + 2] : 0.f;
  s3 += (m0 + 3 < Mreal) ? bias[m0 + 3] : 0.f;
  s0 = fmaxf(s0, 0.f); s1 = fmaxf(s1, 0.f); s2 = fmaxf(s2, 0.f); s3 = fmaxf(s3, 0.f);
  uint2 pk;
  pk.x = (unsigned)f2bf(s0) | ((unsigned)f2bf(s1) << 16);
  pk.y = (unsigned)f2bf(s2) | ((unsigned)f2bf(s3) << 16);
  *(uint2*)&out[off] = pk;
}

// -------- recompute fp32 DCT, mask, IDCT, write clean tiles (bf16) --------
__global__ __launch_bounds__(256)
void mask_idct(const float* __restrict__ x, const unsigned short* __restrict__ masks,
               unsigned short* __restrict__ clean) {
  __shared__ float trp[TRS_SZ];
  const int tid = threadIdx.x;
  const int b   = blockIdx.y;
  const int c0  = blockIdx.x * 16;
  const int t = tid >> 4, q = tid & 15;
  const int c = c0 + t;
  const bool valid = (c < C0R);

  float p[16];
  {
    float4 v0{}, v1{}, v2{}, v3{};
    if (valid) {
      const int ch = c % 3, gw = (c / 3) % GD, gh = c / (3 * GD);
      const float* xr = x + ((size_t)(b * 3 + ch) * INSZ + (gh * 4 + q)) * INSZ + gw * 4;
      v0 = *(const float4*)(xr);      v1 = *(const float4*)(xr + 4);
      v2 = *(const float4*)(xr + 8);  v3 = *(const float4*)(xr + 12);
    }
    p[0]=v0.x; p[1]=v0.y; p[2]=v0.z; p[3]=v0.w;
    p[4]=v1.x; p[5]=v1.y; p[6]=v1.z; p[7]=v1.w;
    p[8]=v2.x; p[9]=v2.y; p[10]=v2.z; p[11]=v2.w;
    p[12]=v3.x; p[13]=v3.y; p[14]=v3.z; p[15]=v3.w;
  }
  float r[16];
#pragma unroll
  for (int k = 0; k < 16; ++k) {
    float s = 0.f;
#pragma unroll
    for (int n = 0; n < 16; ++n) s += p[n] * Dfwd(k, n);
    r[k] = s;
  }
  {
    float* wr = &trp[t * TRS_T + q * TRS_R];
#pragma unroll
    for (int k = 0; k < 16; k += 4)
      *(float4*)(wr + k) = make_float4(r[k], r[k+1], r[k+2], r[k+3]);
  }
  __syncthreads();
  const int j = q;
  float rr[16];
#pragma unroll
  for (int i = 0; i < 16; ++i) rr[i] = trp[t * TRS_T + i * TRS_R + j];
  float cd[16];
  const unsigned short* mrow = masks + (size_t)c * NTOK + (size_t)b * 256 + j;
#pragma unroll
  for (int k = 0; k < 16; ++k) {
    float s = 0.f;
#pragma unroll
    for (int i = 0; i < 16; ++i) s += rr[i] * Dfwd(k, i);
    const float mv = valid ? bf2f(mrow[k * 16]) : 0.f;
    cd[k] = s * mv;
  }
  float t3[16];
#pragma unroll
  for (int m = 0; m < 16; ++m) {
    float s = 0.f;
#pragma unroll
    for (int k = 0; k < 16; ++k) s += cd[k] * Dinv(m, k);
    t3[m] = s;
  }
  __syncthreads();
  {
    float* wr = &trp[t * TRS_T + j * TRS_R];
#pragma unroll
    for (int m = 0; m < 16; m += 4)
      *(float4*)(wr + m) = make_float4(t3[m], t3[m+1], t3[m+2], t3[m+3]);
  }
  __syncthreads();
  float tr[16];
#pragma unroll
  for (int l = 0; l < 16; ++l) tr[l] = trp[t * TRS_T + l * TRS_R + q];
  if (valid) {
    unsigned pk[8];
#pragma unroll
    for (int n2 = 0; n2 < 8; ++n2) {
      float s0 = 0.f, s1 = 0.f;
#pragma unroll
      for (int l = 0; l < 16; ++l) {
        s0 += tr[l] * Dinv(2 * n2, l);
        s1 += tr[l] * Dinv(2 * n2 + 1, l);
      }
      pk[n2] = (unsigned)f2bf(s0) | ((unsigned)f2bf(s1) << 16);
    }
    unsigned short* dst = clean + ((size_t)b * C0R + c) * 256 + q * 16;
    uint4* d4 = (uint4*)dst;
    d4[0] = make_uint4(pk[0], pk[1], pk[2], pk[3]);
    d4[1] = make_uint4(pk[4], pk[5], pk[6], pk[7]);
  }
}

// -------- overlap-add gather + count normalization --------
__global__ void overlap_add(const unsigned short* __restrict__ clean, float* __restrict__ out) {
  const int px = blockIdx.x * 256 + threadIdx.x;
  if (px >= 8 * 3 * 224 * 224) return;
  const int j = px % 224;
  const int i = (px / 224) % 224;
  const int bc = px / (224 * 224);
  const int ch = bc % 3, b = bc / 3;
  const int ilo = i - 15;
  const int ghlo = ilo > 0 ? (ilo + 3) >> 2 : 0;
  const int ghhi = (i >> 2) < 52 ? (i >> 2) : 52;
  const int jlo = j - 15;
  const int gwlo = jlo > 0 ? (jlo + 3) >> 2 : 0;
  const int gwhi = (j >> 2) < 52 ? (j >> 2) : 52;
  float sum = 0.f;
  for (int gh = ghlo; gh <= ghhi; ++gh) {
    const int r = i - gh * 4;
    const size_t base = ((size_t)b * C0R + (size_t)gh * (3 * GD) + ch) * 256 + (size_t)r * 16 + j;
    for (int gw = gwlo; gw <= gwhi; ++gw) {
      sum += bf2f(clean[base + (size_t)gw * 764]);
    }
  }
  const int cnt = (ghhi - ghlo + 1) * (gwhi - gwlo + 1);
  out[px] = sum / (float)cnt;
}

extern "C" void kernel_launch(void* const* d_in, const int* in_sizes, int n_in,
                              void* d_out, int out_size, void* d_ws, size_t ws_size,
                              hipStream_t stream) {
  const float* x  = (const float*)d_in[0];
  const float* w1 = (const float*)d_in[1];
  const float* b1 = (const float*)d_in[2];
  const float* w2 = (const float*)d_in[3];
  const float* b2 = (const float*)d_in[4];
  const float* w3 = (const float*)d_in[5];
  const float* b3 = (const float*)d_in[6];
  const float* w4 = (const float*)d_in[7];
  const float* b4 = (const float*)d_in[8];
  float* out = (float*)d_out;
  char* ws = (char*)d_ws;

  // ---- workspace regions (peak 130.15 MB) ----
  const size_t OFF_A = 0;
  const size_t OFF_B = 38928384;
  const size_t OFF_C = 73531392;

  unsigned short* wb1   = (unsigned short*)(ws + OFF_A);
  unsigned short* wb4   = (unsigned short*)(ws + OFF_A);
  unsigned short* clean = (unsigned short*)(ws + OFF_A);

  unsigned short* H0v = (unsigned short*)(ws + OFF_B);
  unsigned short* Y1  = (unsigned short*)(ws + OFF_B);
  unsigned short* wb2 = (unsigned short*)(ws + OFF_B + 9437184);
  unsigned short* wb3 = (unsigned short*)(ws + OFF_B + 12386304);
  unsigned short* Y2  = (unsigned short*)(ws + OFF_B + 15335424);
  unsigned short* msk = (unsigned short*)(ws + OFF_B);

  float* pt1 = (float*)(ws + OFF_C);
  float* pt2 = (float*)(ws + OFF_C);
  float* pt3 = (float*)(ws + OFF_C);
  unsigned short* Y3 = (unsigned short*)(ws + OFF_C + 37748736);

  // 1. stage inputs for GEMM1
  cvt_pad8_w1<<<dim3(CV1_TOT / 256), 256, 0, stream>>>(w1, wb1);
  dct_h0<<<dim3(C0P / 64, 8), 256, 0, stream>>>(x, H0v);

  // 2. GEMM1: 256^2 deep-pipelined split-K x3 (216 blocks), reduce -> Y1
  gemm256<0, 1, 1><<<dim3(C1P / 256, NTOK / 256, 3), 512, 0, stream>>>(
      wb1, H0v, nullptr, pt1, C1P, C0P, 2816);
  reduce_act<<<dim3(NTOK * C1P / 4 / 256), 256, 0, stream>>>(pt1, b1, Y1, C1P, C1R, 3);

  // 3. remaining weight conversions (vectorized single launch)
  cvt_pad8_all<<<dim3(CV8_T / 256), 256, 0, stream>>>(w2, w3, w4, wb2, wb3, wb4);

  // 4. GEMM2 split-K x4 (chunk 576) -> Y2
  gemm_splitk<<<dim3(C2P / 128, NTOK / 128, 4), 256, 0, stream>>>(wb2, Y1, pt2, C2P, C1P, 576);
  reduce_act<<<dim3(NTOK * C2P / 4 / 256), 256, 0, stream>>>(pt2, b2, Y2, C2P, C2R, 4);

  // 5. GEMM3 split-K x2 (chunk 320) -> Y3
  gemm_splitk<<<dim3(C1P / 128, NTOK / 128, 2), 256, 0, stream>>>(wb3, Y2, pt3, C1P, C2P, 320);
  reduce_act<<<dim3(NTOK * C1P / 4 / 256), 256, 0, stream>>>(pt3, b3, Y3, C1P, C1R, 2);

  // 6. GEMM4: 256^2 main (rows 0..8191) + 128^2 tail (rows 8192..8447, L2-warm)
  gemm256<2, 0, 0><<<dim3(32, NTOK / 256), 512, 0, stream>>>(
      wb4, Y3, b4, msk, NTOK, C1P, C1P);
  gemm_bt<2, 0><<<dim3(2, NTOK / 128), 256, 0, stream>>>(
      wb4 + (size_t)8192 * C1P, Y3, b4 + 8192, C0R - 8192,
      msk + (size_t)8192 * NTOK, NTOK, C1P);

  // 7. mask*DCT -> IDCT -> clean (bf16, A region)
  mask_idct<<<dim3((C0R + 15) / 16, 8), 256, 0, stream>>>(x, msk, clean);

  // 8. overlap-add + normalize
  overlap_add<<<dim3((8 * 3 * 224 * 224 + 255) / 256), 256, 0, stream>>>(clean, out);
}